// Round 7
// baseline (842.793 us; speedup 1.0000x reference)
//
#include <hip/hip_runtime.h>
#include <hip/hip_bf16.h>

#define H64 64
typedef float float4a __attribute__((ext_vector_type(4)));
typedef float f32x4  __attribute__((ext_vector_type(4)));
typedef short bf16x8 __attribute__((ext_vector_type(8)));

__device__ __forceinline__ unsigned short f2bf(float x) {
    unsigned b = __float_as_uint(x);
    unsigned r = (b + 0x7fffu + ((b >> 16) & 1u)) >> 16;
    return (unsigned short)r;
}

#define SCAN_B 256

// ---------------------------------------------------------------------------
// Binned CSR build over concatenated row space [0,2E): U rows [0,E), D [E,2E)
// entry packing in binned: [sign:1][src:21][dst_low:10]
// packed2 final:           [sign:1][src:31]
// ---------------------------------------------------------------------------
#define RPB       1024
#define RPB_SH    10
#define NBKT_MAX  512
#define R1_CHUNK  8192
#define BC_CHUNK  16384

__global__ __launch_bounds__(256) void bcount_kernel(
    const int* __restrict__ up_dst, const int* __restrict__ dn_dst,
    int* __restrict__ bktcnt, int nadj, int E, int nbkt)
{
    __shared__ int lc[NBKT_MAX];
    int t = threadIdx.x;
    for (int i = t; i < nbkt; i += 256) lc[i] = 0;
    __syncthreads();
    long long base = (long long)blockIdx.x * BC_CHUNK;
    long long total = 2LL * nadj;
    for (int i = 0; i < BC_CHUNK / 256; ++i) {
        long long g = base + i * 256 + t;
        if (g < total) {
            int dst2 = (g < nadj) ? up_dst[(int)g] : E + dn_dst[(int)(g - nadj)];
            atomicAdd(&lc[dst2 >> RPB_SH], 1);
        }
    }
    __syncthreads();
    for (int i = t; i < nbkt; i += 256) {
        int c = lc[i];
        if (c) atomicAdd(&bktcnt[i], c);
    }
}

__global__ __launch_bounds__(256) void bscan_kernel(
    const int* __restrict__ bktcnt, int* __restrict__ bstart, int* __restrict__ gcur,
    int nbkt, int total)
{
    __shared__ int s[SCAN_B];
    int t = threadIdx.x;
    int i0 = t * 2;
    int v0 = (i0     < nbkt) ? bktcnt[i0]     : 0;
    int v1 = (i0 + 1 < nbkt) ? bktcnt[i0 + 1] : 0;
    int tsum = v0 + v1;
    s[t] = tsum; __syncthreads();
    for (int off = 1; off < SCAN_B; off <<= 1) {
        int add = (t >= off) ? s[t - off] : 0;
        int cur = s[t];
        __syncthreads();
        s[t] = cur + add;
        __syncthreads();
    }
    int excl = s[t] - tsum;
    if (i0     < nbkt) { bstart[i0]     = excl;      gcur[i0]     = excl; }
    if (i0 + 1 < nbkt) { bstart[i0 + 1] = excl + v0; gcur[i0 + 1] = excl + v0; }
    if (t == 0) bstart[nbkt] = total;
}

__global__ __launch_bounds__(256) void bin_kernel(
    const int* __restrict__ up_index, const float* __restrict__ up_orient,
    const int* __restrict__ dn_index, const float* __restrict__ dn_orient,
    int* __restrict__ gcur, unsigned* __restrict__ binned,
    int nadj, int E, int nbkt)
{
    __shared__ unsigned sval[R1_CHUNK];
    __shared__ unsigned short sbkt[R1_CHUNK];
    __shared__ int lcnt[NBKT_MAX];
    __shared__ int goff[NBKT_MAX];
    __shared__ int lrank[NBKT_MAX];

    int t = threadIdx.x;
    for (int b = t; b < nbkt; b += 256) lcnt[b] = 0;
    __syncthreads();

    long long base = (long long)blockIdx.x * R1_CHUNK;
    int total = 2 * nadj;
    #pragma unroll 4
    for (int i = 0; i < R1_CHUNK / 256; ++i) {
        long long g = base + i * 256 + t;
        int li = i * 256 + t;
        if (g < total) {
            int src, dst2; float orient;
            if (g < nadj) {
                int e = (int)g;
                src = up_index[e]; dst2 = up_index[nadj + e]; orient = up_orient[e];
            } else {
                int e = (int)(g - nadj);
                src = dn_index[e]; dst2 = E + dn_index[nadj + e]; orient = dn_orient[e];
            }
            unsigned v = ((unsigned)src << RPB_SH) | (unsigned)(dst2 & (RPB - 1))
                       | (orient < 0.f ? 0x80000000u : 0u);
            int bk = dst2 >> RPB_SH;
            sval[li] = v;
            sbkt[li] = (unsigned short)bk;
            atomicAdd(&lcnt[bk], 1);
        } else {
            sbkt[li] = 0xFFFFu;
        }
    }
    __syncthreads();
    for (int b = t; b < nbkt; b += 256) {
        int c = lcnt[b];
        lrank[b] = 0;
        if (c > 0) goff[b] = atomicAdd(&gcur[b], c);
    }
    __syncthreads();
    #pragma unroll 4
    for (int i = 0; i < R1_CHUNK / 256; ++i) {
        int li = i * 256 + t;
        unsigned short bk = sbkt[li];
        if (bk != 0xFFFFu) {
            int r = atomicAdd(&lrank[bk], 1);
            binned[goff[bk] + r] = sval[li];
        }
    }
}

// per-bucket exact CSR placement; all per-row atomics in LDS.
// after this kernel, end2[d] == global row_end(d).
__global__ __launch_bounds__(256) void csr_fill2_kernel(
    const unsigned* __restrict__ binned, const int* __restrict__ bstart,
    int* __restrict__ end2, unsigned* __restrict__ packed2, int n2)
{
    __shared__ int lh[RPB];
    __shared__ int lcur[RPB];
    __shared__ int s[SCAN_B];
    int b = blockIdx.x;
    int t = threadIdx.x;
    int s0 = bstart[b], s1 = bstart[b + 1];
    int dbase = b << RPB_SH;

    for (int i = t; i < RPB; i += 256) lh[i] = 0;
    __syncthreads();
    for (int i = s0 + t; i < s1; i += 256) {
        unsigned v = binned[i];
        atomicAdd(&lh[v & (RPB - 1)], 1);
    }
    __syncthreads();

    int i0 = t * 4;
    int c0 = lh[i0], c1 = lh[i0 + 1], c2 = lh[i0 + 2], c3 = lh[i0 + 3];
    int tsum = c0 + c1 + c2 + c3;
    s[t] = tsum; __syncthreads();
    for (int off = 1; off < SCAN_B; off <<= 1) {
        int add = (t >= off) ? s[t - off] : 0;
        int cur = s[t];
        __syncthreads();
        s[t] = cur + add;
        __syncthreads();
    }
    int excl = s[t] - tsum;
    lcur[i0]     = excl;
    lcur[i0 + 1] = excl + c0;
    lcur[i0 + 2] = excl + c0 + c1;
    lcur[i0 + 3] = excl + c0 + c1 + c2;
    int gd = dbase + i0;
    if (gd     < n2) end2[gd]     = s0 + excl + c0;
    if (gd + 1 < n2) end2[gd + 1] = s0 + excl + c0 + c1;
    if (gd + 2 < n2) end2[gd + 2] = s0 + excl + c0 + c1 + c2;
    if (gd + 3 < n2) end2[gd + 3] = s0 + excl + tsum;
    __syncthreads();

    for (int i = s0 + t; i < s1; i += 256) {
        unsigned v = binned[i];
        int d = (int)(v & (RPB - 1));
        int p = atomicAdd(&lcur[d], 1);
        packed2[s0 + p] = (v & 0x80000000u) | ((v >> RPB_SH) & 0x1FFFFFu);
    }
}

// ---------------------------------------------------------------------------
// fallback path (only if nbkt > NBKT_MAX)
// ---------------------------------------------------------------------------
#define SCAN_TILE 1024

__global__ __launch_bounds__(256) void hist2_kernel(
    const int* __restrict__ up_dst, const int* __restrict__ dn_dst,
    int* __restrict__ deg2, int nadj, int E)
{
    int g = blockIdx.x * 256 + threadIdx.x;
    if (g < nadj) {
        atomicAdd(&deg2[up_dst[g]], 1);
    } else {
        int e = g - nadj;
        if (e < nadj) atomicAdd(&deg2[E + dn_dst[e]], 1);
    }
}

__global__ __launch_bounds__(256) void scan_partial(
    const int* __restrict__ deg, int* __restrict__ bsums, int n)
{
    __shared__ int s[SCAN_B];
    int t = threadIdx.x;
    int i0 = blockIdx.x * SCAN_TILE + t * 4;
    int sum = 0;
    if (i0 + 3 < n) {
        int4 v = *(const int4*)(deg + i0);
        sum = v.x + v.y + v.z + v.w;
    } else {
        for (int k = 0; k < 4; ++k) if (i0 + k < n) sum += deg[i0 + k];
    }
    s[t] = sum; __syncthreads();
    for (int off = 128; off > 0; off >>= 1) {
        if (t < off) s[t] += s[t + off];
        __syncthreads();
    }
    if (t == 0) bsums[blockIdx.x] = s[0];
}

__global__ __launch_bounds__(256) void scan_bsums_k(int* bsums, int nblk)
{
    __shared__ int s[SCAN_B];
    int t = threadIdx.x;
    int i0 = t * 4;
    int v0 = 0, v1 = 0, v2 = 0, v3 = 0;
    if (i0     < nblk) v0 = bsums[i0];
    if (i0 + 1 < nblk) v1 = bsums[i0 + 1];
    if (i0 + 2 < nblk) v2 = bsums[i0 + 2];
    if (i0 + 3 < nblk) v3 = bsums[i0 + 3];
    int tsum = v0 + v1 + v2 + v3;
    s[t] = tsum; __syncthreads();
    for (int off = 1; off < SCAN_B; off <<= 1) {
        int add = (t >= off) ? s[t - off] : 0;
        int cur = s[t];
        __syncthreads();
        s[t] = cur + add;
        __syncthreads();
    }
    int excl = s[t] - tsum;
    if (i0     < nblk) bsums[i0]     = excl;
    if (i0 + 1 < nblk) bsums[i0 + 1] = excl + v0;
    if (i0 + 2 < nblk) bsums[i0 + 2] = excl + v0 + v1;
    if (i0 + 3 < nblk) bsums[i0 + 3] = excl + v0 + v1 + v2;
}

__global__ __launch_bounds__(256) void scan_final(
    const int* __restrict__ deg, const int* __restrict__ bsums,
    int* __restrict__ outx, int n)
{
    __shared__ int s[SCAN_B];
    int t = threadIdx.x;
    int i0 = blockIdx.x * SCAN_TILE + t * 4;
    int v0 = 0, v1 = 0, v2 = 0, v3 = 0;
    if (i0 + 3 < n) {
        int4 v = *(const int4*)(deg + i0);
        v0 = v.x; v1 = v.y; v2 = v.z; v3 = v.w;
    } else {
        if (i0     < n) v0 = deg[i0];
        if (i0 + 1 < n) v1 = deg[i0 + 1];
        if (i0 + 2 < n) v2 = deg[i0 + 2];
        if (i0 + 3 < n) v3 = deg[i0 + 3];
    }
    int tsum = v0 + v1 + v2 + v3;
    s[t] = tsum; __syncthreads();
    for (int off = 1; off < SCAN_B; off <<= 1) {
        int add = (t >= off) ? s[t - off] : 0;
        int cur = s[t];
        __syncthreads();
        s[t] = cur + add;
        __syncthreads();
    }
    int excl = s[t] - tsum;
    int base = bsums[blockIdx.x] + excl;
    if (i0     < n) outx[i0]     = base;
    if (i0 + 1 < n) outx[i0 + 1] = base + v0;
    if (i0 + 2 < n) outx[i0 + 2] = base + v0 + v1;
    if (i0 + 3 < n) outx[i0 + 3] = base + v0 + v1 + v2;
}

__global__ __launch_bounds__(256) void reorder2_kernel(
    const int* __restrict__ up_index, const float* __restrict__ up_orient,
    const int* __restrict__ dn_index, const float* __restrict__ dn_orient,
    int* __restrict__ end2, unsigned* __restrict__ packed2, int nadj, int E)
{
    int g = blockIdx.x * 256 + threadIdx.x;
    if (g < nadj) {
        int src = up_index[g];
        int dst = up_index[nadj + g];
        int p = atomicAdd(&end2[dst], 1);
        packed2[p] = (unsigned)src | (up_orient[g] < 0.f ? 0x80000000u : 0u);
    } else {
        int e = g - nadj;
        if (e < nadj) {
            int src = dn_index[e];
            int dst = dn_index[nadj + e];
            int p = atomicAdd(&end2[E + dst], 1);
            packed2[p] = (unsigned)src | (dn_orient[e] < 0.f ? 0x80000000u : 0u);
        }
    }
}

// ---------------------------------------------------------------------------
// f32 -> bf16 conversions
// ---------------------------------------------------------------------------
__global__ __launch_bounds__(256) void conv_bf16_kernel(
    const float* __restrict__ x, unsigned short* __restrict__ hb, size_t n)
{
    size_t i = ((size_t)blockIdx.x * 256 + threadIdx.x) * 4;
    if (i + 3 < n) {
        float4a v = *(const float4a*)(x + i);
        uint2 o;
        o.x = (unsigned)f2bf(v[0]) | ((unsigned)f2bf(v[1]) << 16);
        o.y = (unsigned)f2bf(v[2]) | ((unsigned)f2bf(v[3]) << 16);
        *(uint2*)(hb + i) = o;
    } else {
        for (size_t k = i; k < n; ++k) hb[k] = f2bf(x[k]);
    }
}

// Wb layout: [l][mat(0=self,1=up,2=dn)][j][k] bf16
__global__ __launch_bounds__(256) void convW_kernel(
    const float* __restrict__ Ws, const float* __restrict__ Wu,
    const float* __restrict__ Wd, unsigned short* __restrict__ Wb, int L)
{
    int i = blockIdx.x * 256 + threadIdx.x;
    int total = L * 3 * 4096;
    if (i >= total) return;
    int l = i / (3 * 4096);
    int m = (i / 4096) % 3;
    int r = i & 4095;
    const float* src = (m == 0) ? Ws : ((m == 1) ? Wu : Wd);
    Wb[i] = f2bf(src[l * 4096 + r]);
}

// ---------------------------------------------------------------------------
// gather (scalarized): wave per dst row; dst forced into SGPR so entry
// metadata (packed2) is read via scalar loads; lane = feature (ushort load
// from SGPR row base); sign applied via SGPR xor mask. No shuffles at all.
// ---------------------------------------------------------------------------
__device__ __forceinline__ float seg_sum_scalar(
    const unsigned short* __restrict__ hb, const unsigned* __restrict__ packed2,
    int s0, int s1, int f)
{
    float acc = 0.f;
    int n = s0;
    for (; n + 4 <= s1; n += 4) {
        unsigned p0 = packed2[n];
        unsigned p1 = packed2[n + 1];
        unsigned p2 = packed2[n + 2];
        unsigned p3 = packed2[n + 3];
        const unsigned short* r0 = hb + (size_t)(p0 & 0x7fffffffu) * H64;
        const unsigned short* r1 = hb + (size_t)(p1 & 0x7fffffffu) * H64;
        const unsigned short* r2 = hb + (size_t)(p2 & 0x7fffffffu) * H64;
        const unsigned short* r3 = hb + (size_t)(p3 & 0x7fffffffu) * H64;
        unsigned u0 = (unsigned)r0[f] << 16;
        unsigned u1 = (unsigned)r1[f] << 16;
        unsigned u2 = (unsigned)r2[f] << 16;
        unsigned u3 = (unsigned)r3[f] << 16;
        u0 ^= (p0 & 0x80000000u);
        u1 ^= (p1 & 0x80000000u);
        u2 ^= (p2 & 0x80000000u);
        u3 ^= (p3 & 0x80000000u);
        acc += __uint_as_float(u0);
        acc += __uint_as_float(u1);
        acc += __uint_as_float(u2);
        acc += __uint_as_float(u3);
    }
    for (; n < s1; ++n) {
        unsigned p = packed2[n];
        const unsigned short* r = hb + (size_t)(p & 0x7fffffffu) * H64;
        unsigned u = (unsigned)r[f] << 16;
        u ^= (p & 0x80000000u);
        acc += __uint_as_float(u);
    }
    return acc;
}

__global__ __launch_bounds__(256) void gather_kernel(
    const unsigned short* __restrict__ hb,
    const int* __restrict__ end2, const unsigned* __restrict__ packed2,
    unsigned short* __restrict__ mupb, unsigned short* __restrict__ mdnb, int E)
{
    int dst = (int)((blockIdx.x * 256u + threadIdx.x) >> 6);
    dst = __builtin_amdgcn_readfirstlane(dst);   // force wave-uniform -> SGPR
    if (dst >= E) return;
    int f = threadIdx.x & 63;

    int s0U = (dst == 0) ? 0 : end2[dst - 1];
    int s1U = end2[dst];
    float accU = seg_sum_scalar(hb, packed2, s0U, s1U, f);

    int s0D = end2[E + dst - 1];
    int s1D = end2[E + dst];
    float accD = seg_sum_scalar(hb, packed2, s0D, s1D, f);

    mupb[(size_t)dst * H64 + f] = f2bf(accU);
    mdnb[(size_t)dst * H64 + f] = f2bf(accD);
}

// ---------------------------------------------------------------------------
// MFMA gemm+tanh: hb = tanh(hb@Ws^T + mup@Wu^T + mdn@Wd^T), all bf16 in/out.
// One wave per 16 rows; 24 x mfma_f32_16x16x32_bf16; zero LDS.
// ---------------------------------------------------------------------------
__global__ __launch_bounds__(256) void gemm_tanh_mfma(
    const unsigned short* __restrict__ hbin,
    const unsigned short* __restrict__ mupb, const unsigned short* __restrict__ mdnb,
    const unsigned short* __restrict__ Wb,   // [3][64][64] bf16 for this layer
    unsigned short* __restrict__ hbout, int E, int nblk16)
{
    int wid  = (blockIdx.x * 256 + threadIdx.x) >> 6;
    if (wid >= nblk16) return;
    int lane = threadIdx.x & 63;
    int lg = lane >> 4;      // 0..3
    int lr = lane & 15;      // 0..15

    bf16x8 bfr[3][4][2];
    #pragma unroll
    for (int m = 0; m < 3; ++m)
        #pragma unroll
        for (int jt = 0; jt < 4; ++jt)
            #pragma unroll
            for (int ks = 0; ks < 2; ++ks)
                bfr[m][jt][ks] = *(const bf16x8*)(Wb + m * 4096 + (jt * 16 + lr) * 64 + ks * 32 + lg * 8);

    int base = wid * 16;
    int arow = base + lr;
    bool ok = (arow < E);
    size_t aoff = (size_t)arow * H64 + lg * 8;

    bf16x8 afr[3][2];
    bf16x8 zz = {0, 0, 0, 0, 0, 0, 0, 0};
    #pragma unroll
    for (int ks = 0; ks < 2; ++ks) {
        afr[0][ks] = ok ? *(const bf16x8*)(hbin + aoff + ks * 32) : zz;
        afr[1][ks] = ok ? *(const bf16x8*)(mupb + aoff + ks * 32) : zz;
        afr[2][ks] = ok ? *(const bf16x8*)(mdnb + aoff + ks * 32) : zz;
    }

    f32x4 acc[4];
    #pragma unroll
    for (int jt = 0; jt < 4; ++jt) acc[jt] = (f32x4){0.f, 0.f, 0.f, 0.f};

    #pragma unroll
    for (int m = 0; m < 3; ++m)
        #pragma unroll
        for (int ks = 0; ks < 2; ++ks)
            #pragma unroll
            for (int jt = 0; jt < 4; ++jt)
                acc[jt] = __builtin_amdgcn_mfma_f32_16x16x32_bf16(
                    afr[m][ks], bfr[m][jt][ks], acc[jt], 0, 0, 0);

    #pragma unroll
    for (int jt = 0; jt < 4; ++jt) {
        #pragma unroll
        for (int reg = 0; reg < 4; ++reg) {
            int row = base + lg * 4 + reg;
            if (row < E) {
                float v = acc[jt][reg];
                float e2 = __expf(2.f * v);
                float val = 1.f - 2.f / (e2 + 1.f);
                hbout[(size_t)row * H64 + jt * 16 + lr] = f2bf(val);
            }
        }
    }
}

// ---------------------------------------------------------------------------
// pooled[batch[i]] += |h[i]| over sorted batch; h in bf16
// ---------------------------------------------------------------------------
#define ROWS_PER_WAVE 64
__global__ __launch_bounds__(256) void pool_kernel(
    const unsigned short* __restrict__ hb, const int* __restrict__ batch,
    float* __restrict__ pooled, int E)
{
    int wave = (int)((blockIdx.x * 256 + threadIdx.x) >> 6);
    int j = threadIdx.x & 63;
    int row0 = wave * ROWS_PER_WAVE;
    if (row0 >= E) return;
    int row1 = min(row0 + ROWS_PER_WAVE, E);

    int cur = batch[row0];
    float acc = 0.f;
    for (int i = row0; i < row1; ++i) {
        int b = batch[i];
        if (b != cur) {
            atomicAdd(&pooled[(size_t)cur * H64 + j], acc);
            acc = 0.f;
            cur = b;
        }
        unsigned u = hb[(size_t)i * H64 + j];
        acc += fabsf(__uint_as_float(u << 16));
    }
    atomicAdd(&pooled[(size_t)cur * H64 + j], acc);
}

// ---------------------------------------------------------------------------
__global__ __launch_bounds__(64) void head_kernel(
    const float* __restrict__ pooled,
    const float* __restrict__ lin1_w, const float* __restrict__ lin1_b,
    const float* __restrict__ lin2_w, const float* __restrict__ lin2_b,
    float* __restrict__ out, int C)
{
    __shared__ float p[64];
    __shared__ float z[64];
    int b = blockIdx.x;
    int t = threadIdx.x;

    p[t] = pooled[(size_t)b * H64 + t];
    __syncthreads();

    float acc = lin1_b[t];
    #pragma unroll
    for (int k = 0; k < 64; ++k) acc += p[k] * lin1_w[t * 64 + k];
    z[t] = fmaxf(acc, 0.f);
    __syncthreads();

    if (t < C) {
        float o = lin2_b[t];
        #pragma unroll
        for (int k = 0; k < 64; ++k) o += z[k] * lin2_w[t * 64 + k];
        out[(size_t)b * C + t] = o;
    }
}

// ---------------------------------------------------------------------------
extern "C" void kernel_launch(void* const* d_in, const int* in_sizes, int n_in,
                              void* d_out, int out_size, void* d_ws, size_t ws_size,
                              hipStream_t stream)
{
    const float* x          = (const float*)d_in[0];
    const int*   up_index   = (const int*)  d_in[1];
    const float* up_orient  = (const float*)d_in[2];
    const int*   down_index = (const int*)  d_in[3];
    const float* down_orient= (const float*)d_in[4];
    const int*   batch      = (const int*)  d_in[5];
    const float* W_up       = (const float*)d_in[6];
    const float* W_down     = (const float*)d_in[7];
    const float* W_self     = (const float*)d_in[8];
    const float* lin1_w     = (const float*)d_in[9];
    const float* lin1_b     = (const float*)d_in[10];
    const float* lin2_w     = (const float*)d_in[11];
    const float* lin2_b     = (const float*)d_in[12];
    float* out = (float*)d_out;

    const int E    = in_sizes[0] / H64;
    const int NADJ = in_sizes[1] / 2;
    const int C    = in_sizes[11] / H64;
    const int B    = out_size / C;
    const int L    = in_sizes[6] / (H64 * H64);

    // ---- workspace layout ----
    unsigned short* hb      = (unsigned short*)d_ws;              // E*64 bf16
    unsigned short* mupb    = hb   + (size_t)E * H64;             // E*64 bf16
    unsigned short* mdnb    = mupb + (size_t)E * H64;             // E*64 bf16
    float*          pooled  = (float*)(mdnb + (size_t)E * H64);   // B*64 f32
    int*            end2    = (int*)(pooled + (size_t)B * H64);   // 2E
    int*            deg2    = end2 + (size_t)2 * E;               // 2E (fallback)
    int*            bsums   = deg2 + (size_t)2 * E;               // 1024 (fallback)
    int*            bktcnt  = bsums + 1024;                       // NBKT_MAX
    int*            gcur    = bktcnt + NBKT_MAX;                  // NBKT_MAX
    int*            bstart  = gcur + NBKT_MAX;                    // NBKT_MAX+1
    unsigned short* Wb      = (unsigned short*)(bstart + NBKT_MAX + 1); // L*3*4096 bf16
    unsigned*       packed2 = (unsigned*)(Wb + (size_t)L * 3 * 4096);   // 2*NADJ
    unsigned*       binned  = packed2 + (size_t)2 * NADJ;         // 2*NADJ

    const int n2    = 2 * E;
    const int nbkt  = (n2 + RPB - 1) >> RPB_SH;
    const int total = 2 * NADJ;
    const int gather_blocks = (int)(((long long)E * 64 + 255) / 256);
    const int conv_blocks   = (int)(((long long)E * H64 / 4 + 255) / 256);
    const int nblk16        = (E + 15) / 16;
    const int gemm_blocks   = (nblk16 + 3) / 4;
    const int convw_blocks  = (L * 3 * 4096 + 255) / 256;
    const int pool_waves    = (E + ROWS_PER_WAVE - 1) / ROWS_PER_WAVE;
    const int pool_blocks   = (pool_waves + 3) / 4;

    // ---- CSR build ----
    if (nbkt <= NBKT_MAX) {
        const int bc_blocks = (total + BC_CHUNK - 1) / BC_CHUNK;
        const int r1_blocks = (total + R1_CHUNK - 1) / R1_CHUNK;
        hipMemsetAsync(bktcnt, 0, (size_t)NBKT_MAX * sizeof(int), stream);
        bcount_kernel<<<bc_blocks, 256, 0, stream>>>(up_index + NADJ, down_index + NADJ,
                                                     bktcnt, NADJ, E, nbkt);
        bscan_kernel<<<1, 256, 0, stream>>>(bktcnt, bstart, gcur, nbkt, total);
        bin_kernel<<<r1_blocks, 256, 0, stream>>>(up_index, up_orient, down_index, down_orient,
                                                  gcur, binned, NADJ, E, nbkt);
        csr_fill2_kernel<<<nbkt, 256, 0, stream>>>(binned, bstart, end2, packed2, n2);
    } else {
        const int both_blocks = (total + 255) / 256;
        const int nscan = (n2 + SCAN_TILE - 1) / SCAN_TILE;
        hipMemsetAsync(deg2, 0, (size_t)n2 * sizeof(int), stream);
        hist2_kernel<<<both_blocks, 256, 0, stream>>>(up_index + NADJ, down_index + NADJ, deg2, NADJ, E);
        scan_partial<<<nscan, 256, 0, stream>>>(deg2, bsums, n2);
        scan_bsums_k<<<1, 256, 0, stream>>>(bsums, nscan);
        scan_final<<<nscan, 256, 0, stream>>>(deg2, bsums, end2, n2);
        reorder2_kernel<<<both_blocks, 256, 0, stream>>>(up_index, up_orient, down_index, down_orient,
                                                         end2, packed2, NADJ, E);
    }

    // ---- bf16 conversions ----
    conv_bf16_kernel<<<conv_blocks, 256, 0, stream>>>(x, hb, (size_t)E * H64);
    convW_kernel<<<convw_blocks, 256, 0, stream>>>(W_self, W_up, W_down, Wb, L);

    // ---- layers (all state in hb, bf16) ----
    for (int l = 0; l < L; ++l) {
        gather_kernel<<<gather_blocks, 256, 0, stream>>>(hb, end2, packed2, mupb, mdnb, E);
        gemm_tanh_mfma<<<gemm_blocks, 256, 0, stream>>>(
            hb, mupb, mdnb, Wb + (size_t)l * 3 * 4096, hb, E, nblk16);
    }

    // ---- readout ----
    hipMemsetAsync(pooled, 0, (size_t)B * H64 * sizeof(float), stream);
    pool_kernel<<<pool_blocks, 256, 0, stream>>>(hb, batch, pooled, E);
    head_kernel<<<B, 64, 0, stream>>>(pooled, lin1_w, lin1_b, lin2_w, lin2_b, out, C);
}

// Round 8
// 842.500 us; speedup vs baseline: 1.0003x; 1.0003x over previous
//
#include <hip/hip_runtime.h>
#include <hip/hip_bf16.h>

#define H64 64
typedef float float4a __attribute__((ext_vector_type(4)));
typedef float f32x4  __attribute__((ext_vector_type(4)));
typedef short bf16x8 __attribute__((ext_vector_type(8)));

__device__ __forceinline__ unsigned short f2bf(float x) {
    unsigned b = __float_as_uint(x);
    unsigned r = (b + 0x7fffu + ((b >> 16) & 1u)) >> 16;
    return (unsigned short)r;
}

#define SCAN_B 256

// ---------------------------------------------------------------------------
// Binned CSR build over concatenated row space [0,2E): U rows [0,E), D [E,2E)
// entry packing in binned: [sign:1][src:21][dst_low:10]
// packed2 final:           [sign:1][src:31]
// ---------------------------------------------------------------------------
#define RPB       1024
#define RPB_SH    10
#define NBKT_MAX  512
#define R1_CHUNK  8192
#define BC_CHUNK  16384

__global__ __launch_bounds__(256) void bcount_kernel(
    const int* __restrict__ up_dst, const int* __restrict__ dn_dst,
    int* __restrict__ bktcnt, int nadj, int E, int nbkt)
{
    __shared__ int lc[NBKT_MAX];
    int t = threadIdx.x;
    for (int i = t; i < nbkt; i += 256) lc[i] = 0;
    __syncthreads();
    long long base = (long long)blockIdx.x * BC_CHUNK;
    long long total = 2LL * nadj;
    for (int i = 0; i < BC_CHUNK / 256; ++i) {
        long long g = base + i * 256 + t;
        if (g < total) {
            int dst2 = (g < nadj) ? up_dst[(int)g] : E + dn_dst[(int)(g - nadj)];
            atomicAdd(&lc[dst2 >> RPB_SH], 1);
        }
    }
    __syncthreads();
    for (int i = t; i < nbkt; i += 256) {
        int c = lc[i];
        if (c) atomicAdd(&bktcnt[i], c);
    }
}

__global__ __launch_bounds__(256) void bscan_kernel(
    const int* __restrict__ bktcnt, int* __restrict__ bstart, int* __restrict__ gcur,
    int nbkt, int total)
{
    __shared__ int s[SCAN_B];
    int t = threadIdx.x;
    int i0 = t * 2;
    int v0 = (i0     < nbkt) ? bktcnt[i0]     : 0;
    int v1 = (i0 + 1 < nbkt) ? bktcnt[i0 + 1] : 0;
    int tsum = v0 + v1;
    s[t] = tsum; __syncthreads();
    for (int off = 1; off < SCAN_B; off <<= 1) {
        int add = (t >= off) ? s[t - off] : 0;
        int cur = s[t];
        __syncthreads();
        s[t] = cur + add;
        __syncthreads();
    }
    int excl = s[t] - tsum;
    if (i0     < nbkt) { bstart[i0]     = excl;      gcur[i0]     = excl; }
    if (i0 + 1 < nbkt) { bstart[i0 + 1] = excl + v0; gcur[i0 + 1] = excl + v0; }
    if (t == 0) bstart[nbkt] = total;
}

__global__ __launch_bounds__(256) void bin_kernel(
    const int* __restrict__ up_index, const float* __restrict__ up_orient,
    const int* __restrict__ dn_index, const float* __restrict__ dn_orient,
    int* __restrict__ gcur, unsigned* __restrict__ binned,
    int nadj, int E, int nbkt)
{
    __shared__ unsigned sval[R1_CHUNK];
    __shared__ unsigned short sbkt[R1_CHUNK];
    __shared__ int lcnt[NBKT_MAX];
    __shared__ int goff[NBKT_MAX];
    __shared__ int lrank[NBKT_MAX];

    int t = threadIdx.x;
    for (int b = t; b < nbkt; b += 256) lcnt[b] = 0;
    __syncthreads();

    long long base = (long long)blockIdx.x * R1_CHUNK;
    int total = 2 * nadj;
    #pragma unroll 4
    for (int i = 0; i < R1_CHUNK / 256; ++i) {
        long long g = base + i * 256 + t;
        int li = i * 256 + t;
        if (g < total) {
            int src, dst2; float orient;
            if (g < nadj) {
                int e = (int)g;
                src = up_index[e]; dst2 = up_index[nadj + e]; orient = up_orient[e];
            } else {
                int e = (int)(g - nadj);
                src = dn_index[e]; dst2 = E + dn_index[nadj + e]; orient = dn_orient[e];
            }
            unsigned v = ((unsigned)src << RPB_SH) | (unsigned)(dst2 & (RPB - 1))
                       | (orient < 0.f ? 0x80000000u : 0u);
            int bk = dst2 >> RPB_SH;
            sval[li] = v;
            sbkt[li] = (unsigned short)bk;
            atomicAdd(&lcnt[bk], 1);
        } else {
            sbkt[li] = 0xFFFFu;
        }
    }
    __syncthreads();
    for (int b = t; b < nbkt; b += 256) {
        int c = lcnt[b];
        lrank[b] = 0;
        if (c > 0) goff[b] = atomicAdd(&gcur[b], c);
    }
    __syncthreads();
    #pragma unroll 4
    for (int i = 0; i < R1_CHUNK / 256; ++i) {
        int li = i * 256 + t;
        unsigned short bk = sbkt[li];
        if (bk != 0xFFFFu) {
            int r = atomicAdd(&lrank[bk], 1);
            binned[goff[bk] + r] = sval[li];
        }
    }
}

// per-bucket exact CSR placement; all per-row atomics in LDS.
// after this kernel, end2[d] == global row_end(d).
__global__ __launch_bounds__(256) void csr_fill2_kernel(
    const unsigned* __restrict__ binned, const int* __restrict__ bstart,
    int* __restrict__ end2, unsigned* __restrict__ packed2, int n2)
{
    __shared__ int lh[RPB];
    __shared__ int lcur[RPB];
    __shared__ int s[SCAN_B];
    int b = blockIdx.x;
    int t = threadIdx.x;
    int s0 = bstart[b], s1 = bstart[b + 1];
    int dbase = b << RPB_SH;

    for (int i = t; i < RPB; i += 256) lh[i] = 0;
    __syncthreads();
    for (int i = s0 + t; i < s1; i += 256) {
        unsigned v = binned[i];
        atomicAdd(&lh[v & (RPB - 1)], 1);
    }
    __syncthreads();

    int i0 = t * 4;
    int c0 = lh[i0], c1 = lh[i0 + 1], c2 = lh[i0 + 2], c3 = lh[i0 + 3];
    int tsum = c0 + c1 + c2 + c3;
    s[t] = tsum; __syncthreads();
    for (int off = 1; off < SCAN_B; off <<= 1) {
        int add = (t >= off) ? s[t - off] : 0;
        int cur = s[t];
        __syncthreads();
        s[t] = cur + add;
        __syncthreads();
    }
    int excl = s[t] - tsum;
    lcur[i0]     = excl;
    lcur[i0 + 1] = excl + c0;
    lcur[i0 + 2] = excl + c0 + c1;
    lcur[i0 + 3] = excl + c0 + c1 + c2;
    int gd = dbase + i0;
    if (gd     < n2) end2[gd]     = s0 + excl + c0;
    if (gd + 1 < n2) end2[gd + 1] = s0 + excl + c0 + c1;
    if (gd + 2 < n2) end2[gd + 2] = s0 + excl + c0 + c1 + c2;
    if (gd + 3 < n2) end2[gd + 3] = s0 + excl + tsum;
    __syncthreads();

    for (int i = s0 + t; i < s1; i += 256) {
        unsigned v = binned[i];
        int d = (int)(v & (RPB - 1));
        int p = atomicAdd(&lcur[d], 1);
        packed2[s0 + p] = (v & 0x80000000u) | ((v >> RPB_SH) & 0x1FFFFFu);
    }
}

// ---------------------------------------------------------------------------
// fallback path (only if nbkt > NBKT_MAX)
// ---------------------------------------------------------------------------
#define SCAN_TILE 1024

__global__ __launch_bounds__(256) void hist2_kernel(
    const int* __restrict__ up_dst, const int* __restrict__ dn_dst,
    int* __restrict__ deg2, int nadj, int E)
{
    int g = blockIdx.x * 256 + threadIdx.x;
    if (g < nadj) {
        atomicAdd(&deg2[up_dst[g]], 1);
    } else {
        int e = g - nadj;
        if (e < nadj) atomicAdd(&deg2[E + dn_dst[e]], 1);
    }
}

__global__ __launch_bounds__(256) void scan_partial(
    const int* __restrict__ deg, int* __restrict__ bsums, int n)
{
    __shared__ int s[SCAN_B];
    int t = threadIdx.x;
    int i0 = blockIdx.x * SCAN_TILE + t * 4;
    int sum = 0;
    if (i0 + 3 < n) {
        int4 v = *(const int4*)(deg + i0);
        sum = v.x + v.y + v.z + v.w;
    } else {
        for (int k = 0; k < 4; ++k) if (i0 + k < n) sum += deg[i0 + k];
    }
    s[t] = sum; __syncthreads();
    for (int off = 128; off > 0; off >>= 1) {
        if (t < off) s[t] += s[t + off];
        __syncthreads();
    }
    if (t == 0) bsums[blockIdx.x] = s[0];
}

__global__ __launch_bounds__(256) void scan_bsums_k(int* bsums, int nblk)
{
    __shared__ int s[SCAN_B];
    int t = threadIdx.x;
    int i0 = t * 4;
    int v0 = 0, v1 = 0, v2 = 0, v3 = 0;
    if (i0     < nblk) v0 = bsums[i0];
    if (i0 + 1 < nblk) v1 = bsums[i0 + 1];
    if (i0 + 2 < nblk) v2 = bsums[i0 + 2];
    if (i0 + 3 < nblk) v3 = bsums[i0 + 3];
    int tsum = v0 + v1 + v2 + v3;
    s[t] = tsum; __syncthreads();
    for (int off = 1; off < SCAN_B; off <<= 1) {
        int add = (t >= off) ? s[t - off] : 0;
        int cur = s[t];
        __syncthreads();
        s[t] = cur + add;
        __syncthreads();
    }
    int excl = s[t] - tsum;
    if (i0     < nblk) bsums[i0]     = excl;
    if (i0 + 1 < nblk) bsums[i0 + 1] = excl + v0;
    if (i0 + 2 < nblk) bsums[i0 + 2] = excl + v0 + v1;
    if (i0 + 3 < nblk) bsums[i0 + 3] = excl + v0 + v1 + v2;
}

__global__ __launch_bounds__(256) void scan_final(
    const int* __restrict__ deg, const int* __restrict__ bsums,
    int* __restrict__ outx, int n)
{
    __shared__ int s[SCAN_B];
    int t = threadIdx.x;
    int i0 = blockIdx.x * SCAN_TILE + t * 4;
    int v0 = 0, v1 = 0, v2 = 0, v3 = 0;
    if (i0 + 3 < n) {
        int4 v = *(const int4*)(deg + i0);
        v0 = v.x; v1 = v.y; v2 = v.z; v3 = v.w;
    } else {
        if (i0     < n) v0 = deg[i0];
        if (i0 + 1 < n) v1 = deg[i0 + 1];
        if (i0 + 2 < n) v2 = deg[i0 + 2];
        if (i0 + 3 < n) v3 = deg[i0 + 3];
    }
    int tsum = v0 + v1 + v2 + v3;
    s[t] = tsum; __syncthreads();
    for (int off = 1; off < SCAN_B; off <<= 1) {
        int add = (t >= off) ? s[t - off] : 0;
        int cur = s[t];
        __syncthreads();
        s[t] = cur + add;
        __syncthreads();
    }
    int excl = s[t] - tsum;
    int base = bsums[blockIdx.x] + excl;
    if (i0     < n) outx[i0]     = base;
    if (i0 + 1 < n) outx[i0 + 1] = base + v0;
    if (i0 + 2 < n) outx[i0 + 2] = base + v0 + v1;
    if (i0 + 3 < n) outx[i0 + 3] = base + v0 + v1 + v2;
}

__global__ __launch_bounds__(256) void reorder2_kernel(
    const int* __restrict__ up_index, const float* __restrict__ up_orient,
    const int* __restrict__ dn_index, const float* __restrict__ dn_orient,
    int* __restrict__ end2, unsigned* __restrict__ packed2, int nadj, int E)
{
    int g = blockIdx.x * 256 + threadIdx.x;
    if (g < nadj) {
        int src = up_index[g];
        int dst = up_index[nadj + g];
        int p = atomicAdd(&end2[dst], 1);
        packed2[p] = (unsigned)src | (up_orient[g] < 0.f ? 0x80000000u : 0u);
    } else {
        int e = g - nadj;
        if (e < nadj) {
            int src = dn_index[e];
            int dst = dn_index[nadj + e];
            int p = atomicAdd(&end2[E + dst], 1);
            packed2[p] = (unsigned)src | (dn_orient[e] < 0.f ? 0x80000000u : 0u);
        }
    }
}

// ---------------------------------------------------------------------------
// f32 -> bf16 conversions
// ---------------------------------------------------------------------------
__global__ __launch_bounds__(256) void conv_bf16_kernel(
    const float* __restrict__ x, unsigned short* __restrict__ hb, size_t n)
{
    size_t i = ((size_t)blockIdx.x * 256 + threadIdx.x) * 4;
    if (i + 3 < n) {
        float4a v = *(const float4a*)(x + i);
        uint2 o;
        o.x = (unsigned)f2bf(v[0]) | ((unsigned)f2bf(v[1]) << 16);
        o.y = (unsigned)f2bf(v[2]) | ((unsigned)f2bf(v[3]) << 16);
        *(uint2*)(hb + i) = o;
    } else {
        for (size_t k = i; k < n; ++k) hb[k] = f2bf(x[k]);
    }
}

// Wb layout: [l][mat(0=self,1=up,2=dn)][j][k] bf16
__global__ __launch_bounds__(256) void convW_kernel(
    const float* __restrict__ Ws, const float* __restrict__ Wu,
    const float* __restrict__ Wd, unsigned short* __restrict__ Wb, int L)
{
    int i = blockIdx.x * 256 + threadIdx.x;
    int total = L * 3 * 4096;
    if (i >= total) return;
    int l = i / (3 * 4096);
    int m = (i / 4096) % 3;
    int r = i & 4095;
    const float* src = (m == 0) ? Ws : ((m == 1) ? Wu : Wd);
    Wb[i] = f2bf(src[l * 4096 + r]);
}

// ---------------------------------------------------------------------------
// gather (4 entries / VMEM instr): wave = 4 groups of 16 lanes; group g
// processes entry n+g; each lane loads uint2 = 4 features (512B per instr).
// Sign via +/-1.0/0.0 cndmask feeding fmac (tail entries get sgn=0).
// Cross-group reduce: shfl_xor(16) + shfl_xor(32); g0 stores mup, g1 mdn.
// ---------------------------------------------------------------------------
__device__ __forceinline__ void seg_sum4(
    const unsigned* __restrict__ hb32, const unsigned* __restrict__ packed2,
    int s0, int s1, int g, int fp, int lane, float acc[4])
{
    for (int b = s0; b < s1; b += 64) {
        int cnt = min(64, s1 - b);
        unsigned pk = (lane < cnt) ? packed2[b + lane] : 0u;
        for (int n = 0; n < cnt; n += 4) {
            int idx = n + g;                       // per-lane varying shfl index
            unsigned pe = __shfl(pk, idx);
            bool valid = idx < cnt;
            float sgn = valid ? ((int)pe < 0 ? -1.f : 1.f) : 0.f;
            unsigned src = valid ? (pe & 0x7fffffffu) : 0u;
            uint2 u = *(const uint2*)(hb32 + (size_t)src * 32 + fp * 2);
            acc[0] = fmaf(__uint_as_float(u.x << 16),         sgn, acc[0]);
            acc[1] = fmaf(__uint_as_float(u.x & 0xFFFF0000u), sgn, acc[1]);
            acc[2] = fmaf(__uint_as_float(u.y << 16),         sgn, acc[2]);
            acc[3] = fmaf(__uint_as_float(u.y & 0xFFFF0000u), sgn, acc[3]);
        }
    }
}

__global__ __launch_bounds__(256) void gather_kernel(
    const unsigned* __restrict__ hb32,
    const int* __restrict__ end2, const unsigned* __restrict__ packed2,
    unsigned* __restrict__ mup32, unsigned* __restrict__ mdn32, int E)
{
    int dst = (int)((blockIdx.x * 256u + threadIdx.x) >> 6);
    if (dst >= E) return;
    int lane = threadIdx.x & 63;
    int g  = lane >> 4;      // 0..3: entry group
    int fp = lane & 15;      // feature pack: features [4fp, 4fp+4)

    float accU[4] = {0.f, 0.f, 0.f, 0.f};
    float accD[4] = {0.f, 0.f, 0.f, 0.f};

    int s0U = (dst == 0) ? 0 : end2[dst - 1];
    int s1U = end2[dst];
    seg_sum4(hb32, packed2, s0U, s1U, g, fp, lane, accU);

    int s0D = end2[E + dst - 1];
    int s1D = end2[E + dst];
    seg_sum4(hb32, packed2, s0D, s1D, g, fp, lane, accD);

    #pragma unroll
    for (int k = 0; k < 4; ++k) {
        accU[k] += __shfl_xor(accU[k], 16);
        accU[k] += __shfl_xor(accU[k], 32);
        accD[k] += __shfl_xor(accD[k], 16);
        accD[k] += __shfl_xor(accD[k], 32);
    }

    if (g < 2) {
        float* a = (g == 0) ? accU : accD;
        uint2 o;
        o.x = (unsigned)f2bf(a[0]) | ((unsigned)f2bf(a[1]) << 16);
        o.y = (unsigned)f2bf(a[2]) | ((unsigned)f2bf(a[3]) << 16);
        unsigned* ptr = (g == 0) ? mup32 : mdn32;
        *(uint2*)(ptr + (size_t)dst * 32 + fp * 2) = o;
    }
}

// ---------------------------------------------------------------------------
// MFMA gemm+tanh: hb = tanh(hb@Ws^T + mup@Wu^T + mdn@Wd^T), all bf16 in/out.
// One wave per 16 rows; 24 x mfma_f32_16x16x32_bf16; zero LDS.
// ---------------------------------------------------------------------------
__global__ __launch_bounds__(256) void gemm_tanh_mfma(
    const unsigned short* __restrict__ hbin,
    const unsigned short* __restrict__ mupb, const unsigned short* __restrict__ mdnb,
    const unsigned short* __restrict__ Wb,   // [3][64][64] bf16 for this layer
    unsigned short* __restrict__ hbout, int E, int nblk16)
{
    int wid  = (blockIdx.x * 256 + threadIdx.x) >> 6;
    if (wid >= nblk16) return;
    int lane = threadIdx.x & 63;
    int lg = lane >> 4;      // 0..3
    int lr = lane & 15;      // 0..15

    bf16x8 bfr[3][4][2];
    #pragma unroll
    for (int m = 0; m < 3; ++m)
        #pragma unroll
        for (int jt = 0; jt < 4; ++jt)
            #pragma unroll
            for (int ks = 0; ks < 2; ++ks)
                bfr[m][jt][ks] = *(const bf16x8*)(Wb + m * 4096 + (jt * 16 + lr) * 64 + ks * 32 + lg * 8);

    int base = wid * 16;
    int arow = base + lr;
    bool ok = (arow < E);
    size_t aoff = (size_t)arow * H64 + lg * 8;

    bf16x8 afr[3][2];
    bf16x8 zz = {0, 0, 0, 0, 0, 0, 0, 0};
    #pragma unroll
    for (int ks = 0; ks < 2; ++ks) {
        afr[0][ks] = ok ? *(const bf16x8*)(hbin + aoff + ks * 32) : zz;
        afr[1][ks] = ok ? *(const bf16x8*)(mupb + aoff + ks * 32) : zz;
        afr[2][ks] = ok ? *(const bf16x8*)(mdnb + aoff + ks * 32) : zz;
    }

    f32x4 acc[4];
    #pragma unroll
    for (int jt = 0; jt < 4; ++jt) acc[jt] = (f32x4){0.f, 0.f, 0.f, 0.f};

    #pragma unroll
    for (int m = 0; m < 3; ++m)
        #pragma unroll
        for (int ks = 0; ks < 2; ++ks)
            #pragma unroll
            for (int jt = 0; jt < 4; ++jt)
                acc[jt] = __builtin_amdgcn_mfma_f32_16x16x32_bf16(
                    afr[m][ks], bfr[m][jt][ks], acc[jt], 0, 0, 0);

    #pragma unroll
    for (int jt = 0; jt < 4; ++jt) {
        #pragma unroll
        for (int reg = 0; reg < 4; ++reg) {
            int row = base + lg * 4 + reg;
            if (row < E) {
                float v = acc[jt][reg];
                float e2 = __expf(2.f * v);
                float val = 1.f - 2.f / (e2 + 1.f);
                hbout[(size_t)row * H64 + jt * 16 + lr] = f2bf(val);
            }
        }
    }
}

// ---------------------------------------------------------------------------
// pooled[batch[i]] += |h[i]| over sorted batch; h in bf16
// ---------------------------------------------------------------------------
#define ROWS_PER_WAVE 64
__global__ __launch_bounds__(256) void pool_kernel(
    const unsigned short* __restrict__ hb, const int* __restrict__ batch,
    float* __restrict__ pooled, int E)
{
    int wave = (int)((blockIdx.x * 256 + threadIdx.x) >> 6);
    int j = threadIdx.x & 63;
    int row0 = wave * ROWS_PER_WAVE;
    if (row0 >= E) return;
    int row1 = min(row0 + ROWS_PER_WAVE, E);

    int cur = batch[row0];
    float acc = 0.f;
    for (int i = row0; i < row1; ++i) {
        int b = batch[i];
        if (b != cur) {
            atomicAdd(&pooled[(size_t)cur * H64 + j], acc);
            acc = 0.f;
            cur = b;
        }
        unsigned u = hb[(size_t)i * H64 + j];
        acc += fabsf(__uint_as_float(u << 16));
    }
    atomicAdd(&pooled[(size_t)cur * H64 + j], acc);
}

// ---------------------------------------------------------------------------
__global__ __launch_bounds__(64) void head_kernel(
    const float* __restrict__ pooled,
    const float* __restrict__ lin1_w, const float* __restrict__ lin1_b,
    const float* __restrict__ lin2_w, const float* __restrict__ lin2_b,
    float* __restrict__ out, int C)
{
    __shared__ float p[64];
    __shared__ float z[64];
    int b = blockIdx.x;
    int t = threadIdx.x;

    p[t] = pooled[(size_t)b * H64 + t];
    __syncthreads();

    float acc = lin1_b[t];
    #pragma unroll
    for (int k = 0; k < 64; ++k) acc += p[k] * lin1_w[t * 64 + k];
    z[t] = fmaxf(acc, 0.f);
    __syncthreads();

    if (t < C) {
        float o = lin2_b[t];
        #pragma unroll
        for (int k = 0; k < 64; ++k) o += z[k] * lin2_w[t * 64 + k];
        out[(size_t)b * C + t] = o;
    }
}

// ---------------------------------------------------------------------------
extern "C" void kernel_launch(void* const* d_in, const int* in_sizes, int n_in,
                              void* d_out, int out_size, void* d_ws, size_t ws_size,
                              hipStream_t stream)
{
    const float* x          = (const float*)d_in[0];
    const int*   up_index   = (const int*)  d_in[1];
    const float* up_orient  = (const float*)d_in[2];
    const int*   down_index = (const int*)  d_in[3];
    const float* down_orient= (const float*)d_in[4];
    const int*   batch      = (const int*)  d_in[5];
    const float* W_up       = (const float*)d_in[6];
    const float* W_down     = (const float*)d_in[7];
    const float* W_self     = (const float*)d_in[8];
    const float* lin1_w     = (const float*)d_in[9];
    const float* lin1_b     = (const float*)d_in[10];
    const float* lin2_w     = (const float*)d_in[11];
    const float* lin2_b     = (const float*)d_in[12];
    float* out = (float*)d_out;

    const int E    = in_sizes[0] / H64;
    const int NADJ = in_sizes[1] / 2;
    const int C    = in_sizes[11] / H64;
    const int B    = out_size / C;
    const int L    = in_sizes[6] / (H64 * H64);

    // ---- workspace layout ----
    unsigned short* hb      = (unsigned short*)d_ws;              // E*64 bf16
    unsigned short* mupb    = hb   + (size_t)E * H64;             // E*64 bf16
    unsigned short* mdnb    = mupb + (size_t)E * H64;             // E*64 bf16
    float*          pooled  = (float*)(mdnb + (size_t)E * H64);   // B*64 f32
    int*            end2    = (int*)(pooled + (size_t)B * H64);   // 2E
    int*            deg2    = end2 + (size_t)2 * E;               // 2E (fallback)
    int*            bsums   = deg2 + (size_t)2 * E;               // 1024 (fallback)
    int*            bktcnt  = bsums + 1024;                       // NBKT_MAX
    int*            gcur    = bktcnt + NBKT_MAX;                  // NBKT_MAX
    int*            bstart  = gcur + NBKT_MAX;                    // NBKT_MAX+1
    unsigned short* Wb      = (unsigned short*)(bstart + NBKT_MAX + 1); // L*3*4096 bf16
    unsigned*       packed2 = (unsigned*)(Wb + (size_t)L * 3 * 4096);   // 2*NADJ
    unsigned*       binned  = packed2 + (size_t)2 * NADJ;         // 2*NADJ

    const int n2    = 2 * E;
    const int nbkt  = (n2 + RPB - 1) >> RPB_SH;
    const int total = 2 * NADJ;
    const int gather_blocks = (int)(((long long)E * 64 + 255) / 256);
    const int conv_blocks   = (int)(((long long)E * H64 / 4 + 255) / 256);
    const int nblk16        = (E + 15) / 16;
    const int gemm_blocks   = (nblk16 + 3) / 4;
    const int convw_blocks  = (L * 3 * 4096 + 255) / 256;
    const int pool_waves    = (E + ROWS_PER_WAVE - 1) / ROWS_PER_WAVE;
    const int pool_blocks   = (pool_waves + 3) / 4;

    // ---- CSR build ----
    if (nbkt <= NBKT_MAX) {
        const int bc_blocks = (total + BC_CHUNK - 1) / BC_CHUNK;
        const int r1_blocks = (total + R1_CHUNK - 1) / R1_CHUNK;
        hipMemsetAsync(bktcnt, 0, (size_t)NBKT_MAX * sizeof(int), stream);
        bcount_kernel<<<bc_blocks, 256, 0, stream>>>(up_index + NADJ, down_index + NADJ,
                                                     bktcnt, NADJ, E, nbkt);
        bscan_kernel<<<1, 256, 0, stream>>>(bktcnt, bstart, gcur, nbkt, total);
        bin_kernel<<<r1_blocks, 256, 0, stream>>>(up_index, up_orient, down_index, down_orient,
                                                  gcur, binned, NADJ, E, nbkt);
        csr_fill2_kernel<<<nbkt, 256, 0, stream>>>(binned, bstart, end2, packed2, n2);
    } else {
        const int both_blocks = (total + 255) / 256;
        const int nscan = (n2 + SCAN_TILE - 1) / SCAN_TILE;
        hipMemsetAsync(deg2, 0, (size_t)n2 * sizeof(int), stream);
        hist2_kernel<<<both_blocks, 256, 0, stream>>>(up_index + NADJ, down_index + NADJ, deg2, NADJ, E);
        scan_partial<<<nscan, 256, 0, stream>>>(deg2, bsums, n2);
        scan_bsums_k<<<1, 256, 0, stream>>>(bsums, nscan);
        scan_final<<<nscan, 256, 0, stream>>>(deg2, bsums, end2, n2);
        reorder2_kernel<<<both_blocks, 256, 0, stream>>>(up_index, up_orient, down_index, down_orient,
                                                         end2, packed2, NADJ, E);
    }

    // ---- bf16 conversions ----
    conv_bf16_kernel<<<conv_blocks, 256, 0, stream>>>(x, hb, (size_t)E * H64);
    convW_kernel<<<convw_blocks, 256, 0, stream>>>(W_self, W_up, W_down, Wb, L);

    // ---- layers (all state in hb, bf16) ----
    for (int l = 0; l < L; ++l) {
        gather_kernel<<<gather_blocks, 256, 0, stream>>>(
            (const unsigned*)hb, end2, packed2,
            (unsigned*)mupb, (unsigned*)mdnb, E);
        gemm_tanh_mfma<<<gemm_blocks, 256, 0, stream>>>(
            hb, mupb, mdnb, Wb + (size_t)l * 3 * 4096, hb, E, nblk16);
    }

    // ---- readout ----
    hipMemsetAsync(pooled, 0, (size_t)B * H64 * sizeof(float), stream);
    pool_kernel<<<pool_blocks, 256, 0, stream>>>(hb, batch, pooled, E);
    head_kernel<<<B, 64, 0, stream>>>(pooled, lin1_w, lin1_b, lin2_w, lin2_b, out, C);
}

// Round 9
// 780.940 us; speedup vs baseline: 1.0792x; 1.0788x over previous
//
#include <hip/hip_runtime.h>
#include <hip/hip_bf16.h>

#define H64 64
typedef float float4a __attribute__((ext_vector_type(4)));
typedef float f32x4  __attribute__((ext_vector_type(4)));
typedef short bf16x8 __attribute__((ext_vector_type(8)));

__device__ __forceinline__ unsigned short f2bf(float x) {
    unsigned b = __float_as_uint(x);
    unsigned r = (b + 0x7fffu + ((b >> 16) & 1u)) >> 16;
    return (unsigned short)r;
}

#define SCAN_B 256

// ---------------------------------------------------------------------------
// Binned CSR build over concatenated row space [0,2E): U rows [0,E), D [E,2E)
// entry packing in binned: [sign:1][src:21][dst_low:10]
// packed2 final:           [sign:1][src:31]
// ---------------------------------------------------------------------------
#define RPB       1024
#define RPB_SH    10
#define NBKT_MAX  512
#define R1_CHUNK  8192
#define BC_CHUNK  16384

__global__ __launch_bounds__(256) void bcount_kernel(
    const int* __restrict__ up_dst, const int* __restrict__ dn_dst,
    int* __restrict__ bktcnt, int nadj, int E, int nbkt)
{
    __shared__ int lc[NBKT_MAX];
    int t = threadIdx.x;
    for (int i = t; i < nbkt; i += 256) lc[i] = 0;
    __syncthreads();
    long long base = (long long)blockIdx.x * BC_CHUNK;
    long long total = 2LL * nadj;
    for (int i = 0; i < BC_CHUNK / 256; ++i) {
        long long g = base + i * 256 + t;
        if (g < total) {
            int dst2 = (g < nadj) ? up_dst[(int)g] : E + dn_dst[(int)(g - nadj)];
            atomicAdd(&lc[dst2 >> RPB_SH], 1);
        }
    }
    __syncthreads();
    for (int i = t; i < nbkt; i += 256) {
        int c = lc[i];
        if (c) atomicAdd(&bktcnt[i], c);
    }
}

__global__ __launch_bounds__(256) void bscan_kernel(
    const int* __restrict__ bktcnt, int* __restrict__ bstart, int* __restrict__ gcur,
    int nbkt, int total)
{
    __shared__ int s[SCAN_B];
    int t = threadIdx.x;
    int i0 = t * 2;
    int v0 = (i0     < nbkt) ? bktcnt[i0]     : 0;
    int v1 = (i0 + 1 < nbkt) ? bktcnt[i0 + 1] : 0;
    int tsum = v0 + v1;
    s[t] = tsum; __syncthreads();
    for (int off = 1; off < SCAN_B; off <<= 1) {
        int add = (t >= off) ? s[t - off] : 0;
        int cur = s[t];
        __syncthreads();
        s[t] = cur + add;
        __syncthreads();
    }
    int excl = s[t] - tsum;
    if (i0     < nbkt) { bstart[i0]     = excl;      gcur[i0]     = excl; }
    if (i0 + 1 < nbkt) { bstart[i0 + 1] = excl + v0; gcur[i0 + 1] = excl + v0; }
    if (t == 0) bstart[nbkt] = total;
}

__global__ __launch_bounds__(256) void bin_kernel(
    const int* __restrict__ up_index, const float* __restrict__ up_orient,
    const int* __restrict__ dn_index, const float* __restrict__ dn_orient,
    int* __restrict__ gcur, unsigned* __restrict__ binned,
    int nadj, int E, int nbkt)
{
    __shared__ unsigned sval[R1_CHUNK];
    __shared__ unsigned short sbkt[R1_CHUNK];
    __shared__ int lcnt[NBKT_MAX];
    __shared__ int goff[NBKT_MAX];
    __shared__ int lrank[NBKT_MAX];

    int t = threadIdx.x;
    for (int b = t; b < nbkt; b += 256) lcnt[b] = 0;
    __syncthreads();

    long long base = (long long)blockIdx.x * R1_CHUNK;
    int total = 2 * nadj;
    #pragma unroll 4
    for (int i = 0; i < R1_CHUNK / 256; ++i) {
        long long g = base + i * 256 + t;
        int li = i * 256 + t;
        if (g < total) {
            int src, dst2; float orient;
            if (g < nadj) {
                int e = (int)g;
                src = up_index[e]; dst2 = up_index[nadj + e]; orient = up_orient[e];
            } else {
                int e = (int)(g - nadj);
                src = dn_index[e]; dst2 = E + dn_index[nadj + e]; orient = dn_orient[e];
            }
            unsigned v = ((unsigned)src << RPB_SH) | (unsigned)(dst2 & (RPB - 1))
                       | (orient < 0.f ? 0x80000000u : 0u);
            int bk = dst2 >> RPB_SH;
            sval[li] = v;
            sbkt[li] = (unsigned short)bk;
            atomicAdd(&lcnt[bk], 1);
        } else {
            sbkt[li] = 0xFFFFu;
        }
    }
    __syncthreads();
    for (int b = t; b < nbkt; b += 256) {
        int c = lcnt[b];
        lrank[b] = 0;
        if (c > 0) goff[b] = atomicAdd(&gcur[b], c);
    }
    __syncthreads();
    #pragma unroll 4
    for (int i = 0; i < R1_CHUNK / 256; ++i) {
        int li = i * 256 + t;
        unsigned short bk = sbkt[li];
        if (bk != 0xFFFFu) {
            int r = atomicAdd(&lrank[bk], 1);
            binned[goff[bk] + r] = sval[li];
        }
    }
}

// per-bucket exact CSR placement; all per-row atomics in LDS.
// after this kernel, end2[d] == global row_end(d).
__global__ __launch_bounds__(256) void csr_fill2_kernel(
    const unsigned* __restrict__ binned, const int* __restrict__ bstart,
    int* __restrict__ end2, unsigned* __restrict__ packed2, int n2)
{
    __shared__ int lh[RPB];
    __shared__ int lcur[RPB];
    __shared__ int s[SCAN_B];
    int b = blockIdx.x;
    int t = threadIdx.x;
    int s0 = bstart[b], s1 = bstart[b + 1];
    int dbase = b << RPB_SH;

    for (int i = t; i < RPB; i += 256) lh[i] = 0;
    __syncthreads();
    for (int i = s0 + t; i < s1; i += 256) {
        unsigned v = binned[i];
        atomicAdd(&lh[v & (RPB - 1)], 1);
    }
    __syncthreads();

    int i0 = t * 4;
    int c0 = lh[i0], c1 = lh[i0 + 1], c2 = lh[i0 + 2], c3 = lh[i0 + 3];
    int tsum = c0 + c1 + c2 + c3;
    s[t] = tsum; __syncthreads();
    for (int off = 1; off < SCAN_B; off <<= 1) {
        int add = (t >= off) ? s[t - off] : 0;
        int cur = s[t];
        __syncthreads();
        s[t] = cur + add;
        __syncthreads();
    }
    int excl = s[t] - tsum;
    lcur[i0]     = excl;
    lcur[i0 + 1] = excl + c0;
    lcur[i0 + 2] = excl + c0 + c1;
    lcur[i0 + 3] = excl + c0 + c1 + c2;
    int gd = dbase + i0;
    if (gd     < n2) end2[gd]     = s0 + excl + c0;
    if (gd + 1 < n2) end2[gd + 1] = s0 + excl + c0 + c1;
    if (gd + 2 < n2) end2[gd + 2] = s0 + excl + c0 + c1 + c2;
    if (gd + 3 < n2) end2[gd + 3] = s0 + excl + tsum;
    __syncthreads();

    for (int i = s0 + t; i < s1; i += 256) {
        unsigned v = binned[i];
        int d = (int)(v & (RPB - 1));
        int p = atomicAdd(&lcur[d], 1);
        packed2[s0 + p] = (v & 0x80000000u) | ((v >> RPB_SH) & 0x1FFFFFu);
    }
}

// ---------------------------------------------------------------------------
// fallback path (only if nbkt > NBKT_MAX)
// ---------------------------------------------------------------------------
#define SCAN_TILE 1024

__global__ __launch_bounds__(256) void hist2_kernel(
    const int* __restrict__ up_dst, const int* __restrict__ dn_dst,
    int* __restrict__ deg2, int nadj, int E)
{
    int g = blockIdx.x * 256 + threadIdx.x;
    if (g < nadj) {
        atomicAdd(&deg2[up_dst[g]], 1);
    } else {
        int e = g - nadj;
        if (e < nadj) atomicAdd(&deg2[E + dn_dst[e]], 1);
    }
}

__global__ __launch_bounds__(256) void scan_partial(
    const int* __restrict__ deg, int* __restrict__ bsums, int n)
{
    __shared__ int s[SCAN_B];
    int t = threadIdx.x;
    int i0 = blockIdx.x * SCAN_TILE + t * 4;
    int sum = 0;
    if (i0 + 3 < n) {
        int4 v = *(const int4*)(deg + i0);
        sum = v.x + v.y + v.z + v.w;
    } else {
        for (int k = 0; k < 4; ++k) if (i0 + k < n) sum += deg[i0 + k];
    }
    s[t] = sum; __syncthreads();
    for (int off = 128; off > 0; off >>= 1) {
        if (t < off) s[t] += s[t + off];
        __syncthreads();
    }
    if (t == 0) bsums[blockIdx.x] = s[0];
}

__global__ __launch_bounds__(256) void scan_bsums_k(int* bsums, int nblk)
{
    __shared__ int s[SCAN_B];
    int t = threadIdx.x;
    int i0 = t * 4;
    int v0 = 0, v1 = 0, v2 = 0, v3 = 0;
    if (i0     < nblk) v0 = bsums[i0];
    if (i0 + 1 < nblk) v1 = bsums[i0 + 1];
    if (i0 + 2 < nblk) v2 = bsums[i0 + 2];
    if (i0 + 3 < nblk) v3 = bsums[i0 + 3];
    int tsum = v0 + v1 + v2 + v3;
    s[t] = tsum; __syncthreads();
    for (int off = 1; off < SCAN_B; off <<= 1) {
        int add = (t >= off) ? s[t - off] : 0;
        int cur = s[t];
        __syncthreads();
        s[t] = cur + add;
        __syncthreads();
    }
    int excl = s[t] - tsum;
    if (i0     < nblk) bsums[i0]     = excl;
    if (i0 + 1 < nblk) bsums[i0 + 1] = excl + v0;
    if (i0 + 2 < nblk) bsums[i0 + 2] = excl + v0 + v1;
    if (i0 + 3 < nblk) bsums[i0 + 3] = excl + v0 + v1 + v2;
}

__global__ __launch_bounds__(256) void scan_final(
    const int* __restrict__ deg, const int* __restrict__ bsums,
    int* __restrict__ outx, int n)
{
    __shared__ int s[SCAN_B];
    int t = threadIdx.x;
    int i0 = blockIdx.x * SCAN_TILE + t * 4;
    int v0 = 0, v1 = 0, v2 = 0, v3 = 0;
    if (i0 + 3 < n) {
        int4 v = *(const int4*)(deg + i0);
        v0 = v.x; v1 = v.y; v2 = v.z; v3 = v.w;
    } else {
        if (i0     < n) v0 = deg[i0];
        if (i0 + 1 < n) v1 = deg[i0 + 1];
        if (i0 + 2 < n) v2 = deg[i0 + 2];
        if (i0 + 3 < n) v3 = deg[i0 + 3];
    }
    int tsum = v0 + v1 + v2 + v3;
    s[t] = tsum; __syncthreads();
    for (int off = 1; off < SCAN_B; off <<= 1) {
        int add = (t >= off) ? s[t - off] : 0;
        int cur = s[t];
        __syncthreads();
        s[t] = cur + add;
        __syncthreads();
    }
    int excl = s[t] - tsum;
    int base = bsums[blockIdx.x] + excl;
    if (i0     < n) outx[i0]     = base;
    if (i0 + 1 < n) outx[i0 + 1] = base + v0;
    if (i0 + 2 < n) outx[i0 + 2] = base + v0 + v1;
    if (i0 + 3 < n) outx[i0 + 3] = base + v0 + v1 + v2;
}

__global__ __launch_bounds__(256) void reorder2_kernel(
    const int* __restrict__ up_index, const float* __restrict__ up_orient,
    const int* __restrict__ dn_index, const float* __restrict__ dn_orient,
    int* __restrict__ end2, unsigned* __restrict__ packed2, int nadj, int E)
{
    int g = blockIdx.x * 256 + threadIdx.x;
    if (g < nadj) {
        int src = up_index[g];
        int dst = up_index[nadj + g];
        int p = atomicAdd(&end2[dst], 1);
        packed2[p] = (unsigned)src | (up_orient[g] < 0.f ? 0x80000000u : 0u);
    } else {
        int e = g - nadj;
        if (e < nadj) {
            int src = dn_index[e];
            int dst = dn_index[nadj + e];
            int p = atomicAdd(&end2[E + dst], 1);
            packed2[p] = (unsigned)src | (dn_orient[e] < 0.f ? 0x80000000u : 0u);
        }
    }
}

// ---------------------------------------------------------------------------
// f32 -> bf16 conversions
// ---------------------------------------------------------------------------
__global__ __launch_bounds__(256) void conv_bf16_kernel(
    const float* __restrict__ x, unsigned short* __restrict__ hb, size_t n)
{
    size_t i = ((size_t)blockIdx.x * 256 + threadIdx.x) * 4;
    if (i + 3 < n) {
        float4a v = *(const float4a*)(x + i);
        uint2 o;
        o.x = (unsigned)f2bf(v[0]) | ((unsigned)f2bf(v[1]) << 16);
        o.y = (unsigned)f2bf(v[2]) | ((unsigned)f2bf(v[3]) << 16);
        *(uint2*)(hb + i) = o;
    } else {
        for (size_t k = i; k < n; ++k) hb[k] = f2bf(x[k]);
    }
}

// Wb layout: [l][mat(0=self,1=up,2=dn)][j][k] bf16
__global__ __launch_bounds__(256) void convW_kernel(
    const float* __restrict__ Ws, const float* __restrict__ Wu,
    const float* __restrict__ Wd, unsigned short* __restrict__ Wb, int L)
{
    int i = blockIdx.x * 256 + threadIdx.x;
    int total = L * 3 * 4096;
    if (i >= total) return;
    int l = i / (3 * 4096);
    int m = (i / 4096) % 3;
    int r = i & 4095;
    const float* src = (m == 0) ? Ws : ((m == 1) ? Wu : Wd);
    Wb[i] = f2bf(src[l * 4096 + r]);
}

// ---------------------------------------------------------------------------
// gather (pair-vectorized, deep-unrolled): wave per dst row; lane loads uint
// (2 bf16 feats); lanes 0-31 process even entries, 32-63 odd. Main block:
// 16 entries with 8 independent loads in flight (16 rows); then 8; then tail.
// ---------------------------------------------------------------------------
__device__ __forceinline__ void seg_sum2(
    const unsigned* __restrict__ hb32, const unsigned* __restrict__ packed2,
    int s0, int s1, int fp, int g, int lane, float& r0, float& r1)
{
    float a0 = 0.f, a1 = 0.f;
    for (int b = s0; b < s1; b += 64) {
        int cnt = min(64, s1 - b);
        unsigned pk = (lane < cnt) ? packed2[b + lane] : 0u;
        int n = 0;
        for (; n + 16 <= cnt; n += 16) {
            unsigned p[8], u[8];
            #pragma unroll
            for (int t = 0; t < 8; ++t) p[t] = __shfl(pk, n + 2 * t + g);
            #pragma unroll
            for (int t = 0; t < 8; ++t)
                u[t] = hb32[(size_t)(p[t] & 0x7fffffffu) * 32 + fp];
            #pragma unroll
            for (int t = 0; t < 8; ++t) {
                unsigned s = p[t] & 0x80000000u;
                unsigned x = u[t] ^ (s | (s >> 16));
                a0 += __uint_as_float(x << 16);
                a1 += __uint_as_float(x & 0xFFFF0000u);
            }
        }
        for (; n + 8 <= cnt; n += 8) {
            unsigned p[4], u[4];
            #pragma unroll
            for (int t = 0; t < 4; ++t) p[t] = __shfl(pk, n + 2 * t + g);
            #pragma unroll
            for (int t = 0; t < 4; ++t)
                u[t] = hb32[(size_t)(p[t] & 0x7fffffffu) * 32 + fp];
            #pragma unroll
            for (int t = 0; t < 4; ++t) {
                unsigned s = p[t] & 0x80000000u;
                unsigned x = u[t] ^ (s | (s >> 16));
                a0 += __uint_as_float(x << 16);
                a1 += __uint_as_float(x & 0xFFFF0000u);
            }
        }
        for (; n < cnt; n += 2) {
            int idx = n + g;
            bool valid = idx < cnt;
            unsigned pe = __shfl(pk, valid ? idx : n);
            if (valid) {
                unsigned x = hb32[(size_t)(pe & 0x7fffffffu) * 32 + fp];
                unsigned s = pe & 0x80000000u;
                x ^= (s | (s >> 16));
                a0 += __uint_as_float(x << 16);
                a1 += __uint_as_float(x & 0xFFFF0000u);
            }
        }
    }
    r0 = a0; r1 = a1;
}

__global__ __launch_bounds__(256) void gather_kernel(
    const unsigned* __restrict__ hb32,
    const int* __restrict__ end2, const unsigned* __restrict__ packed2,
    unsigned* __restrict__ mup32, unsigned* __restrict__ mdn32, int E)
{
    int dst = (int)((blockIdx.x * 256u + threadIdx.x) >> 6);
    if (dst >= E) return;
    int lane = threadIdx.x & 63;
    int g  = lane >> 5;
    int fp = lane & 31;

    int s0U = (dst == 0) ? 0 : end2[dst - 1];
    int s1U = end2[dst];
    float u0, u1;
    seg_sum2(hb32, packed2, s0U, s1U, fp, g, lane, u0, u1);

    int s0D = end2[E + dst - 1];
    int s1D = end2[E + dst];
    float d0, d1;
    seg_sum2(hb32, packed2, s0D, s1D, fp, g, lane, d0, d1);

    u0 += __shfl_xor(u0, 32); u1 += __shfl_xor(u1, 32);
    d0 += __shfl_xor(d0, 32); d1 += __shfl_xor(d1, 32);

    unsigned valU = (unsigned)f2bf(u0) | ((unsigned)f2bf(u1) << 16);
    unsigned valD = (unsigned)f2bf(d0) | ((unsigned)f2bf(d1) << 16);
    unsigned* ptr = g ? mdn32 : mup32;
    ptr[(size_t)dst * 32 + fp] = g ? valD : valU;
}

// ---------------------------------------------------------------------------
// MFMA gemm+tanh: hb = tanh(hb@Ws^T + mup@Wu^T + mdn@Wd^T), all bf16 in/out.
// One wave per 16 rows; 24 x mfma_f32_16x16x32_bf16; zero LDS.
// ---------------------------------------------------------------------------
__global__ __launch_bounds__(256) void gemm_tanh_mfma(
    const unsigned short* __restrict__ hbin,
    const unsigned short* __restrict__ mupb, const unsigned short* __restrict__ mdnb,
    const unsigned short* __restrict__ Wb,   // [3][64][64] bf16 for this layer
    unsigned short* __restrict__ hbout, int E, int nblk16)
{
    int wid  = (blockIdx.x * 256 + threadIdx.x) >> 6;
    if (wid >= nblk16) return;
    int lane = threadIdx.x & 63;
    int lg = lane >> 4;      // 0..3
    int lr = lane & 15;      // 0..15

    bf16x8 bfr[3][4][2];
    #pragma unroll
    for (int m = 0; m < 3; ++m)
        #pragma unroll
        for (int jt = 0; jt < 4; ++jt)
            #pragma unroll
            for (int ks = 0; ks < 2; ++ks)
                bfr[m][jt][ks] = *(const bf16x8*)(Wb + m * 4096 + (jt * 16 + lr) * 64 + ks * 32 + lg * 8);

    int base = wid * 16;
    int arow = base + lr;
    bool ok = (arow < E);
    size_t aoff = (size_t)arow * H64 + lg * 8;

    bf16x8 afr[3][2];
    bf16x8 zz = {0, 0, 0, 0, 0, 0, 0, 0};
    #pragma unroll
    for (int ks = 0; ks < 2; ++ks) {
        afr[0][ks] = ok ? *(const bf16x8*)(hbin + aoff + ks * 32) : zz;
        afr[1][ks] = ok ? *(const bf16x8*)(mupb + aoff + ks * 32) : zz;
        afr[2][ks] = ok ? *(const bf16x8*)(mdnb + aoff + ks * 32) : zz;
    }

    f32x4 acc[4];
    #pragma unroll
    for (int jt = 0; jt < 4; ++jt) acc[jt] = (f32x4){0.f, 0.f, 0.f, 0.f};

    #pragma unroll
    for (int m = 0; m < 3; ++m)
        #pragma unroll
        for (int ks = 0; ks < 2; ++ks)
            #pragma unroll
            for (int jt = 0; jt < 4; ++jt)
                acc[jt] = __builtin_amdgcn_mfma_f32_16x16x32_bf16(
                    afr[m][ks], bfr[m][jt][ks], acc[jt], 0, 0, 0);

    #pragma unroll
    for (int jt = 0; jt < 4; ++jt) {
        #pragma unroll
        for (int reg = 0; reg < 4; ++reg) {
            int row = base + lg * 4 + reg;
            if (row < E) {
                float v = acc[jt][reg];
                float e2 = __expf(2.f * v);
                float val = 1.f - 2.f / (e2 + 1.f);
                hbout[(size_t)row * H64 + jt * 16 + lr] = f2bf(val);
            }
        }
    }
}

// ---------------------------------------------------------------------------
// pooled[batch[i]] += |h[i]| over sorted batch; h in bf16
// ---------------------------------------------------------------------------
#define ROWS_PER_WAVE 64
__global__ __launch_bounds__(256) void pool_kernel(
    const unsigned short* __restrict__ hb, const int* __restrict__ batch,
    float* __restrict__ pooled, int E)
{
    int wave = (int)((blockIdx.x * 256 + threadIdx.x) >> 6);
    int j = threadIdx.x & 63;
    int row0 = wave * ROWS_PER_WAVE;
    if (row0 >= E) return;
    int row1 = min(row0 + ROWS_PER_WAVE, E);

    int cur = batch[row0];
    float acc = 0.f;
    for (int i = row0; i < row1; ++i) {
        int b = batch[i];
        if (b != cur) {
            atomicAdd(&pooled[(size_t)cur * H64 + j], acc);
            acc = 0.f;
            cur = b;
        }
        unsigned u = hb[(size_t)i * H64 + j];
        acc += fabsf(__uint_as_float(u << 16));
    }
    atomicAdd(&pooled[(size_t)cur * H64 + j], acc);
}

// ---------------------------------------------------------------------------
__global__ __launch_bounds__(64) void head_kernel(
    const float* __restrict__ pooled,
    const float* __restrict__ lin1_w, const float* __restrict__ lin1_b,
    const float* __restrict__ lin2_w, const float* __restrict__ lin2_b,
    float* __restrict__ out, int C)
{
    __shared__ float p[64];
    __shared__ float z[64];
    int b = blockIdx.x;
    int t = threadIdx.x;

    p[t] = pooled[(size_t)b * H64 + t];
    __syncthreads();

    float acc = lin1_b[t];
    #pragma unroll
    for (int k = 0; k < 64; ++k) acc += p[k] * lin1_w[t * 64 + k];
    z[t] = fmaxf(acc, 0.f);
    __syncthreads();

    if (t < C) {
        float o = lin2_b[t];
        #pragma unroll
        for (int k = 0; k < 64; ++k) o += z[k] * lin2_w[t * 64 + k];
        out[(size_t)b * C + t] = o;
    }
}

// ---------------------------------------------------------------------------
extern "C" void kernel_launch(void* const* d_in, const int* in_sizes, int n_in,
                              void* d_out, int out_size, void* d_ws, size_t ws_size,
                              hipStream_t stream)
{
    const float* x          = (const float*)d_in[0];
    const int*   up_index   = (const int*)  d_in[1];
    const float* up_orient  = (const float*)d_in[2];
    const int*   down_index = (const int*)  d_in[3];
    const float* down_orient= (const float*)d_in[4];
    const int*   batch      = (const int*)  d_in[5];
    const float* W_up       = (const float*)d_in[6];
    const float* W_down     = (const float*)d_in[7];
    const float* W_self     = (const float*)d_in[8];
    const float* lin1_w     = (const float*)d_in[9];
    const float* lin1_b     = (const float*)d_in[10];
    const float* lin2_w     = (const float*)d_in[11];
    const float* lin2_b     = (const float*)d_in[12];
    float* out = (float*)d_out;

    const int E    = in_sizes[0] / H64;
    const int NADJ = in_sizes[1] / 2;
    const int C    = in_sizes[11] / H64;
    const int B    = out_size / C;
    const int L    = in_sizes[6] / (H64 * H64);

    // ---- workspace layout ----
    unsigned short* hb      = (unsigned short*)d_ws;              // E*64 bf16
    unsigned short* mupb    = hb   + (size_t)E * H64;             // E*64 bf16
    unsigned short* mdnb    = mupb + (size_t)E * H64;             // E*64 bf16
    float*          pooled  = (float*)(mdnb + (size_t)E * H64);   // B*64 f32
    int*            end2    = (int*)(pooled + (size_t)B * H64);   // 2E
    int*            deg2    = end2 + (size_t)2 * E;               // 2E (fallback)
    int*            bsums   = deg2 + (size_t)2 * E;               // 1024 (fallback)
    int*            bktcnt  = bsums + 1024;                       // NBKT_MAX
    int*            gcur    = bktcnt + NBKT_MAX;                  // NBKT_MAX
    int*            bstart  = gcur + NBKT_MAX;                    // NBKT_MAX+1
    unsigned short* Wb      = (unsigned short*)(bstart + NBKT_MAX + 1); // L*3*4096 bf16
    unsigned*       packed2 = (unsigned*)(Wb + (size_t)L * 3 * 4096);   // 2*NADJ
    unsigned*       binned  = packed2 + (size_t)2 * NADJ;         // 2*NADJ

    const int n2    = 2 * E;
    const int nbkt  = (n2 + RPB - 1) >> RPB_SH;
    const int total = 2 * NADJ;
    const int gather_blocks = (int)(((long long)E * 64 + 255) / 256);
    const int conv_blocks   = (int)(((long long)E * H64 / 4 + 255) / 256);
    const int nblk16        = (E + 15) / 16;
    const int gemm_blocks   = (nblk16 + 3) / 4;
    const int convw_blocks  = (L * 3 * 4096 + 255) / 256;
    const int pool_waves    = (E + ROWS_PER_WAVE - 1) / ROWS_PER_WAVE;
    const int pool_blocks   = (pool_waves + 3) / 4;

    // ---- CSR build ----
    if (nbkt <= NBKT_MAX) {
        const int bc_blocks = (total + BC_CHUNK - 1) / BC_CHUNK;
        const int r1_blocks = (total + R1_CHUNK - 1) / R1_CHUNK;
        hipMemsetAsync(bktcnt, 0, (size_t)NBKT_MAX * sizeof(int), stream);
        bcount_kernel<<<bc_blocks, 256, 0, stream>>>(up_index + NADJ, down_index + NADJ,
                                                     bktcnt, NADJ, E, nbkt);
        bscan_kernel<<<1, 256, 0, stream>>>(bktcnt, bstart, gcur, nbkt, total);
        bin_kernel<<<r1_blocks, 256, 0, stream>>>(up_index, up_orient, down_index, down_orient,
                                                  gcur, binned, NADJ, E, nbkt);
        csr_fill2_kernel<<<nbkt, 256, 0, stream>>>(binned, bstart, end2, packed2, n2);
    } else {
        const int both_blocks = (total + 255) / 256;
        const int nscan = (n2 + SCAN_TILE - 1) / SCAN_TILE;
        hipMemsetAsync(deg2, 0, (size_t)n2 * sizeof(int), stream);
        hist2_kernel<<<both_blocks, 256, 0, stream>>>(up_index + NADJ, down_index + NADJ, deg2, NADJ, E);
        scan_partial<<<nscan, 256, 0, stream>>>(deg2, bsums, n2);
        scan_bsums_k<<<1, 256, 0, stream>>>(bsums, nscan);
        scan_final<<<nscan, 256, 0, stream>>>(deg2, bsums, end2, n2);
        reorder2_kernel<<<both_blocks, 256, 0, stream>>>(up_index, up_orient, down_index, down_orient,
                                                         end2, packed2, NADJ, E);
    }

    // ---- bf16 conversions ----
    conv_bf16_kernel<<<conv_blocks, 256, 0, stream>>>(x, hb, (size_t)E * H64);
    convW_kernel<<<convw_blocks, 256, 0, stream>>>(W_self, W_up, W_down, Wb, L);

    // ---- layers (all state in hb, bf16) ----
    for (int l = 0; l < L; ++l) {
        gather_kernel<<<gather_blocks, 256, 0, stream>>>(
            (const unsigned*)hb, end2, packed2,
            (unsigned*)mupb, (unsigned*)mdnb, E);
        gemm_tanh_mfma<<<gemm_blocks, 256, 0, stream>>>(
            hb, mupb, mdnb, Wb + (size_t)l * 3 * 4096, hb, E, nblk16);
    }

    // ---- readout ----
    hipMemsetAsync(pooled, 0, (size_t)B * H64 * sizeof(float), stream);
    pool_kernel<<<pool_blocks, 256, 0, stream>>>(hb, batch, pooled, E);
    head_kernel<<<B, 64, 0, stream>>>(pooled, lin1_w, lin1_b, lin2_w, lin2_b, out, C);
}

// Round 10
// 770.192 us; speedup vs baseline: 1.0943x; 1.0140x over previous
//
#include <hip/hip_runtime.h>
#include <hip/hip_bf16.h>

#define H64 64
typedef float float4a __attribute__((ext_vector_type(4)));
typedef float f32x4  __attribute__((ext_vector_type(4)));
typedef short bf16x8 __attribute__((ext_vector_type(8)));

__device__ __forceinline__ unsigned short f2bf(float x) {
    unsigned b = __float_as_uint(x);
    unsigned r = (b + 0x7fffu + ((b >> 16) & 1u)) >> 16;
    return (unsigned short)r;
}

#define SCAN_B 256

// ---------------------------------------------------------------------------
// Binned CSR build over concatenated row space [0,2E): U rows [0,E), D [E,2E)
// entry packing in binned: [sign:1][src:21][dst_low:10]
// packed2 final:           [sign:1][src:31]
// ---------------------------------------------------------------------------
#define RPB       1024
#define RPB_SH    10
#define NBKT_MAX  512
#define R1_CHUNK  8192
#define BC_CHUNK  16384

__global__ __launch_bounds__(256) void bcount_kernel(
    const int* __restrict__ up_dst, const int* __restrict__ dn_dst,
    int* __restrict__ bktcnt, int nadj, int E, int nbkt)
{
    __shared__ int lc[NBKT_MAX];
    int t = threadIdx.x;
    for (int i = t; i < nbkt; i += 256) lc[i] = 0;
    __syncthreads();
    long long base = (long long)blockIdx.x * BC_CHUNK;
    long long total = 2LL * nadj;
    for (int i = 0; i < BC_CHUNK / 256; ++i) {
        long long g = base + i * 256 + t;
        if (g < total) {
            int dst2 = (g < nadj) ? up_dst[(int)g] : E + dn_dst[(int)(g - nadj)];
            atomicAdd(&lc[dst2 >> RPB_SH], 1);
        }
    }
    __syncthreads();
    for (int i = t; i < nbkt; i += 256) {
        int c = lc[i];
        if (c) atomicAdd(&bktcnt[i], c);
    }
}

__global__ __launch_bounds__(256) void bscan_kernel(
    const int* __restrict__ bktcnt, int* __restrict__ bstart, int* __restrict__ gcur,
    int nbkt, int total)
{
    __shared__ int s[SCAN_B];
    int t = threadIdx.x;
    int i0 = t * 2;
    int v0 = (i0     < nbkt) ? bktcnt[i0]     : 0;
    int v1 = (i0 + 1 < nbkt) ? bktcnt[i0 + 1] : 0;
    int tsum = v0 + v1;
    s[t] = tsum; __syncthreads();
    for (int off = 1; off < SCAN_B; off <<= 1) {
        int add = (t >= off) ? s[t - off] : 0;
        int cur = s[t];
        __syncthreads();
        s[t] = cur + add;
        __syncthreads();
    }
    int excl = s[t] - tsum;
    if (i0     < nbkt) { bstart[i0]     = excl;      gcur[i0]     = excl; }
    if (i0 + 1 < nbkt) { bstart[i0 + 1] = excl + v0; gcur[i0 + 1] = excl + v0; }
    if (t == 0) bstart[nbkt] = total;
}

__global__ __launch_bounds__(256) void bin_kernel(
    const int* __restrict__ up_index, const float* __restrict__ up_orient,
    const int* __restrict__ dn_index, const float* __restrict__ dn_orient,
    int* __restrict__ gcur, unsigned* __restrict__ binned,
    int nadj, int E, int nbkt)
{
    __shared__ unsigned sval[R1_CHUNK];
    __shared__ unsigned short sbkt[R1_CHUNK];
    __shared__ int lcnt[NBKT_MAX];
    __shared__ int goff[NBKT_MAX];
    __shared__ int lrank[NBKT_MAX];

    int t = threadIdx.x;
    for (int b = t; b < nbkt; b += 256) lcnt[b] = 0;
    __syncthreads();

    long long base = (long long)blockIdx.x * R1_CHUNK;
    int total = 2 * nadj;
    #pragma unroll 4
    for (int i = 0; i < R1_CHUNK / 256; ++i) {
        long long g = base + i * 256 + t;
        int li = i * 256 + t;
        if (g < total) {
            int src, dst2; float orient;
            if (g < nadj) {
                int e = (int)g;
                src = up_index[e]; dst2 = up_index[nadj + e]; orient = up_orient[e];
            } else {
                int e = (int)(g - nadj);
                src = dn_index[e]; dst2 = E + dn_index[nadj + e]; orient = dn_orient[e];
            }
            unsigned v = ((unsigned)src << RPB_SH) | (unsigned)(dst2 & (RPB - 1))
                       | (orient < 0.f ? 0x80000000u : 0u);
            int bk = dst2 >> RPB_SH;
            sval[li] = v;
            sbkt[li] = (unsigned short)bk;
            atomicAdd(&lcnt[bk], 1);
        } else {
            sbkt[li] = 0xFFFFu;
        }
    }
    __syncthreads();
    for (int b = t; b < nbkt; b += 256) {
        int c = lcnt[b];
        lrank[b] = 0;
        if (c > 0) goff[b] = atomicAdd(&gcur[b], c);
    }
    __syncthreads();
    #pragma unroll 4
    for (int i = 0; i < R1_CHUNK / 256; ++i) {
        int li = i * 256 + t;
        unsigned short bk = sbkt[li];
        if (bk != 0xFFFFu) {
            int r = atomicAdd(&lrank[bk], 1);
            binned[goff[bk] + r] = sval[li];
        }
    }
}

// per-bucket exact CSR placement; all per-row atomics in LDS.
// after this kernel, end2[d] == global row_end(d).
__global__ __launch_bounds__(256) void csr_fill2_kernel(
    const unsigned* __restrict__ binned, const int* __restrict__ bstart,
    int* __restrict__ end2, unsigned* __restrict__ packed2, int n2)
{
    __shared__ int lh[RPB];
    __shared__ int lcur[RPB];
    __shared__ int s[SCAN_B];
    int b = blockIdx.x;
    int t = threadIdx.x;
    int s0 = bstart[b], s1 = bstart[b + 1];
    int dbase = b << RPB_SH;

    for (int i = t; i < RPB; i += 256) lh[i] = 0;
    __syncthreads();
    for (int i = s0 + t; i < s1; i += 256) {
        unsigned v = binned[i];
        atomicAdd(&lh[v & (RPB - 1)], 1);
    }
    __syncthreads();

    int i0 = t * 4;
    int c0 = lh[i0], c1 = lh[i0 + 1], c2 = lh[i0 + 2], c3 = lh[i0 + 3];
    int tsum = c0 + c1 + c2 + c3;
    s[t] = tsum; __syncthreads();
    for (int off = 1; off < SCAN_B; off <<= 1) {
        int add = (t >= off) ? s[t - off] : 0;
        int cur = s[t];
        __syncthreads();
        s[t] = cur + add;
        __syncthreads();
    }
    int excl = s[t] - tsum;
    lcur[i0]     = excl;
    lcur[i0 + 1] = excl + c0;
    lcur[i0 + 2] = excl + c0 + c1;
    lcur[i0 + 3] = excl + c0 + c1 + c2;
    int gd = dbase + i0;
    if (gd     < n2) end2[gd]     = s0 + excl + c0;
    if (gd + 1 < n2) end2[gd + 1] = s0 + excl + c0 + c1;
    if (gd + 2 < n2) end2[gd + 2] = s0 + excl + c0 + c1 + c2;
    if (gd + 3 < n2) end2[gd + 3] = s0 + excl + tsum;
    __syncthreads();

    for (int i = s0 + t; i < s1; i += 256) {
        unsigned v = binned[i];
        int d = (int)(v & (RPB - 1));
        int p = atomicAdd(&lcur[d], 1);
        packed2[s0 + p] = (v & 0x80000000u) | ((v >> RPB_SH) & 0x1FFFFFu);
    }
}

// ---------------------------------------------------------------------------
// fallback path (only if nbkt > NBKT_MAX)
// ---------------------------------------------------------------------------
#define SCAN_TILE 1024

__global__ __launch_bounds__(256) void hist2_kernel(
    const int* __restrict__ up_dst, const int* __restrict__ dn_dst,
    int* __restrict__ deg2, int nadj, int E)
{
    int g = blockIdx.x * 256 + threadIdx.x;
    if (g < nadj) {
        atomicAdd(&deg2[up_dst[g]], 1);
    } else {
        int e = g - nadj;
        if (e < nadj) atomicAdd(&deg2[E + dn_dst[e]], 1);
    }
}

__global__ __launch_bounds__(256) void scan_partial(
    const int* __restrict__ deg, int* __restrict__ bsums, int n)
{
    __shared__ int s[SCAN_B];
    int t = threadIdx.x;
    int i0 = blockIdx.x * SCAN_TILE + t * 4;
    int sum = 0;
    if (i0 + 3 < n) {
        int4 v = *(const int4*)(deg + i0);
        sum = v.x + v.y + v.z + v.w;
    } else {
        for (int k = 0; k < 4; ++k) if (i0 + k < n) sum += deg[i0 + k];
    }
    s[t] = sum; __syncthreads();
    for (int off = 128; off > 0; off >>= 1) {
        if (t < off) s[t] += s[t + off];
        __syncthreads();
    }
    if (t == 0) bsums[blockIdx.x] = s[0];
}

__global__ __launch_bounds__(256) void scan_bsums_k(int* bsums, int nblk)
{
    __shared__ int s[SCAN_B];
    int t = threadIdx.x;
    int i0 = t * 4;
    int v0 = 0, v1 = 0, v2 = 0, v3 = 0;
    if (i0     < nblk) v0 = bsums[i0];
    if (i0 + 1 < nblk) v1 = bsums[i0 + 1];
    if (i0 + 2 < nblk) v2 = bsums[i0 + 2];
    if (i0 + 3 < nblk) v3 = bsums[i0 + 3];
    int tsum = v0 + v1 + v2 + v3;
    s[t] = tsum; __syncthreads();
    for (int off = 1; off < SCAN_B; off <<= 1) {
        int add = (t >= off) ? s[t - off] : 0;
        int cur = s[t];
        __syncthreads();
        s[t] = cur + add;
        __syncthreads();
    }
    int excl = s[t] - tsum;
    if (i0     < nblk) bsums[i0]     = excl;
    if (i0 + 1 < nblk) bsums[i0 + 1] = excl + v0;
    if (i0 + 2 < nblk) bsums[i0 + 2] = excl + v0 + v1;
    if (i0 + 3 < nblk) bsums[i0 + 3] = excl + v0 + v1 + v2;
}

__global__ __launch_bounds__(256) void scan_final(
    const int* __restrict__ deg, const int* __restrict__ bsums,
    int* __restrict__ outx, int n)
{
    __shared__ int s[SCAN_B];
    int t = threadIdx.x;
    int i0 = blockIdx.x * SCAN_TILE + t * 4;
    int v0 = 0, v1 = 0, v2 = 0, v3 = 0;
    if (i0 + 3 < n) {
        int4 v = *(const int4*)(deg + i0);
        v0 = v.x; v1 = v.y; v2 = v.z; v3 = v.w;
    } else {
        if (i0     < n) v0 = deg[i0];
        if (i0 + 1 < n) v1 = deg[i0 + 1];
        if (i0 + 2 < n) v2 = deg[i0 + 2];
        if (i0 + 3 < n) v3 = deg[i0 + 3];
    }
    int tsum = v0 + v1 + v2 + v3;
    s[t] = tsum; __syncthreads();
    for (int off = 1; off < SCAN_B; off <<= 1) {
        int add = (t >= off) ? s[t - off] : 0;
        int cur = s[t];
        __syncthreads();
        s[t] = cur + add;
        __syncthreads();
    }
    int excl = s[t] - tsum;
    int base = bsums[blockIdx.x] + excl;
    if (i0     < n) outx[i0]     = base;
    if (i0 + 1 < n) outx[i0 + 1] = base + v0;
    if (i0 + 2 < n) outx[i0 + 2] = base + v0 + v1;
    if (i0 + 3 < n) outx[i0 + 3] = base + v0 + v1 + v2;
}

__global__ __launch_bounds__(256) void reorder2_kernel(
    const int* __restrict__ up_index, const float* __restrict__ up_orient,
    const int* __restrict__ dn_index, const float* __restrict__ dn_orient,
    int* __restrict__ end2, unsigned* __restrict__ packed2, int nadj, int E)
{
    int g = blockIdx.x * 256 + threadIdx.x;
    if (g < nadj) {
        int src = up_index[g];
        int dst = up_index[nadj + g];
        int p = atomicAdd(&end2[dst], 1);
        packed2[p] = (unsigned)src | (up_orient[g] < 0.f ? 0x80000000u : 0u);
    } else {
        int e = g - nadj;
        if (e < nadj) {
            int src = dn_index[e];
            int dst = dn_index[nadj + e];
            int p = atomicAdd(&end2[E + dst], 1);
            packed2[p] = (unsigned)src | (dn_orient[e] < 0.f ? 0x80000000u : 0u);
        }
    }
}

// ---------------------------------------------------------------------------
// f32 -> bf16 conversions
// ---------------------------------------------------------------------------
__global__ __launch_bounds__(256) void conv_bf16_kernel(
    const float* __restrict__ x, unsigned short* __restrict__ hb, size_t n)
{
    size_t i = ((size_t)blockIdx.x * 256 + threadIdx.x) * 4;
    if (i + 3 < n) {
        float4a v = *(const float4a*)(x + i);
        uint2 o;
        o.x = (unsigned)f2bf(v[0]) | ((unsigned)f2bf(v[1]) << 16);
        o.y = (unsigned)f2bf(v[2]) | ((unsigned)f2bf(v[3]) << 16);
        *(uint2*)(hb + i) = o;
    } else {
        for (size_t k = i; k < n; ++k) hb[k] = f2bf(x[k]);
    }
}

// Wb layout: [l][mat(0=self,1=up,2=dn)][j][k] bf16
__global__ __launch_bounds__(256) void convW_kernel(
    const float* __restrict__ Ws, const float* __restrict__ Wu,
    const float* __restrict__ Wd, unsigned short* __restrict__ Wb, int L)
{
    int i = blockIdx.x * 256 + threadIdx.x;
    int total = L * 3 * 4096;
    if (i >= total) return;
    int l = i / (3 * 4096);
    int m = (i / 4096) % 3;
    int r = i & 4095;
    const float* src = (m == 0) ? Ws : ((m == 1) ? Wu : Wd);
    Wb[i] = f2bf(src[l * 4096 + r]);
}

// ---------------------------------------------------------------------------
// gather (pair-vectorized, deep-unrolled, lean VALU): wave per dst row; lane
// loads uint (2 bf16 feats); lanes 0-31 even entries, 32-63 odd.
// Address: byte offset = (p<<7) + fp*4  (sign bit shifts out; src < 2^18)
//   -> one v_lshl_add_u32 + saddr global_load (no 64-bit math).
// Sign: +/-1.0 cndmask feeding 2 fma (no mask build / xor).
// Main block: 16 entries = 8 independent loads in flight; then 8; then
// branchless tail (sgn = 0 for invalid).
// ---------------------------------------------------------------------------
__device__ __forceinline__ void seg_sum2(
    const char* __restrict__ hbase, const unsigned* __restrict__ packed2,
    int s0, int s1, unsigned fp4, int g, int lane, float& r0, float& r1)
{
    float a0 = 0.f, a1 = 0.f;
    for (int b = s0; b < s1; b += 64) {
        int cnt = min(64, s1 - b);
        unsigned pk = (lane < cnt) ? packed2[b + lane] : 0u;
        int n = 0;
        for (; n + 16 <= cnt; n += 16) {
            unsigned p[8], u[8];
            #pragma unroll
            for (int t = 0; t < 8; ++t) p[t] = __shfl(pk, n + 2 * t + g);
            #pragma unroll
            for (int t = 0; t < 8; ++t)
                u[t] = *(const unsigned*)(hbase + ((p[t] << 7) + fp4));
            #pragma unroll
            for (int t = 0; t < 8; ++t) {
                float sgn = ((int)p[t] < 0) ? -1.f : 1.f;
                a0 = fmaf(__uint_as_float(u[t] << 16),         sgn, a0);
                a1 = fmaf(__uint_as_float(u[t] & 0xFFFF0000u), sgn, a1);
            }
        }
        for (; n + 8 <= cnt; n += 8) {
            unsigned p[4], u[4];
            #pragma unroll
            for (int t = 0; t < 4; ++t) p[t] = __shfl(pk, n + 2 * t + g);
            #pragma unroll
            for (int t = 0; t < 4; ++t)
                u[t] = *(const unsigned*)(hbase + ((p[t] << 7) + fp4));
            #pragma unroll
            for (int t = 0; t < 4; ++t) {
                float sgn = ((int)p[t] < 0) ? -1.f : 1.f;
                a0 = fmaf(__uint_as_float(u[t] << 16),         sgn, a0);
                a1 = fmaf(__uint_as_float(u[t] & 0xFFFF0000u), sgn, a1);
            }
        }
        for (; n < cnt; n += 2) {
            int idx = n + g;
            unsigned pe = __shfl(pk, min(idx, cnt - 1));
            float sgn = (idx < cnt) ? (((int)pe < 0) ? -1.f : 1.f) : 0.f;
            unsigned u = *(const unsigned*)(hbase + ((pe << 7) + fp4));
            a0 = fmaf(__uint_as_float(u << 16),         sgn, a0);
            a1 = fmaf(__uint_as_float(u & 0xFFFF0000u), sgn, a1);
        }
    }
    r0 = a0; r1 = a1;
}

__global__ __launch_bounds__(256) void gather_kernel(
    const unsigned* __restrict__ hb32,
    const int* __restrict__ end2, const unsigned* __restrict__ packed2,
    unsigned* __restrict__ mup32, unsigned* __restrict__ mdn32, int E)
{
    int dst = (int)((blockIdx.x * 256u + threadIdx.x) >> 6);
    if (dst >= E) return;
    int lane = threadIdx.x & 63;
    int g  = lane >> 5;
    unsigned fp = lane & 31;
    unsigned fp4 = fp * 4;
    const char* hbase = (const char*)hb32;

    int s0U = (dst == 0) ? 0 : end2[dst - 1];
    int s1U = end2[dst];
    float u0, u1;
    seg_sum2(hbase, packed2, s0U, s1U, fp4, g, lane, u0, u1);

    int s0D = end2[E + dst - 1];
    int s1D = end2[E + dst];
    float d0, d1;
    seg_sum2(hbase, packed2, s0D, s1D, fp4, g, lane, d0, d1);

    u0 += __shfl_xor(u0, 32); u1 += __shfl_xor(u1, 32);
    d0 += __shfl_xor(d0, 32); d1 += __shfl_xor(d1, 32);

    unsigned valU = (unsigned)f2bf(u0) | ((unsigned)f2bf(u1) << 16);
    unsigned valD = (unsigned)f2bf(d0) | ((unsigned)f2bf(d1) << 16);
    unsigned* ptr = g ? mdn32 : mup32;
    ptr[(size_t)dst * 32 + fp] = g ? valD : valU;
}

// ---------------------------------------------------------------------------
// MFMA gemm+tanh: hb = tanh(hb@Ws^T + mup@Wu^T + mdn@Wd^T), all bf16 in/out.
// One wave per 16 rows; 24 x mfma_f32_16x16x32_bf16; zero LDS.
// ---------------------------------------------------------------------------
__global__ __launch_bounds__(256) void gemm_tanh_mfma(
    const unsigned short* __restrict__ hbin,
    const unsigned short* __restrict__ mupb, const unsigned short* __restrict__ mdnb,
    const unsigned short* __restrict__ Wb,   // [3][64][64] bf16 for this layer
    unsigned short* __restrict__ hbout, int E, int nblk16)
{
    int wid  = (blockIdx.x * 256 + threadIdx.x) >> 6;
    if (wid >= nblk16) return;
    int lane = threadIdx.x & 63;
    int lg = lane >> 4;      // 0..3
    int lr = lane & 15;      // 0..15

    bf16x8 bfr[3][4][2];
    #pragma unroll
    for (int m = 0; m < 3; ++m)
        #pragma unroll
        for (int jt = 0; jt < 4; ++jt)
            #pragma unroll
            for (int ks = 0; ks < 2; ++ks)
                bfr[m][jt][ks] = *(const bf16x8*)(Wb + m * 4096 + (jt * 16 + lr) * 64 + ks * 32 + lg * 8);

    int base = wid * 16;
    int arow = base + lr;
    bool ok = (arow < E);
    size_t aoff = (size_t)arow * H64 + lg * 8;

    bf16x8 afr[3][2];
    bf16x8 zz = {0, 0, 0, 0, 0, 0, 0, 0};
    #pragma unroll
    for (int ks = 0; ks < 2; ++ks) {
        afr[0][ks] = ok ? *(const bf16x8*)(hbin + aoff + ks * 32) : zz;
        afr[1][ks] = ok ? *(const bf16x8*)(mupb + aoff + ks * 32) : zz;
        afr[2][ks] = ok ? *(const bf16x8*)(mdnb + aoff + ks * 32) : zz;
    }

    f32x4 acc[4];
    #pragma unroll
    for (int jt = 0; jt < 4; ++jt) acc[jt] = (f32x4){0.f, 0.f, 0.f, 0.f};

    #pragma unroll
    for (int m = 0; m < 3; ++m)
        #pragma unroll
        for (int ks = 0; ks < 2; ++ks)
            #pragma unroll
            for (int jt = 0; jt < 4; ++jt)
                acc[jt] = __builtin_amdgcn_mfma_f32_16x16x32_bf16(
                    afr[m][ks], bfr[m][jt][ks], acc[jt], 0, 0, 0);

    #pragma unroll
    for (int jt = 0; jt < 4; ++jt) {
        #pragma unroll
        for (int reg = 0; reg < 4; ++reg) {
            int row = base + lg * 4 + reg;
            if (row < E) {
                float v = acc[jt][reg];
                float e2 = __expf(2.f * v);
                float val = 1.f - 2.f / (e2 + 1.f);
                hbout[(size_t)row * H64 + jt * 16 + lr] = f2bf(val);
            }
        }
    }
}

// ---------------------------------------------------------------------------
// pooled[batch[i]] += |h[i]| over sorted batch; h in bf16
// ---------------------------------------------------------------------------
#define ROWS_PER_WAVE 64
__global__ __launch_bounds__(256) void pool_kernel(
    const unsigned short* __restrict__ hb, const int* __restrict__ batch,
    float* __restrict__ pooled, int E)
{
    int wave = (int)((blockIdx.x * 256 + threadIdx.x) >> 6);
    int j = threadIdx.x & 63;
    int row0 = wave * ROWS_PER_WAVE;
    if (row0 >= E) return;
    int row1 = min(row0 + ROWS_PER_WAVE, E);

    int cur = batch[row0];
    float acc = 0.f;
    for (int i = row0; i < row1; ++i) {
        int b = batch[i];
        if (b != cur) {
            atomicAdd(&pooled[(size_t)cur * H64 + j], acc);
            acc = 0.f;
            cur = b;
        }
        unsigned u = hb[(size_t)i * H64 + j];
        acc += fabsf(__uint_as_float(u << 16));
    }
    atomicAdd(&pooled[(size_t)cur * H64 + j], acc);
}

// ---------------------------------------------------------------------------
__global__ __launch_bounds__(64) void head_kernel(
    const float* __restrict__ pooled,
    const float* __restrict__ lin1_w, const float* __restrict__ lin1_b,
    const float* __restrict__ lin2_w, const float* __restrict__ lin2_b,
    float* __restrict__ out, int C)
{
    __shared__ float p[64];
    __shared__ float z[64];
    int b = blockIdx.x;
    int t = threadIdx.x;

    p[t] = pooled[(size_t)b * H64 + t];
    __syncthreads();

    float acc = lin1_b[t];
    #pragma unroll
    for (int k = 0; k < 64; ++k) acc += p[k] * lin1_w[t * 64 + k];
    z[t] = fmaxf(acc, 0.f);
    __syncthreads();

    if (t < C) {
        float o = lin2_b[t];
        #pragma unroll
        for (int k = 0; k < 64; ++k) o += z[k] * lin2_w[t * 64 + k];
        out[(size_t)b * C + t] = o;
    }
}

// ---------------------------------------------------------------------------
extern "C" void kernel_launch(void* const* d_in, const int* in_sizes, int n_in,
                              void* d_out, int out_size, void* d_ws, size_t ws_size,
                              hipStream_t stream)
{
    const float* x          = (const float*)d_in[0];
    const int*   up_index   = (const int*)  d_in[1];
    const float* up_orient  = (const float*)d_in[2];
    const int*   down_index = (const int*)  d_in[3];
    const float* down_orient= (const float*)d_in[4];
    const int*   batch      = (const int*)  d_in[5];
    const float* W_up       = (const float*)d_in[6];
    const float* W_down     = (const float*)d_in[7];
    const float* W_self     = (const float*)d_in[8];
    const float* lin1_w     = (const float*)d_in[9];
    const float* lin1_b     = (const float*)d_in[10];
    const float* lin2_w     = (const float*)d_in[11];
    const float* lin2_b     = (const float*)d_in[12];
    float* out = (float*)d_out;

    const int E    = in_sizes[0] / H64;
    const int NADJ = in_sizes[1] / 2;
    const int C    = in_sizes[11] / H64;
    const int B    = out_size / C;
    const int L    = in_sizes[6] / (H64 * H64);

    // ---- workspace layout ----
    unsigned short* hb      = (unsigned short*)d_ws;              // E*64 bf16
    unsigned short* mupb    = hb   + (size_t)E * H64;             // E*64 bf16
    unsigned short* mdnb    = mupb + (size_t)E * H64;             // E*64 bf16
    float*          pooled  = (float*)(mdnb + (size_t)E * H64);   // B*64 f32
    int*            end2    = (int*)(pooled + (size_t)B * H64);   // 2E
    int*            deg2    = end2 + (size_t)2 * E;               // 2E (fallback)
    int*            bsums   = deg2 + (size_t)2 * E;               // 1024 (fallback)
    int*            bktcnt  = bsums + 1024;                       // NBKT_MAX
    int*            gcur    = bktcnt + NBKT_MAX;                  // NBKT_MAX
    int*            bstart  = gcur + NBKT_MAX;                    // NBKT_MAX+1
    unsigned short* Wb      = (unsigned short*)(bstart + NBKT_MAX + 1); // L*3*4096 bf16
    unsigned*       packed2 = (unsigned*)(Wb + (size_t)L * 3 * 4096);   // 2*NADJ
    unsigned*       binned  = packed2 + (size_t)2 * NADJ;         // 2*NADJ

    const int n2    = 2 * E;
    const int nbkt  = (n2 + RPB - 1) >> RPB_SH;
    const int total = 2 * NADJ;
    const int gather_blocks = (int)(((long long)E * 64 + 255) / 256);
    const int conv_blocks   = (int)(((long long)E * H64 / 4 + 255) / 256);
    const int nblk16        = (E + 15) / 16;
    const int gemm_blocks   = (nblk16 + 3) / 4;
    const int convw_blocks  = (L * 3 * 4096 + 255) / 256;
    const int pool_waves    = (E + ROWS_PER_WAVE - 1) / ROWS_PER_WAVE;
    const int pool_blocks   = (pool_waves + 3) / 4;

    // ---- CSR build ----
    if (nbkt <= NBKT_MAX) {
        const int bc_blocks = (total + BC_CHUNK - 1) / BC_CHUNK;
        const int r1_blocks = (total + R1_CHUNK - 1) / R1_CHUNK;
        hipMemsetAsync(bktcnt, 0, (size_t)NBKT_MAX * sizeof(int), stream);
        bcount_kernel<<<bc_blocks, 256, 0, stream>>>(up_index + NADJ, down_index + NADJ,
                                                     bktcnt, NADJ, E, nbkt);
        bscan_kernel<<<1, 256, 0, stream>>>(bktcnt, bstart, gcur, nbkt, total);
        bin_kernel<<<r1_blocks, 256, 0, stream>>>(up_index, up_orient, down_index, down_orient,
                                                  gcur, binned, NADJ, E, nbkt);
        csr_fill2_kernel<<<nbkt, 256, 0, stream>>>(binned, bstart, end2, packed2, n2);
    } else {
        const int both_blocks = (total + 255) / 256;
        const int nscan = (n2 + SCAN_TILE - 1) / SCAN_TILE;
        hipMemsetAsync(deg2, 0, (size_t)n2 * sizeof(int), stream);
        hist2_kernel<<<both_blocks, 256, 0, stream>>>(up_index + NADJ, down_index + NADJ, deg2, NADJ, E);
        scan_partial<<<nscan, 256, 0, stream>>>(deg2, bsums, n2);
        scan_bsums_k<<<1, 256, 0, stream>>>(bsums, nscan);
        scan_final<<<nscan, 256, 0, stream>>>(deg2, bsums, end2, n2);
        reorder2_kernel<<<both_blocks, 256, 0, stream>>>(up_index, up_orient, down_index, down_orient,
                                                         end2, packed2, NADJ, E);
    }

    // ---- bf16 conversions ----
    conv_bf16_kernel<<<conv_blocks, 256, 0, stream>>>(x, hb, (size_t)E * H64);
    convW_kernel<<<convw_blocks, 256, 0, stream>>>(W_self, W_up, W_down, Wb, L);

    // ---- layers (all state in hb, bf16) ----
    for (int l = 0; l < L; ++l) {
        gather_kernel<<<gather_blocks, 256, 0, stream>>>(
            (const unsigned*)hb, end2, packed2,
            (unsigned*)mupb, (unsigned*)mdnb, E);
        gemm_tanh_mfma<<<gemm_blocks, 256, 0, stream>>>(
            hb, mupb, mdnb, Wb + (size_t)l * 3 * 4096, hb, E, nblk16);
    }

    // ---- readout ----
    hipMemsetAsync(pooled, 0, (size_t)B * H64 * sizeof(float), stream);
    pool_kernel<<<pool_blocks, 256, 0, stream>>>(hb, batch, pooled, E);
    head_kernel<<<B, 64, 0, stream>>>(pooled, lin1_w, lin1_b, lin2_w, lin2_b, out, C);
}

// Round 11
// 731.507 us; speedup vs baseline: 1.1521x; 1.0529x over previous
//
#include <hip/hip_runtime.h>
#include <hip/hip_bf16.h>

#define H64 64
typedef float float4a __attribute__((ext_vector_type(4)));
typedef float f32x4  __attribute__((ext_vector_type(4)));
typedef short bf16x8 __attribute__((ext_vector_type(8)));

__device__ __forceinline__ unsigned short f2bf(float x) {
    unsigned b = __float_as_uint(x);
    unsigned r = (b + 0x7fffu + ((b >> 16) & 1u)) >> 16;
    return (unsigned short)r;
}

#define SCAN_B 256

// ---------------------------------------------------------------------------
// Binned CSR build over concatenated row space [0,2E): U rows [0,E), D [E,2E)
// entry packing in binned: [sign:1][src:21][dst_low:9]
// packed2 final:           [sign:1][src:31]
// ---------------------------------------------------------------------------
#define RPB       512
#define RPB_SH    9
#define NBKT_MAX  1024
#define R1_CHUNK  8192
#define BC_CHUNK  16384

__global__ __launch_bounds__(256) void bcount_kernel(
    const int* __restrict__ up_dst, const int* __restrict__ dn_dst,
    int* __restrict__ bktcnt, int nadj, int E, int nbkt)
{
    __shared__ int lc[NBKT_MAX];
    int t = threadIdx.x;
    for (int i = t; i < nbkt; i += 256) lc[i] = 0;
    __syncthreads();
    long long base = (long long)blockIdx.x * BC_CHUNK;
    long long total = 2LL * nadj;
    for (int i = 0; i < BC_CHUNK / 256; ++i) {
        long long g = base + i * 256 + t;
        if (g < total) {
            int dst2 = (g < nadj) ? up_dst[(int)g] : E + dn_dst[(int)(g - nadj)];
            atomicAdd(&lc[dst2 >> RPB_SH], 1);
        }
    }
    __syncthreads();
    for (int i = t; i < nbkt; i += 256) {
        int c = lc[i];
        if (c) atomicAdd(&bktcnt[i], c);
    }
}

// scan of up to 1024 bucket counts (4 per thread)
__global__ __launch_bounds__(256) void bscan_kernel(
    const int* __restrict__ bktcnt, int* __restrict__ bstart, int* __restrict__ gcur,
    int nbkt, int total)
{
    __shared__ int s[SCAN_B];
    int t = threadIdx.x;
    int i0 = t * 4;
    int v0 = (i0     < nbkt) ? bktcnt[i0]     : 0;
    int v1 = (i0 + 1 < nbkt) ? bktcnt[i0 + 1] : 0;
    int v2 = (i0 + 2 < nbkt) ? bktcnt[i0 + 2] : 0;
    int v3 = (i0 + 3 < nbkt) ? bktcnt[i0 + 3] : 0;
    int tsum = v0 + v1 + v2 + v3;
    s[t] = tsum; __syncthreads();
    for (int off = 1; off < SCAN_B; off <<= 1) {
        int add = (t >= off) ? s[t - off] : 0;
        int cur = s[t];
        __syncthreads();
        s[t] = cur + add;
        __syncthreads();
    }
    int excl = s[t] - tsum;
    if (i0     < nbkt) { bstart[i0]     = excl;                gcur[i0]     = excl; }
    if (i0 + 1 < nbkt) { bstart[i0 + 1] = excl + v0;           gcur[i0 + 1] = excl + v0; }
    if (i0 + 2 < nbkt) { bstart[i0 + 2] = excl + v0 + v1;      gcur[i0 + 2] = excl + v0 + v1; }
    if (i0 + 3 < nbkt) { bstart[i0 + 3] = excl + v0 + v1 + v2; gcur[i0 + 3] = excl + v0 + v1 + v2; }
    if (t == 0) bstart[nbkt] = total;
}

__global__ __launch_bounds__(256) void bin_kernel(
    const int* __restrict__ up_index, const float* __restrict__ up_orient,
    const int* __restrict__ dn_index, const float* __restrict__ dn_orient,
    int* __restrict__ gcur, unsigned* __restrict__ binned,
    int nadj, int E, int nbkt)
{
    __shared__ unsigned sval[R1_CHUNK];
    __shared__ unsigned short sbkt[R1_CHUNK];
    __shared__ int lcnt[NBKT_MAX];
    __shared__ int goff[NBKT_MAX];
    __shared__ int lrank[NBKT_MAX];

    int t = threadIdx.x;
    for (int b = t; b < nbkt; b += 256) lcnt[b] = 0;
    __syncthreads();

    long long base = (long long)blockIdx.x * R1_CHUNK;
    int total = 2 * nadj;
    #pragma unroll 4
    for (int i = 0; i < R1_CHUNK / 256; ++i) {
        long long g = base + i * 256 + t;
        int li = i * 256 + t;
        if (g < total) {
            int src, dst2; float orient;
            if (g < nadj) {
                int e = (int)g;
                src = up_index[e]; dst2 = up_index[nadj + e]; orient = up_orient[e];
            } else {
                int e = (int)(g - nadj);
                src = dn_index[e]; dst2 = E + dn_index[nadj + e]; orient = dn_orient[e];
            }
            unsigned v = ((unsigned)src << RPB_SH) | (unsigned)(dst2 & (RPB - 1))
                       | (orient < 0.f ? 0x80000000u : 0u);
            int bk = dst2 >> RPB_SH;
            sval[li] = v;
            sbkt[li] = (unsigned short)bk;
            atomicAdd(&lcnt[bk], 1);
        } else {
            sbkt[li] = 0xFFFFu;
        }
    }
    __syncthreads();
    for (int b = t; b < nbkt; b += 256) {
        int c = lcnt[b];
        lrank[b] = 0;
        if (c > 0) goff[b] = atomicAdd(&gcur[b], c);
    }
    __syncthreads();
    #pragma unroll 4
    for (int i = 0; i < R1_CHUNK / 256; ++i) {
        int li = i * 256 + t;
        unsigned short bk = sbkt[li];
        if (bk != 0xFFFFu) {
            int r = atomicAdd(&lrank[bk], 1);
            binned[goff[bk] + r] = sval[li];
        }
    }
}

// per-bucket exact CSR placement; all per-row atomics in LDS.
// after this kernel, end2[d] == global row_end(d).
__global__ __launch_bounds__(256) void csr_fill2_kernel(
    const unsigned* __restrict__ binned, const int* __restrict__ bstart,
    int* __restrict__ end2, unsigned* __restrict__ packed2, int n2)
{
    __shared__ int lh[RPB];
    __shared__ int lcur[RPB];
    __shared__ int s[SCAN_B];
    int b = blockIdx.x;
    int t = threadIdx.x;
    int s0 = bstart[b], s1 = bstart[b + 1];
    int dbase = b << RPB_SH;

    for (int i = t; i < RPB; i += 256) lh[i] = 0;
    __syncthreads();
    for (int i = s0 + t; i < s1; i += 256) {
        unsigned v = binned[i];
        atomicAdd(&lh[v & (RPB - 1)], 1);
    }
    __syncthreads();

    int i0 = t * 2;
    int c0 = lh[i0], c1 = lh[i0 + 1];
    int tsum = c0 + c1;
    s[t] = tsum; __syncthreads();
    for (int off = 1; off < SCAN_B; off <<= 1) {
        int add = (t >= off) ? s[t - off] : 0;
        int cur = s[t];
        __syncthreads();
        s[t] = cur + add;
        __syncthreads();
    }
    int excl = s[t] - tsum;
    lcur[i0]     = excl;
    lcur[i0 + 1] = excl + c0;
    int gd = dbase + i0;
    if (gd     < n2) end2[gd]     = s0 + excl + c0;
    if (gd + 1 < n2) end2[gd + 1] = s0 + excl + tsum;
    __syncthreads();

    for (int i = s0 + t; i < s1; i += 256) {
        unsigned v = binned[i];
        int d = (int)(v & (RPB - 1));
        int p = atomicAdd(&lcur[d], 1);
        packed2[s0 + p] = (v & 0x80000000u) | ((v >> RPB_SH) & 0x1FFFFFu);
    }
}

// ---------------------------------------------------------------------------
// fallback path (only if nbkt > NBKT_MAX)
// ---------------------------------------------------------------------------
#define SCAN_TILE 1024

__global__ __launch_bounds__(256) void hist2_kernel(
    const int* __restrict__ up_dst, const int* __restrict__ dn_dst,
    int* __restrict__ deg2, int nadj, int E)
{
    int g = blockIdx.x * 256 + threadIdx.x;
    if (g < nadj) {
        atomicAdd(&deg2[up_dst[g]], 1);
    } else {
        int e = g - nadj;
        if (e < nadj) atomicAdd(&deg2[E + dn_dst[e]], 1);
    }
}

__global__ __launch_bounds__(256) void scan_partial(
    const int* __restrict__ deg, int* __restrict__ bsums, int n)
{
    __shared__ int s[SCAN_B];
    int t = threadIdx.x;
    int i0 = blockIdx.x * SCAN_TILE + t * 4;
    int sum = 0;
    if (i0 + 3 < n) {
        int4 v = *(const int4*)(deg + i0);
        sum = v.x + v.y + v.z + v.w;
    } else {
        for (int k = 0; k < 4; ++k) if (i0 + k < n) sum += deg[i0 + k];
    }
    s[t] = sum; __syncthreads();
    for (int off = 128; off > 0; off >>= 1) {
        if (t < off) s[t] += s[t + off];
        __syncthreads();
    }
    if (t == 0) bsums[blockIdx.x] = s[0];
}

__global__ __launch_bounds__(256) void scan_bsums_k(int* bsums, int nblk)
{
    __shared__ int s[SCAN_B];
    int t = threadIdx.x;
    int i0 = t * 4;
    int v0 = 0, v1 = 0, v2 = 0, v3 = 0;
    if (i0     < nblk) v0 = bsums[i0];
    if (i0 + 1 < nblk) v1 = bsums[i0 + 1];
    if (i0 + 2 < nblk) v2 = bsums[i0 + 2];
    if (i0 + 3 < nblk) v3 = bsums[i0 + 3];
    int tsum = v0 + v1 + v2 + v3;
    s[t] = tsum; __syncthreads();
    for (int off = 1; off < SCAN_B; off <<= 1) {
        int add = (t >= off) ? s[t - off] : 0;
        int cur = s[t];
        __syncthreads();
        s[t] = cur + add;
        __syncthreads();
    }
    int excl = s[t] - tsum;
    if (i0     < nblk) bsums[i0]     = excl;
    if (i0 + 1 < nblk) bsums[i0 + 1] = excl + v0;
    if (i0 + 2 < nblk) bsums[i0 + 2] = excl + v0 + v1;
    if (i0 + 3 < nblk) bsums[i0 + 3] = excl + v0 + v1 + v2;
}

__global__ __launch_bounds__(256) void scan_final(
    const int* __restrict__ deg, const int* __restrict__ bsums,
    int* __restrict__ outx, int n)
{
    __shared__ int s[SCAN_B];
    int t = threadIdx.x;
    int i0 = blockIdx.x * SCAN_TILE + t * 4;
    int v0 = 0, v1 = 0, v2 = 0, v3 = 0;
    if (i0 + 3 < n) {
        int4 v = *(const int4*)(deg + i0);
        v0 = v.x; v1 = v.y; v2 = v.z; v3 = v.w;
    } else {
        if (i0     < n) v0 = deg[i0];
        if (i0 + 1 < n) v1 = deg[i0 + 1];
        if (i0 + 2 < n) v2 = deg[i0 + 2];
        if (i0 + 3 < n) v3 = deg[i0 + 3];
    }
    int tsum = v0 + v1 + v2 + v3;
    s[t] = tsum; __syncthreads();
    for (int off = 1; off < SCAN_B; off <<= 1) {
        int add = (t >= off) ? s[t - off] : 0;
        int cur = s[t];
        __syncthreads();
        s[t] = cur + add;
        __syncthreads();
    }
    int excl = s[t] - tsum;
    int base = bsums[blockIdx.x] + excl;
    if (i0     < n) outx[i0]     = base;
    if (i0 + 1 < n) outx[i0 + 1] = base + v0;
    if (i0 + 2 < n) outx[i0 + 2] = base + v0 + v1;
    if (i0 + 3 < n) outx[i0 + 3] = base + v0 + v1 + v2;
}

__global__ __launch_bounds__(256) void reorder2_kernel(
    const int* __restrict__ up_index, const float* __restrict__ up_orient,
    const int* __restrict__ dn_index, const float* __restrict__ dn_orient,
    int* __restrict__ end2, unsigned* __restrict__ packed2, int nadj, int E)
{
    int g = blockIdx.x * 256 + threadIdx.x;
    if (g < nadj) {
        int src = up_index[g];
        int dst = up_index[nadj + g];
        int p = atomicAdd(&end2[dst], 1);
        packed2[p] = (unsigned)src | (up_orient[g] < 0.f ? 0x80000000u : 0u);
    } else {
        int e = g - nadj;
        if (e < nadj) {
            int src = dn_index[e];
            int dst = dn_index[nadj + e];
            int p = atomicAdd(&end2[E + dst], 1);
            packed2[p] = (unsigned)src | (dn_orient[e] < 0.f ? 0x80000000u : 0u);
        }
    }
}

// ---------------------------------------------------------------------------
// f32 -> bf16 conversions
// ---------------------------------------------------------------------------
__global__ __launch_bounds__(256) void conv_bf16_kernel(
    const float* __restrict__ x, unsigned short* __restrict__ hb, size_t n)
{
    size_t i = ((size_t)blockIdx.x * 256 + threadIdx.x) * 4;
    if (i + 3 < n) {
        float4a v = *(const float4a*)(x + i);
        uint2 o;
        o.x = (unsigned)f2bf(v[0]) | ((unsigned)f2bf(v[1]) << 16);
        o.y = (unsigned)f2bf(v[2]) | ((unsigned)f2bf(v[3]) << 16);
        *(uint2*)(hb + i) = o;
    } else {
        for (size_t k = i; k < n; ++k) hb[k] = f2bf(x[k]);
    }
}

// Wb layout: [l][mat(0=self,1=up,2=dn)][j][k] bf16
__global__ __launch_bounds__(256) void convW_kernel(
    const float* __restrict__ Ws, const float* __restrict__ Wu,
    const float* __restrict__ Wd, unsigned short* __restrict__ Wb, int L)
{
    int i = blockIdx.x * 256 + threadIdx.x;
    int total = L * 3 * 4096;
    if (i >= total) return;
    int l = i / (3 * 4096);
    int m = (i / 4096) % 3;
    int r = i & 4095;
    const float* src = (m == 0) ? Ws : ((m == 1) ? Wu : Wd);
    Wb[i] = f2bf(src[l * 4096 + r]);
}

// ---------------------------------------------------------------------------
// gather: wave per dst row; lanes 0-31 even entries, 32-63 odd (uint = 2 bf16
// feats per lane). FAST PATH (deg<=64 both segs): load both pk upfront, then
// one branchless loop issuing 4 U-loads + 4 D-loads per iteration (8 random
// rows continuously in flight; clamped entries re-hit L1, sgn=0).
// ---------------------------------------------------------------------------
__device__ __forceinline__ void seg_sum2_slow(
    const unsigned* __restrict__ hb32, const unsigned* __restrict__ packed2,
    int s0, int s1, unsigned fp, int g, int lane, float& r0, float& r1)
{
    float a0 = 0.f, a1 = 0.f;
    for (int b = s0; b < s1; b += 64) {
        int cnt = min(64, s1 - b);
        unsigned pk = (lane < cnt) ? packed2[b + lane] : 0u;
        for (int n = 0; n < cnt; n += 2) {
            int idx = n + g;
            unsigned pe = __shfl(pk, min(idx, cnt - 1));
            float sgn = (idx < cnt) ? (((int)pe < 0) ? -1.f : 1.f) : 0.f;
            unsigned u = hb32[(pe << 5) + fp];
            a0 = fmaf(__uint_as_float(u << 16),         sgn, a0);
            a1 = fmaf(__uint_as_float(u & 0xFFFF0000u), sgn, a1);
        }
    }
    r0 = a0; r1 = a1;
}

__global__ __launch_bounds__(256) void gather_kernel(
    const unsigned* __restrict__ hb32,
    const int* __restrict__ end2, const unsigned* __restrict__ packed2,
    unsigned* __restrict__ mup32, unsigned* __restrict__ mdn32, int E)
{
    int dst = (int)((blockIdx.x * 256u + threadIdx.x) >> 6);
    if (dst >= E) return;
    int lane = threadIdx.x & 63;
    int g  = lane >> 5;
    unsigned fp = lane & 31;

    int s0U = (dst == 0) ? 0 : end2[dst - 1];
    int s1U = end2[dst];
    int s0D = end2[E + dst - 1];
    int s1D = end2[E + dst];
    int cntU = s1U - s0U, cntD = s1D - s0D;

    float u0, u1, d0, d1;
    if (cntU <= 64 && cntD <= 64) {
        int limU = max(cntU - 1, 0), limD = max(cntD - 1, 0);
        unsigned pkU = (cntU > 0) ? packed2[s0U + min(lane, limU)] : 0u;
        unsigned pkD = (cntD > 0) ? packed2[s0D + min(lane, limD)] : 0u;
        float a0 = 0.f, a1 = 0.f, b0 = 0.f, b1 = 0.f;
        int nmax = max(cntU, cntD);
        for (int n = 0; n < nmax; n += 8) {
            unsigned pU[4], pD[4], vU[4], vD[4];
            float sU[4], sD[4];
            #pragma unroll
            for (int t = 0; t < 4; ++t) {
                int idx = n + 2 * t + g;
                pU[t] = __shfl(pkU, min(idx, limU));
                pD[t] = __shfl(pkD, min(idx, limD));
                sU[t] = (idx < cntU) ? (((int)pU[t] < 0) ? -1.f : 1.f) : 0.f;
                sD[t] = (idx < cntD) ? (((int)pD[t] < 0) ? -1.f : 1.f) : 0.f;
            }
            #pragma unroll
            for (int t = 0; t < 4; ++t) vU[t] = hb32[(pU[t] << 5) + fp];
            #pragma unroll
            for (int t = 0; t < 4; ++t) vD[t] = hb32[(pD[t] << 5) + fp];
            #pragma unroll
            for (int t = 0; t < 4; ++t) {
                a0 = fmaf(__uint_as_float(vU[t] << 16),         sU[t], a0);
                a1 = fmaf(__uint_as_float(vU[t] & 0xFFFF0000u), sU[t], a1);
                b0 = fmaf(__uint_as_float(vD[t] << 16),         sD[t], b0);
                b1 = fmaf(__uint_as_float(vD[t] & 0xFFFF0000u), sD[t], b1);
            }
        }
        u0 = a0; u1 = a1; d0 = b0; d1 = b1;
    } else {
        seg_sum2_slow(hb32, packed2, s0U, s1U, fp, g, lane, u0, u1);
        seg_sum2_slow(hb32, packed2, s0D, s1D, fp, g, lane, d0, d1);
    }

    u0 += __shfl_xor(u0, 32); u1 += __shfl_xor(u1, 32);
    d0 += __shfl_xor(d0, 32); d1 += __shfl_xor(d1, 32);

    unsigned valU = (unsigned)f2bf(u0) | ((unsigned)f2bf(u1) << 16);
    unsigned valD = (unsigned)f2bf(d0) | ((unsigned)f2bf(d1) << 16);
    unsigned* ptr = g ? mdn32 : mup32;
    ptr[(size_t)dst * 32 + fp] = g ? valD : valU;
}

// ---------------------------------------------------------------------------
// MFMA gemm+tanh: hb = tanh(hb@Ws^T + mup@Wu^T + mdn@Wd^T), all bf16 in/out.
// One wave per 16 rows; 24 x mfma_f32_16x16x32_bf16; zero LDS.
// ---------------------------------------------------------------------------
__global__ __launch_bounds__(256) void gemm_tanh_mfma(
    const unsigned short* __restrict__ hbin,
    const unsigned short* __restrict__ mupb, const unsigned short* __restrict__ mdnb,
    const unsigned short* __restrict__ Wb,   // [3][64][64] bf16 for this layer
    unsigned short* __restrict__ hbout, int E, int nblk16)
{
    int wid  = (blockIdx.x * 256 + threadIdx.x) >> 6;
    if (wid >= nblk16) return;
    int lane = threadIdx.x & 63;
    int lg = lane >> 4;      // 0..3
    int lr = lane & 15;      // 0..15

    bf16x8 bfr[3][4][2];
    #pragma unroll
    for (int m = 0; m < 3; ++m)
        #pragma unroll
        for (int jt = 0; jt < 4; ++jt)
            #pragma unroll
            for (int ks = 0; ks < 2; ++ks)
                bfr[m][jt][ks] = *(const bf16x8*)(Wb + m * 4096 + (jt * 16 + lr) * 64 + ks * 32 + lg * 8);

    int base = wid * 16;
    int arow = base + lr;
    bool ok = (arow < E);
    size_t aoff = (size_t)arow * H64 + lg * 8;

    bf16x8 afr[3][2];
    bf16x8 zz = {0, 0, 0, 0, 0, 0, 0, 0};
    #pragma unroll
    for (int ks = 0; ks < 2; ++ks) {
        afr[0][ks] = ok ? *(const bf16x8*)(hbin + aoff + ks * 32) : zz;
        afr[1][ks] = ok ? *(const bf16x8*)(mupb + aoff + ks * 32) : zz;
        afr[2][ks] = ok ? *(const bf16x8*)(mdnb + aoff + ks * 32) : zz;
    }

    f32x4 acc[4];
    #pragma unroll
    for (int jt = 0; jt < 4; ++jt) acc[jt] = (f32x4){0.f, 0.f, 0.f, 0.f};

    #pragma unroll
    for (int m = 0; m < 3; ++m)
        #pragma unroll
        for (int ks = 0; ks < 2; ++ks)
            #pragma unroll
            for (int jt = 0; jt < 4; ++jt)
                acc[jt] = __builtin_amdgcn_mfma_f32_16x16x32_bf16(
                    afr[m][ks], bfr[m][jt][ks], acc[jt], 0, 0, 0);

    #pragma unroll
    for (int jt = 0; jt < 4; ++jt) {
        #pragma unroll
        for (int reg = 0; reg < 4; ++reg) {
            int row = base + lg * 4 + reg;
            if (row < E) {
                float v = acc[jt][reg];
                float e2 = __expf(2.f * v);
                float val = 1.f - 2.f / (e2 + 1.f);
                hbout[(size_t)row * H64 + jt * 16 + lr] = f2bf(val);
            }
        }
    }
}

// ---------------------------------------------------------------------------
// pooled[batch[i]] += |h[i]| over sorted batch; h in bf16
// ---------------------------------------------------------------------------
#define ROWS_PER_WAVE 64
__global__ __launch_bounds__(256) void pool_kernel(
    const unsigned short* __restrict__ hb, const int* __restrict__ batch,
    float* __restrict__ pooled, int E)
{
    int wave = (int)((blockIdx.x * 256 + threadIdx.x) >> 6);
    int j = threadIdx.x & 63;
    int row0 = wave * ROWS_PER_WAVE;
    if (row0 >= E) return;
    int row1 = min(row0 + ROWS_PER_WAVE, E);

    int cur = batch[row0];
    float acc = 0.f;
    for (int i = row0; i < row1; ++i) {
        int b = batch[i];
        if (b != cur) {
            atomicAdd(&pooled[(size_t)cur * H64 + j], acc);
            acc = 0.f;
            cur = b;
        }
        unsigned u = hb[(size_t)i * H64 + j];
        acc += fabsf(__uint_as_float(u << 16));
    }
    atomicAdd(&pooled[(size_t)cur * H64 + j], acc);
}

// ---------------------------------------------------------------------------
__global__ __launch_bounds__(64) void head_kernel(
    const float* __restrict__ pooled,
    const float* __restrict__ lin1_w, const float* __restrict__ lin1_b,
    const float* __restrict__ lin2_w, const float* __restrict__ lin2_b,
    float* __restrict__ out, int C)
{
    __shared__ float p[64];
    __shared__ float z[64];
    int b = blockIdx.x;
    int t = threadIdx.x;

    p[t] = pooled[(size_t)b * H64 + t];
    __syncthreads();

    float acc = lin1_b[t];
    #pragma unroll
    for (int k = 0; k < 64; ++k) acc += p[k] * lin1_w[t * 64 + k];
    z[t] = fmaxf(acc, 0.f);
    __syncthreads();

    if (t < C) {
        float o = lin2_b[t];
        #pragma unroll
        for (int k = 0; k < 64; ++k) o += z[k] * lin2_w[t * 64 + k];
        out[(size_t)b * C + t] = o;
    }
}

// ---------------------------------------------------------------------------
extern "C" void kernel_launch(void* const* d_in, const int* in_sizes, int n_in,
                              void* d_out, int out_size, void* d_ws, size_t ws_size,
                              hipStream_t stream)
{
    const float* x          = (const float*)d_in[0];
    const int*   up_index   = (const int*)  d_in[1];
    const float* up_orient  = (const float*)d_in[2];
    const int*   down_index = (const int*)  d_in[3];
    const float* down_orient= (const float*)d_in[4];
    const int*   batch      = (const int*)  d_in[5];
    const float* W_up       = (const float*)d_in[6];
    const float* W_down     = (const float*)d_in[7];
    const float* W_self     = (const float*)d_in[8];
    const float* lin1_w     = (const float*)d_in[9];
    const float* lin1_b     = (const float*)d_in[10];
    const float* lin2_w     = (const float*)d_in[11];
    const float* lin2_b     = (const float*)d_in[12];
    float* out = (float*)d_out;

    const int E    = in_sizes[0] / H64;
    const int NADJ = in_sizes[1] / 2;
    const int C    = in_sizes[11] / H64;
    const int B    = out_size / C;
    const int L    = in_sizes[6] / (H64 * H64);

    // ---- workspace layout ----
    unsigned short* hb      = (unsigned short*)d_ws;              // E*64 bf16
    unsigned short* mupb    = hb   + (size_t)E * H64;             // E*64 bf16
    unsigned short* mdnb    = mupb + (size_t)E * H64;             // E*64 bf16
    float*          pooled  = (float*)(mdnb + (size_t)E * H64);   // B*64 f32
    int*            end2    = (int*)(pooled + (size_t)B * H64);   // 2E
    int*            deg2    = end2 + (size_t)2 * E;               // 2E (fallback)
    int*            bsums   = deg2 + (size_t)2 * E;               // 1024 (fallback)
    int*            bktcnt  = bsums + 1024;                       // NBKT_MAX
    int*            gcur    = bktcnt + NBKT_MAX;                  // NBKT_MAX
    int*            bstart  = gcur + NBKT_MAX;                    // NBKT_MAX+1
    unsigned short* Wb      = (unsigned short*)(bstart + NBKT_MAX + 1); // L*3*4096 bf16
    unsigned*       packed2 = (unsigned*)(Wb + (size_t)L * 3 * 4096);   // 2*NADJ
    unsigned*       binned  = packed2 + (size_t)2 * NADJ;         // 2*NADJ

    const int n2    = 2 * E;
    const int nbkt  = (n2 + RPB - 1) >> RPB_SH;
    const int total = 2 * NADJ;
    const int gather_blocks = (int)(((long long)E * 64 + 255) / 256);
    const int conv_blocks   = (int)(((long long)E * H64 / 4 + 255) / 256);
    const int nblk16        = (E + 15) / 16;
    const int gemm_blocks   = (nblk16 + 3) / 4;
    const int convw_blocks  = (L * 3 * 4096 + 255) / 256;
    const int pool_waves    = (E + ROWS_PER_WAVE - 1) / ROWS_PER_WAVE;
    const int pool_blocks   = (pool_waves + 3) / 4;

    // ---- CSR build ----
    if (nbkt <= NBKT_MAX) {
        const int bc_blocks = (total + BC_CHUNK - 1) / BC_CHUNK;
        const int r1_blocks = (total + R1_CHUNK - 1) / R1_CHUNK;
        hipMemsetAsync(bktcnt, 0, (size_t)NBKT_MAX * sizeof(int), stream);
        bcount_kernel<<<bc_blocks, 256, 0, stream>>>(up_index + NADJ, down_index + NADJ,
                                                     bktcnt, NADJ, E, nbkt);
        bscan_kernel<<<1, 256, 0, stream>>>(bktcnt, bstart, gcur, nbkt, total);
        bin_kernel<<<r1_blocks, 256, 0, stream>>>(up_index, up_orient, down_index, down_orient,
                                                  gcur, binned, NADJ, E, nbkt);
        csr_fill2_kernel<<<nbkt, 256, 0, stream>>>(binned, bstart, end2, packed2, n2);
    } else {
        const int both_blocks = (total + 255) / 256;
        const int nscan = (n2 + SCAN_TILE - 1) / SCAN_TILE;
        hipMemsetAsync(deg2, 0, (size_t)n2 * sizeof(int), stream);
        hist2_kernel<<<both_blocks, 256, 0, stream>>>(up_index + NADJ, down_index + NADJ, deg2, NADJ, E);
        scan_partial<<<nscan, 256, 0, stream>>>(deg2, bsums, n2);
        scan_bsums_k<<<1, 256, 0, stream>>>(bsums, nscan);
        scan_final<<<nscan, 256, 0, stream>>>(deg2, bsums, end2, n2);
        reorder2_kernel<<<both_blocks, 256, 0, stream>>>(up_index, up_orient, down_index, down_orient,
                                                         end2, packed2, NADJ, E);
    }

    // ---- bf16 conversions ----
    conv_bf16_kernel<<<conv_blocks, 256, 0, stream>>>(x, hb, (size_t)E * H64);
    convW_kernel<<<convw_blocks, 256, 0, stream>>>(W_self, W_up, W_down, Wb, L);

    // ---- layers (all state in hb, bf16) ----
    for (int l = 0; l < L; ++l) {
        gather_kernel<<<gather_blocks, 256, 0, stream>>>(
            (const unsigned*)hb, end2, packed2,
            (unsigned*)mupb, (unsigned*)mdnb, E);
        gemm_tanh_mfma<<<gemm_blocks, 256, 0, stream>>>(
            hb, mupb, mdnb, Wb + (size_t)l * 3 * 4096, hb, E, nblk16);
    }

    // ---- readout ----
    hipMemsetAsync(pooled, 0, (size_t)B * H64 * sizeof(float), stream);
    pool_kernel<<<pool_blocks, 256, 0, stream>>>(hb, batch, pooled, E);
    head_kernel<<<B, 64, 0, stream>>>(pooled, lin1_w, lin1_b, lin2_w, lin2_b, out, C);
}

// Round 12
// 713.768 us; speedup vs baseline: 1.1808x; 1.0249x over previous
//
#include <hip/hip_runtime.h>
#include <hip/hip_bf16.h>

#define H64 64
typedef float float4a __attribute__((ext_vector_type(4)));
typedef float f32x4  __attribute__((ext_vector_type(4)));
typedef short bf16x8 __attribute__((ext_vector_type(8)));

__device__ __forceinline__ unsigned short f2bf(float x) {
    unsigned b = __float_as_uint(x);
    unsigned r = (b + 0x7fffu + ((b >> 16) & 1u)) >> 16;
    return (unsigned short)r;
}

#define SCAN_B 256

// ---------------------------------------------------------------------------
// Binned CSR build over concatenated row space [0,2E): U rows [0,E), D [E,2E)
// entry packing in binned: [sign:1][src:21][dst_low:9]
// packed2 final:           [sign:1][src:31]
// ---------------------------------------------------------------------------
#define RPB       512
#define RPB_SH    9
#define NBKT_MAX  1024
#define R1_CHUNK  8192
#define BC_CHUNK  16384

__global__ __launch_bounds__(256) void bcount_kernel(
    const int* __restrict__ up_dst, const int* __restrict__ dn_dst,
    int* __restrict__ bktcnt, int nadj, int E, int nbkt)
{
    __shared__ int lc[NBKT_MAX];
    int t = threadIdx.x;
    for (int i = t; i < nbkt; i += 256) lc[i] = 0;
    __syncthreads();
    long long base = (long long)blockIdx.x * BC_CHUNK;
    long long total = 2LL * nadj;
    for (int i = 0; i < BC_CHUNK / 256; ++i) {
        long long g = base + i * 256 + t;
        if (g < total) {
            int dst2 = (g < nadj) ? up_dst[(int)g] : E + dn_dst[(int)(g - nadj)];
            atomicAdd(&lc[dst2 >> RPB_SH], 1);
        }
    }
    __syncthreads();
    for (int i = t; i < nbkt; i += 256) {
        int c = lc[i];
        if (c) atomicAdd(&bktcnt[i], c);
    }
}

__global__ __launch_bounds__(256) void bscan_kernel(
    const int* __restrict__ bktcnt, int* __restrict__ bstart, int* __restrict__ gcur,
    int nbkt, int total)
{
    __shared__ int s[SCAN_B];
    int t = threadIdx.x;
    int i0 = t * 4;
    int v0 = (i0     < nbkt) ? bktcnt[i0]     : 0;
    int v1 = (i0 + 1 < nbkt) ? bktcnt[i0 + 1] : 0;
    int v2 = (i0 + 2 < nbkt) ? bktcnt[i0 + 2] : 0;
    int v3 = (i0 + 3 < nbkt) ? bktcnt[i0 + 3] : 0;
    int tsum = v0 + v1 + v2 + v3;
    s[t] = tsum; __syncthreads();
    for (int off = 1; off < SCAN_B; off <<= 1) {
        int add = (t >= off) ? s[t - off] : 0;
        int cur = s[t];
        __syncthreads();
        s[t] = cur + add;
        __syncthreads();
    }
    int excl = s[t] - tsum;
    if (i0     < nbkt) { bstart[i0]     = excl;                gcur[i0]     = excl; }
    if (i0 + 1 < nbkt) { bstart[i0 + 1] = excl + v0;           gcur[i0 + 1] = excl + v0; }
    if (i0 + 2 < nbkt) { bstart[i0 + 2] = excl + v0 + v1;      gcur[i0 + 2] = excl + v0 + v1; }
    if (i0 + 3 < nbkt) { bstart[i0 + 3] = excl + v0 + v1 + v2; gcur[i0 + 3] = excl + v0 + v1 + v2; }
    if (t == 0) bstart[nbkt] = total;
}

__global__ __launch_bounds__(256) void bin_kernel(
    const int* __restrict__ up_index, const float* __restrict__ up_orient,
    const int* __restrict__ dn_index, const float* __restrict__ dn_orient,
    int* __restrict__ gcur, unsigned* __restrict__ binned,
    int nadj, int E, int nbkt)
{
    __shared__ unsigned sval[R1_CHUNK];
    __shared__ unsigned short sbkt[R1_CHUNK];
    __shared__ int lcnt[NBKT_MAX];
    __shared__ int goff[NBKT_MAX];
    __shared__ int lrank[NBKT_MAX];

    int t = threadIdx.x;
    for (int b = t; b < nbkt; b += 256) lcnt[b] = 0;
    __syncthreads();

    long long base = (long long)blockIdx.x * R1_CHUNK;
    int total = 2 * nadj;
    #pragma unroll 4
    for (int i = 0; i < R1_CHUNK / 256; ++i) {
        long long g = base + i * 256 + t;
        int li = i * 256 + t;
        if (g < total) {
            int src, dst2; float orient;
            if (g < nadj) {
                int e = (int)g;
                src = up_index[e]; dst2 = up_index[nadj + e]; orient = up_orient[e];
            } else {
                int e = (int)(g - nadj);
                src = dn_index[e]; dst2 = E + dn_index[nadj + e]; orient = dn_orient[e];
            }
            unsigned v = ((unsigned)src << RPB_SH) | (unsigned)(dst2 & (RPB - 1))
                       | (orient < 0.f ? 0x80000000u : 0u);
            int bk = dst2 >> RPB_SH;
            sval[li] = v;
            sbkt[li] = (unsigned short)bk;
            atomicAdd(&lcnt[bk], 1);
        } else {
            sbkt[li] = 0xFFFFu;
        }
    }
    __syncthreads();
    for (int b = t; b < nbkt; b += 256) {
        int c = lcnt[b];
        lrank[b] = 0;
        if (c > 0) goff[b] = atomicAdd(&gcur[b], c);
    }
    __syncthreads();
    #pragma unroll 4
    for (int i = 0; i < R1_CHUNK / 256; ++i) {
        int li = i * 256 + t;
        unsigned short bk = sbkt[li];
        if (bk != 0xFFFFu) {
            int r = atomicAdd(&lrank[bk], 1);
            binned[goff[bk] + r] = sval[li];
        }
    }
}

// per-bucket exact CSR placement; all per-row atomics in LDS.
// after this kernel, end2[d] == global row_end(d).
__global__ __launch_bounds__(256) void csr_fill2_kernel(
    const unsigned* __restrict__ binned, const int* __restrict__ bstart,
    int* __restrict__ end2, unsigned* __restrict__ packed2, int n2)
{
    __shared__ int lh[RPB];
    __shared__ int lcur[RPB];
    __shared__ int s[SCAN_B];
    int b = blockIdx.x;
    int t = threadIdx.x;
    int s0 = bstart[b], s1 = bstart[b + 1];
    int dbase = b << RPB_SH;

    for (int i = t; i < RPB; i += 256) lh[i] = 0;
    __syncthreads();
    for (int i = s0 + t; i < s1; i += 256) {
        unsigned v = binned[i];
        atomicAdd(&lh[v & (RPB - 1)], 1);
    }
    __syncthreads();

    int i0 = t * 2;
    int c0 = lh[i0], c1 = lh[i0 + 1];
    int tsum = c0 + c1;
    s[t] = tsum; __syncthreads();
    for (int off = 1; off < SCAN_B; off <<= 1) {
        int add = (t >= off) ? s[t - off] : 0;
        int cur = s[t];
        __syncthreads();
        s[t] = cur + add;
        __syncthreads();
    }
    int excl = s[t] - tsum;
    lcur[i0]     = excl;
    lcur[i0 + 1] = excl + c0;
    int gd = dbase + i0;
    if (gd     < n2) end2[gd]     = s0 + excl + c0;
    if (gd + 1 < n2) end2[gd + 1] = s0 + excl + tsum;
    __syncthreads();

    for (int i = s0 + t; i < s1; i += 256) {
        unsigned v = binned[i];
        int d = (int)(v & (RPB - 1));
        int p = atomicAdd(&lcur[d], 1);
        packed2[s0 + p] = (v & 0x80000000u) | ((v >> RPB_SH) & 0x1FFFFFu);
    }
}

// ---------------------------------------------------------------------------
// fallback path (only if nbkt > NBKT_MAX)
// ---------------------------------------------------------------------------
#define SCAN_TILE 1024

__global__ __launch_bounds__(256) void hist2_kernel(
    const int* __restrict__ up_dst, const int* __restrict__ dn_dst,
    int* __restrict__ deg2, int nadj, int E)
{
    int g = blockIdx.x * 256 + threadIdx.x;
    if (g < nadj) {
        atomicAdd(&deg2[up_dst[g]], 1);
    } else {
        int e = g - nadj;
        if (e < nadj) atomicAdd(&deg2[E + dn_dst[e]], 1);
    }
}

__global__ __launch_bounds__(256) void scan_partial(
    const int* __restrict__ deg, int* __restrict__ bsums, int n)
{
    __shared__ int s[SCAN_B];
    int t = threadIdx.x;
    int i0 = blockIdx.x * SCAN_TILE + t * 4;
    int sum = 0;
    if (i0 + 3 < n) {
        int4 v = *(const int4*)(deg + i0);
        sum = v.x + v.y + v.z + v.w;
    } else {
        for (int k = 0; k < 4; ++k) if (i0 + k < n) sum += deg[i0 + k];
    }
    s[t] = sum; __syncthreads();
    for (int off = 128; off > 0; off >>= 1) {
        if (t < off) s[t] += s[t + off];
        __syncthreads();
    }
    if (t == 0) bsums[blockIdx.x] = s[0];
}

__global__ __launch_bounds__(256) void scan_bsums_k(int* bsums, int nblk)
{
    __shared__ int s[SCAN_B];
    int t = threadIdx.x;
    int i0 = t * 4;
    int v0 = 0, v1 = 0, v2 = 0, v3 = 0;
    if (i0     < nblk) v0 = bsums[i0];
    if (i0 + 1 < nblk) v1 = bsums[i0 + 1];
    if (i0 + 2 < nblk) v2 = bsums[i0 + 2];
    if (i0 + 3 < nblk) v3 = bsums[i0 + 3];
    int tsum = v0 + v1 + v2 + v3;
    s[t] = tsum; __syncthreads();
    for (int off = 1; off < SCAN_B; off <<= 1) {
        int add = (t >= off) ? s[t - off] : 0;
        int cur = s[t];
        __syncthreads();
        s[t] = cur + add;
        __syncthreads();
    }
    int excl = s[t] - tsum;
    if (i0     < nblk) bsums[i0]     = excl;
    if (i0 + 1 < nblk) bsums[i0 + 1] = excl + v0;
    if (i0 + 2 < nblk) bsums[i0 + 2] = excl + v0 + v1;
    if (i0 + 3 < nblk) bsums[i0 + 3] = excl + v0 + v1 + v2;
}

__global__ __launch_bounds__(256) void scan_final(
    const int* __restrict__ deg, const int* __restrict__ bsums,
    int* __restrict__ outx, int n)
{
    __shared__ int s[SCAN_B];
    int t = threadIdx.x;
    int i0 = blockIdx.x * SCAN_TILE + t * 4;
    int v0 = 0, v1 = 0, v2 = 0, v3 = 0;
    if (i0 + 3 < n) {
        int4 v = *(const int4*)(deg + i0);
        v0 = v.x; v1 = v.y; v2 = v.z; v3 = v.w;
    } else {
        if (i0     < n) v0 = deg[i0];
        if (i0 + 1 < n) v1 = deg[i0 + 1];
        if (i0 + 2 < n) v2 = deg[i0 + 2];
        if (i0 + 3 < n) v3 = deg[i0 + 3];
    }
    int tsum = v0 + v1 + v2 + v3;
    s[t] = tsum; __syncthreads();
    for (int off = 1; off < SCAN_B; off <<= 1) {
        int add = (t >= off) ? s[t - off] : 0;
        int cur = s[t];
        __syncthreads();
        s[t] = cur + add;
        __syncthreads();
    }
    int excl = s[t] - tsum;
    int base = bsums[blockIdx.x] + excl;
    if (i0     < n) outx[i0]     = base;
    if (i0 + 1 < n) outx[i0 + 1] = base + v0;
    if (i0 + 2 < n) outx[i0 + 2] = base + v0 + v1;
    if (i0 + 3 < n) outx[i0 + 3] = base + v0 + v1 + v2;
}

__global__ __launch_bounds__(256) void reorder2_kernel(
    const int* __restrict__ up_index, const float* __restrict__ up_orient,
    const int* __restrict__ dn_index, const float* __restrict__ dn_orient,
    int* __restrict__ end2, unsigned* __restrict__ packed2, int nadj, int E)
{
    int g = blockIdx.x * 256 + threadIdx.x;
    if (g < nadj) {
        int src = up_index[g];
        int dst = up_index[nadj + g];
        int p = atomicAdd(&end2[dst], 1);
        packed2[p] = (unsigned)src | (up_orient[g] < 0.f ? 0x80000000u : 0u);
    } else {
        int e = g - nadj;
        if (e < nadj) {
            int src = dn_index[e];
            int dst = dn_index[nadj + e];
            int p = atomicAdd(&end2[E + dst], 1);
            packed2[p] = (unsigned)src | (dn_orient[e] < 0.f ? 0x80000000u : 0u);
        }
    }
}

// ---------------------------------------------------------------------------
// f32 -> bf16 conversions: x (blocks [0, conv_blocks)) and W (rest)
// Wb layout: [l][mat(0=self,1=up,2=dn)][j][k] bf16
// ---------------------------------------------------------------------------
__global__ __launch_bounds__(256) void conv_all_kernel(
    const float* __restrict__ x, unsigned short* __restrict__ hb, size_t n,
    int conv_blocks,
    const float* __restrict__ Ws, const float* __restrict__ Wu,
    const float* __restrict__ Wd, unsigned short* __restrict__ Wb, int L)
{
    if (blockIdx.x < (unsigned)conv_blocks) {
        size_t i = ((size_t)blockIdx.x * 256 + threadIdx.x) * 4;
        if (i + 3 < n) {
            float4a v = *(const float4a*)(x + i);
            uint2 o;
            o.x = (unsigned)f2bf(v[0]) | ((unsigned)f2bf(v[1]) << 16);
            o.y = (unsigned)f2bf(v[2]) | ((unsigned)f2bf(v[3]) << 16);
            *(uint2*)(hb + i) = o;
        } else {
            for (size_t k = i; k < n; ++k) hb[k] = f2bf(x[k]);
        }
    } else {
        int i = (blockIdx.x - conv_blocks) * 256 + threadIdx.x;
        int total = L * 3 * 4096;
        if (i >= total) return;
        int l = i / (3 * 4096);
        int m = (i / 4096) % 3;
        int r = i & 4095;
        const float* src = (m == 0) ? Ws : ((m == 1) ? Wu : Wd);
        Wb[i] = f2bf(src[l * 4096 + r]);
    }
}

// ---------------------------------------------------------------------------
// gather: wave per dst row; lanes 0-31 even entries, 32-63 odd (uint = 2 bf16
// feats/lane). Fast path (deg<=64 both): fused 4U+4D loop to min(cntU,cntD)
// (8 random rows in flight), then single-side remainder loops (no wasted
// clamped loads beyond the shorter segment).
// ---------------------------------------------------------------------------
__device__ __forceinline__ void seg_sum2_slow(
    const unsigned* __restrict__ hb32, const unsigned* __restrict__ packed2,
    int s0, int s1, unsigned fp, int g, int lane, float& r0, float& r1)
{
    float a0 = 0.f, a1 = 0.f;
    for (int b = s0; b < s1; b += 64) {
        int cnt = min(64, s1 - b);
        unsigned pk = (lane < cnt) ? packed2[b + lane] : 0u;
        for (int n = 0; n < cnt; n += 2) {
            int idx = n + g;
            unsigned pe = __shfl(pk, min(idx, cnt - 1));
            float sgn = (idx < cnt) ? (((int)pe < 0) ? -1.f : 1.f) : 0.f;
            unsigned u = hb32[(pe << 5) + fp];
            a0 = fmaf(__uint_as_float(u << 16),         sgn, a0);
            a1 = fmaf(__uint_as_float(u & 0xFFFF0000u), sgn, a1);
        }
    }
    r0 = a0; r1 = a1;
}

__global__ __launch_bounds__(256) void gather_kernel(
    const unsigned* __restrict__ hb32,
    const int* __restrict__ end2, const unsigned* __restrict__ packed2,
    unsigned* __restrict__ mup32, unsigned* __restrict__ mdn32, int E)
{
    int dst = (int)((blockIdx.x * 256u + threadIdx.x) >> 6);
    if (dst >= E) return;
    int lane = threadIdx.x & 63;
    int g  = lane >> 5;
    unsigned fp = lane & 31;

    int s0U = (dst == 0) ? 0 : end2[dst - 1];
    int s1U = end2[dst];
    int s0D = end2[E + dst - 1];
    int s1D = end2[E + dst];
    int cntU = s1U - s0U, cntD = s1D - s0D;

    float u0, u1, d0, d1;
    if (cntU <= 64 && cntD <= 64) {
        int limU = max(cntU - 1, 0), limD = max(cntD - 1, 0);
        unsigned pkU = (cntU > 0) ? packed2[s0U + min(lane, limU)] : 0u;
        unsigned pkD = (cntD > 0) ? packed2[s0D + min(lane, limD)] : 0u;
        float a0 = 0.f, a1 = 0.f, b0 = 0.f, b1 = 0.f;
        int nmin = min(cntU, cntD);
        int n = 0;
        for (; n < nmin; n += 8) {
            unsigned pU[4], pD[4], vU[4], vD[4];
            float sU[4], sD[4];
            #pragma unroll
            for (int t = 0; t < 4; ++t) {
                int idx = n + 2 * t + g;
                pU[t] = __shfl(pkU, min(idx, limU));
                pD[t] = __shfl(pkD, min(idx, limD));
                sU[t] = (idx < cntU) ? (((int)pU[t] < 0) ? -1.f : 1.f) : 0.f;
                sD[t] = (idx < cntD) ? (((int)pD[t] < 0) ? -1.f : 1.f) : 0.f;
            }
            #pragma unroll
            for (int t = 0; t < 4; ++t) vU[t] = hb32[(pU[t] << 5) + fp];
            #pragma unroll
            for (int t = 0; t < 4; ++t) vD[t] = hb32[(pD[t] << 5) + fp];
            #pragma unroll
            for (int t = 0; t < 4; ++t) {
                a0 = fmaf(__uint_as_float(vU[t] << 16),         sU[t], a0);
                a1 = fmaf(__uint_as_float(vU[t] & 0xFFFF0000u), sU[t], a1);
                b0 = fmaf(__uint_as_float(vD[t] << 16),         sD[t], b0);
                b1 = fmaf(__uint_as_float(vD[t] & 0xFFFF0000u), sD[t], b1);
            }
        }
        for (int q = n; q < cntU; q += 8) {
            unsigned p[4], v[4]; float sg[4];
            #pragma unroll
            for (int t = 0; t < 4; ++t) {
                int idx = q + 2 * t + g;
                p[t] = __shfl(pkU, min(idx, limU));
                sg[t] = (idx < cntU) ? (((int)p[t] < 0) ? -1.f : 1.f) : 0.f;
            }
            #pragma unroll
            for (int t = 0; t < 4; ++t) v[t] = hb32[(p[t] << 5) + fp];
            #pragma unroll
            for (int t = 0; t < 4; ++t) {
                a0 = fmaf(__uint_as_float(v[t] << 16),         sg[t], a0);
                a1 = fmaf(__uint_as_float(v[t] & 0xFFFF0000u), sg[t], a1);
            }
        }
        for (int q = n; q < cntD; q += 8) {
            unsigned p[4], v[4]; float sg[4];
            #pragma unroll
            for (int t = 0; t < 4; ++t) {
                int idx = q + 2 * t + g;
                p[t] = __shfl(pkD, min(idx, limD));
                sg[t] = (idx < cntD) ? (((int)p[t] < 0) ? -1.f : 1.f) : 0.f;
            }
            #pragma unroll
            for (int t = 0; t < 4; ++t) v[t] = hb32[(p[t] << 5) + fp];
            #pragma unroll
            for (int t = 0; t < 4; ++t) {
                b0 = fmaf(__uint_as_float(v[t] << 16),         sg[t], b0);
                b1 = fmaf(__uint_as_float(v[t] & 0xFFFF0000u), sg[t], b1);
            }
        }
        u0 = a0; u1 = a1; d0 = b0; d1 = b1;
    } else {
        seg_sum2_slow(hb32, packed2, s0U, s1U, fp, g, lane, u0, u1);
        seg_sum2_slow(hb32, packed2, s0D, s1D, fp, g, lane, d0, d1);
    }

    u0 += __shfl_xor(u0, 32); u1 += __shfl_xor(u1, 32);
    d0 += __shfl_xor(d0, 32); d1 += __shfl_xor(d1, 32);

    unsigned valU = (unsigned)f2bf(u0) | ((unsigned)f2bf(u1) << 16);
    unsigned valD = (unsigned)f2bf(d0) | ((unsigned)f2bf(d1) << 16);
    unsigned* ptr = g ? mdn32 : mup32;
    ptr[(size_t)dst * 32 + fp] = g ? valD : valU;
}

// ---------------------------------------------------------------------------
// MFMA gemm+tanh: hb = tanh(hb@Ws^T + mup@Wu^T + mdn@Wd^T), all bf16 in/out.
// One wave per 16 rows; B-frags loaded per-matrix (lower VGPR -> more waves).
// ---------------------------------------------------------------------------
__global__ __launch_bounds__(256) void gemm_tanh_mfma(
    const unsigned short* __restrict__ hbin,
    const unsigned short* __restrict__ mupb, const unsigned short* __restrict__ mdnb,
    const unsigned short* __restrict__ Wb,   // [3][64][64] bf16 for this layer
    unsigned short* __restrict__ hbout, int E, int nblk16)
{
    int wid  = (blockIdx.x * 256 + threadIdx.x) >> 6;
    if (wid >= nblk16) return;
    int lane = threadIdx.x & 63;
    int lg = lane >> 4;      // 0..3
    int lr = lane & 15;      // 0..15

    int base = wid * 16;
    int arow = base + lr;
    bool ok = (arow < E);
    size_t aoff = (size_t)arow * H64 + lg * 8;

    f32x4 acc[4];
    #pragma unroll
    for (int jt = 0; jt < 4; ++jt) acc[jt] = (f32x4){0.f, 0.f, 0.f, 0.f};

    bf16x8 zz = {0, 0, 0, 0, 0, 0, 0, 0};
    #pragma unroll
    for (int m = 0; m < 3; ++m) {
        const unsigned short* src = (m == 0) ? hbin : ((m == 1) ? mupb : mdnb);
        bf16x8 a0 = ok ? *(const bf16x8*)(src + aoff)      : zz;
        bf16x8 a1 = ok ? *(const bf16x8*)(src + aoff + 32) : zz;
        const unsigned short* wbase = Wb + m * 4096 + lr * 64 + lg * 8;
        #pragma unroll
        for (int jt = 0; jt < 4; ++jt) {
            bf16x8 b0 = *(const bf16x8*)(wbase + jt * 1024);
            bf16x8 b1 = *(const bf16x8*)(wbase + jt * 1024 + 32);
            acc[jt] = __builtin_amdgcn_mfma_f32_16x16x32_bf16(a0, b0, acc[jt], 0, 0, 0);
            acc[jt] = __builtin_amdgcn_mfma_f32_16x16x32_bf16(a1, b1, acc[jt], 0, 0, 0);
        }
    }

    #pragma unroll
    for (int jt = 0; jt < 4; ++jt) {
        #pragma unroll
        for (int reg = 0; reg < 4; ++reg) {
            int row = base + lg * 4 + reg;
            if (row < E) {
                float v = acc[jt][reg];
                float e2 = __expf(2.f * v);
                float val = 1.f - 2.f / (e2 + 1.f);
                hbout[(size_t)row * H64 + jt * 16 + lr] = f2bf(val);
            }
        }
    }
}

// ---------------------------------------------------------------------------
// pooled[batch[i]] += |h[i]| over sorted batch; h in bf16
// ---------------------------------------------------------------------------
#define ROWS_PER_WAVE 64
__global__ __launch_bounds__(256) void pool_kernel(
    const unsigned short* __restrict__ hb, const int* __restrict__ batch,
    float* __restrict__ pooled, int E)
{
    int wave = (int)((blockIdx.x * 256 + threadIdx.x) >> 6);
    int j = threadIdx.x & 63;
    int row0 = wave * ROWS_PER_WAVE;
    if (row0 >= E) return;
    int row1 = min(row0 + ROWS_PER_WAVE, E);

    int cur = batch[row0];
    float acc = 0.f;
    for (int i = row0; i < row1; ++i) {
        int b = batch[i];
        if (b != cur) {
            atomicAdd(&pooled[(size_t)cur * H64 + j], acc);
            acc = 0.f;
            cur = b;
        }
        unsigned u = hb[(size_t)i * H64 + j];
        acc += fabsf(__uint_as_float(u << 16));
    }
    atomicAdd(&pooled[(size_t)cur * H64 + j], acc);
}

// ---------------------------------------------------------------------------
__global__ __launch_bounds__(64) void head_kernel(
    const float* __restrict__ pooled,
    const float* __restrict__ lin1_w, const float* __restrict__ lin1_b,
    const float* __restrict__ lin2_w, const float* __restrict__ lin2_b,
    float* __restrict__ out, int C)
{
    __shared__ float p[64];
    __shared__ float z[64];
    int b = blockIdx.x;
    int t = threadIdx.x;

    p[t] = pooled[(size_t)b * H64 + t];
    __syncthreads();

    float acc = lin1_b[t];
    #pragma unroll
    for (int k = 0; k < 64; ++k) acc += p[k] * lin1_w[t * 64 + k];
    z[t] = fmaxf(acc, 0.f);
    __syncthreads();

    if (t < C) {
        float o = lin2_b[t];
        #pragma unroll
        for (int k = 0; k < 64; ++k) o += z[k] * lin2_w[t * 64 + k];
        out[(size_t)b * C + t] = o;
    }
}

// ---------------------------------------------------------------------------
extern "C" void kernel_launch(void* const* d_in, const int* in_sizes, int n_in,
                              void* d_out, int out_size, void* d_ws, size_t ws_size,
                              hipStream_t stream)
{
    const float* x          = (const float*)d_in[0];
    const int*   up_index   = (const int*)  d_in[1];
    const float* up_orient  = (const float*)d_in[2];
    const int*   down_index = (const int*)  d_in[3];
    const float* down_orient= (const float*)d_in[4];
    const int*   batch      = (const int*)  d_in[5];
    const float* W_up       = (const float*)d_in[6];
    const float* W_down     = (const float*)d_in[7];
    const float* W_self     = (const float*)d_in[8];
    const float* lin1_w     = (const float*)d_in[9];
    const float* lin1_b     = (const float*)d_in[10];
    const float* lin2_w     = (const float*)d_in[11];
    const float* lin2_b     = (const float*)d_in[12];
    float* out = (float*)d_out;

    const int E    = in_sizes[0] / H64;
    const int NADJ = in_sizes[1] / 2;
    const int C    = in_sizes[11] / H64;
    const int B    = out_size / C;
    const int L    = in_sizes[6] / (H64 * H64);

    // ---- workspace layout ----
    unsigned short* hb      = (unsigned short*)d_ws;              // E*64 bf16
    unsigned short* mupb    = hb   + (size_t)E * H64;             // E*64 bf16
    unsigned short* mdnb    = mupb + (size_t)E * H64;             // E*64 bf16
    float*          pooled  = (float*)(mdnb + (size_t)E * H64);   // B*64 f32
    int*            end2    = (int*)(pooled + (size_t)B * H64);   // 2E
    int*            deg2    = end2 + (size_t)2 * E;               // 2E (fallback)
    int*            bsums   = deg2 + (size_t)2 * E;               // 1024 (fallback)
    int*            bktcnt  = bsums + 1024;                       // NBKT_MAX
    int*            gcur    = bktcnt + NBKT_MAX;                  // NBKT_MAX
    int*            bstart  = gcur + NBKT_MAX;                    // NBKT_MAX+1
    unsigned short* Wb      = (unsigned short*)(bstart + NBKT_MAX + 1); // L*3*4096 bf16
    unsigned*       packed2 = (unsigned*)(Wb + (size_t)L * 3 * 4096);   // 2*NADJ
    unsigned*       binned  = packed2 + (size_t)2 * NADJ;         // 2*NADJ

    const int n2    = 2 * E;
    const int nbkt  = (n2 + RPB - 1) >> RPB_SH;
    const int total = 2 * NADJ;
    const int gather_blocks = (int)(((long long)E * 64 + 255) / 256);
    const int conv_blocks   = (int)(((long long)E * H64 / 4 + 255) / 256);
    const int convw_blocks  = (L * 3 * 4096 + 255) / 256;
    const int nblk16        = (E + 15) / 16;
    const int gemm_blocks   = (nblk16 + 3) / 4;
    const int pool_waves    = (E + ROWS_PER_WAVE - 1) / ROWS_PER_WAVE;
    const int pool_blocks   = (pool_waves + 3) / 4;

    // ---- CSR build ----
    if (nbkt <= NBKT_MAX) {
        const int bc_blocks = (total + BC_CHUNK - 1) / BC_CHUNK;
        const int r1_blocks = (total + R1_CHUNK - 1) / R1_CHUNK;
        hipMemsetAsync(bktcnt, 0, (size_t)NBKT_MAX * sizeof(int), stream);
        bcount_kernel<<<bc_blocks, 256, 0, stream>>>(up_index + NADJ, down_index + NADJ,
                                                     bktcnt, NADJ, E, nbkt);
        bscan_kernel<<<1, 256, 0, stream>>>(bktcnt, bstart, gcur, nbkt, total);
        bin_kernel<<<r1_blocks, 256, 0, stream>>>(up_index, up_orient, down_index, down_orient,
                                                  gcur, binned, NADJ, E, nbkt);
        csr_fill2_kernel<<<nbkt, 256, 0, stream>>>(binned, bstart, end2, packed2, n2);
    } else {
        const int both_blocks = (total + 255) / 256;
        const int nscan = (n2 + SCAN_TILE - 1) / SCAN_TILE;
        hipMemsetAsync(deg2, 0, (size_t)n2 * sizeof(int), stream);
        hist2_kernel<<<both_blocks, 256, 0, stream>>>(up_index + NADJ, down_index + NADJ, deg2, NADJ, E);
        scan_partial<<<nscan, 256, 0, stream>>>(deg2, bsums, n2);
        scan_bsums_k<<<1, 256, 0, stream>>>(bsums, nscan);
        scan_final<<<nscan, 256, 0, stream>>>(deg2, bsums, end2, n2);
        reorder2_kernel<<<both_blocks, 256, 0, stream>>>(up_index, up_orient, down_index, down_orient,
                                                         end2, packed2, NADJ, E);
    }

    // ---- bf16 conversions (x + weights, one kernel) ----
    conv_all_kernel<<<conv_blocks + convw_blocks, 256, 0, stream>>>(
        x, hb, (size_t)E * H64, conv_blocks, W_self, W_up, W_down, Wb, L);

    // ---- layers (all state in hb, bf16) ----
    for (int l = 0; l < L; ++l) {
        gather_kernel<<<gather_blocks, 256, 0, stream>>>(
            (const unsigned*)hb, end2, packed2,
            (unsigned*)mupb, (unsigned*)mdnb, E);
        gemm_tanh_mfma<<<gemm_blocks, 256, 0, stream>>>(
            hb, mupb, mdnb, Wb + (size_t)l * 3 * 4096, hb, E, nblk16);
    }

    // ---- readout ----
    hipMemsetAsync(pooled, 0, (size_t)B * H64 * sizeof(float), stream);
    pool_kernel<<<pool_blocks, 256, 0, stream>>>(hb, batch, pooled, E);
    head_kernel<<<B, 64, 0, stream>>>(pooled, lin1_w, lin1_b, lin2_w, lin2_b, out, C);
}

// Round 13
// 705.198 us; speedup vs baseline: 1.1951x; 1.0122x over previous
//
#include <hip/hip_runtime.h>
#include <hip/hip_bf16.h>

#define H64 64
typedef float float4a __attribute__((ext_vector_type(4)));
typedef float f32x4  __attribute__((ext_vector_type(4)));
typedef short bf16x8 __attribute__((ext_vector_type(8)));

__device__ __forceinline__ unsigned short f2bf(float x) {
    unsigned b = __float_as_uint(x);
    unsigned r = (b + 0x7fffu + ((b >> 16) & 1u)) >> 16;
    return (unsigned short)r;
}

#define SCAN_B 256

// ---------------------------------------------------------------------------
// Binned CSR build over concatenated row space [0,2E): U rows [0,E), D [E,2E)
// entry packing in binned: [sign:1][src:21][dst_low:9]
// packed2 final:           [sign:1][src:31]
// ---------------------------------------------------------------------------
#define RPB       512
#define RPB_SH    9
#define NBKT_MAX  1024
#define R1_CHUNK  8192
#define BC_CHUNK  16384

__global__ __launch_bounds__(256) void bcount_kernel(
    const int* __restrict__ up_dst, const int* __restrict__ dn_dst,
    int* __restrict__ bktcnt, int nadj, int E, int nbkt)
{
    __shared__ int lc[NBKT_MAX];
    int t = threadIdx.x;
    for (int i = t; i < nbkt; i += 256) lc[i] = 0;
    __syncthreads();
    long long base = (long long)blockIdx.x * BC_CHUNK;
    long long total = 2LL * nadj;
    for (int i = 0; i < BC_CHUNK / 256; ++i) {
        long long g = base + i * 256 + t;
        if (g < total) {
            int dst2 = (g < nadj) ? up_dst[(int)g] : E + dn_dst[(int)(g - nadj)];
            atomicAdd(&lc[dst2 >> RPB_SH], 1);
        }
    }
    __syncthreads();
    for (int i = t; i < nbkt; i += 256) {
        int c = lc[i];
        if (c) atomicAdd(&bktcnt[i], c);
    }
}

__global__ __launch_bounds__(256) void bscan_kernel(
    const int* __restrict__ bktcnt, int* __restrict__ bstart, int* __restrict__ gcur,
    int nbkt, int total)
{
    __shared__ int s[SCAN_B];
    int t = threadIdx.x;
    int i0 = t * 4;
    int v0 = (i0     < nbkt) ? bktcnt[i0]     : 0;
    int v1 = (i0 + 1 < nbkt) ? bktcnt[i0 + 1] : 0;
    int v2 = (i0 + 2 < nbkt) ? bktcnt[i0 + 2] : 0;
    int v3 = (i0 + 3 < nbkt) ? bktcnt[i0 + 3] : 0;
    int tsum = v0 + v1 + v2 + v3;
    s[t] = tsum; __syncthreads();
    for (int off = 1; off < SCAN_B; off <<= 1) {
        int add = (t >= off) ? s[t - off] : 0;
        int cur = s[t];
        __syncthreads();
        s[t] = cur + add;
        __syncthreads();
    }
    int excl = s[t] - tsum;
    if (i0     < nbkt) { bstart[i0]     = excl;                gcur[i0]     = excl; }
    if (i0 + 1 < nbkt) { bstart[i0 + 1] = excl + v0;           gcur[i0 + 1] = excl + v0; }
    if (i0 + 2 < nbkt) { bstart[i0 + 2] = excl + v0 + v1;      gcur[i0 + 2] = excl + v0 + v1; }
    if (i0 + 3 < nbkt) { bstart[i0 + 3] = excl + v0 + v1 + v2; gcur[i0 + 3] = excl + v0 + v1 + v2; }
    if (t == 0) bstart[nbkt] = total;
}

__global__ __launch_bounds__(256) void bin_kernel(
    const int* __restrict__ up_index, const float* __restrict__ up_orient,
    const int* __restrict__ dn_index, const float* __restrict__ dn_orient,
    int* __restrict__ gcur, unsigned* __restrict__ binned,
    int nadj, int E, int nbkt)
{
    __shared__ unsigned sval[R1_CHUNK];
    __shared__ unsigned short sbkt[R1_CHUNK];
    __shared__ int lcnt[NBKT_MAX];
    __shared__ int goff[NBKT_MAX];
    __shared__ int lrank[NBKT_MAX];

    int t = threadIdx.x;
    for (int b = t; b < nbkt; b += 256) lcnt[b] = 0;
    __syncthreads();

    long long base = (long long)blockIdx.x * R1_CHUNK;
    int total = 2 * nadj;
    #pragma unroll 4
    for (int i = 0; i < R1_CHUNK / 256; ++i) {
        long long g = base + i * 256 + t;
        int li = i * 256 + t;
        if (g < total) {
            int src, dst2; float orient;
            if (g < nadj) {
                int e = (int)g;
                src = up_index[e]; dst2 = up_index[nadj + e]; orient = up_orient[e];
            } else {
                int e = (int)(g - nadj);
                src = dn_index[e]; dst2 = E + dn_index[nadj + e]; orient = dn_orient[e];
            }
            unsigned v = ((unsigned)src << RPB_SH) | (unsigned)(dst2 & (RPB - 1))
                       | (orient < 0.f ? 0x80000000u : 0u);
            int bk = dst2 >> RPB_SH;
            sval[li] = v;
            sbkt[li] = (unsigned short)bk;
            atomicAdd(&lcnt[bk], 1);
        } else {
            sbkt[li] = 0xFFFFu;
        }
    }
    __syncthreads();
    for (int b = t; b < nbkt; b += 256) {
        int c = lcnt[b];
        lrank[b] = 0;
        if (c > 0) goff[b] = atomicAdd(&gcur[b], c);
    }
    __syncthreads();
    #pragma unroll 4
    for (int i = 0; i < R1_CHUNK / 256; ++i) {
        int li = i * 256 + t;
        unsigned short bk = sbkt[li];
        if (bk != 0xFFFFu) {
            int r = atomicAdd(&lrank[bk], 1);
            binned[goff[bk] + r] = sval[li];
        }
    }
}

// per-bucket exact CSR placement; all per-row atomics in LDS.
// after this kernel, end2[d] == global row_end(d).
__global__ __launch_bounds__(256) void csr_fill2_kernel(
    const unsigned* __restrict__ binned, const int* __restrict__ bstart,
    int* __restrict__ end2, unsigned* __restrict__ packed2, int n2)
{
    __shared__ int lh[RPB];
    __shared__ int lcur[RPB];
    __shared__ int s[SCAN_B];
    int b = blockIdx.x;
    int t = threadIdx.x;
    int s0 = bstart[b], s1 = bstart[b + 1];
    int dbase = b << RPB_SH;

    for (int i = t; i < RPB; i += 256) lh[i] = 0;
    __syncthreads();
    for (int i = s0 + t; i < s1; i += 256) {
        unsigned v = binned[i];
        atomicAdd(&lh[v & (RPB - 1)], 1);
    }
    __syncthreads();

    int i0 = t * 2;
    int c0 = lh[i0], c1 = lh[i0 + 1];
    int tsum = c0 + c1;
    s[t] = tsum; __syncthreads();
    for (int off = 1; off < SCAN_B; off <<= 1) {
        int add = (t >= off) ? s[t - off] : 0;
        int cur = s[t];
        __syncthreads();
        s[t] = cur + add;
        __syncthreads();
    }
    int excl = s[t] - tsum;
    lcur[i0]     = excl;
    lcur[i0 + 1] = excl + c0;
    int gd = dbase + i0;
    if (gd     < n2) end2[gd]     = s0 + excl + c0;
    if (gd + 1 < n2) end2[gd + 1] = s0 + excl + tsum;
    __syncthreads();

    for (int i = s0 + t; i < s1; i += 256) {
        unsigned v = binned[i];
        int d = (int)(v & (RPB - 1));
        int p = atomicAdd(&lcur[d], 1);
        packed2[s0 + p] = (v & 0x80000000u) | ((v >> RPB_SH) & 0x1FFFFFu);
    }
}

// ---------------------------------------------------------------------------
// fallback path (only if nbkt > NBKT_MAX)
// ---------------------------------------------------------------------------
#define SCAN_TILE 1024

__global__ __launch_bounds__(256) void hist2_kernel(
    const int* __restrict__ up_dst, const int* __restrict__ dn_dst,
    int* __restrict__ deg2, int nadj, int E)
{
    int g = blockIdx.x * 256 + threadIdx.x;
    if (g < nadj) {
        atomicAdd(&deg2[up_dst[g]], 1);
    } else {
        int e = g - nadj;
        if (e < nadj) atomicAdd(&deg2[E + dn_dst[e]], 1);
    }
}

__global__ __launch_bounds__(256) void scan_partial(
    const int* __restrict__ deg, int* __restrict__ bsums, int n)
{
    __shared__ int s[SCAN_B];
    int t = threadIdx.x;
    int i0 = blockIdx.x * SCAN_TILE + t * 4;
    int sum = 0;
    if (i0 + 3 < n) {
        int4 v = *(const int4*)(deg + i0);
        sum = v.x + v.y + v.z + v.w;
    } else {
        for (int k = 0; k < 4; ++k) if (i0 + k < n) sum += deg[i0 + k];
    }
    s[t] = sum; __syncthreads();
    for (int off = 128; off > 0; off >>= 1) {
        if (t < off) s[t] += s[t + off];
        __syncthreads();
    }
    if (t == 0) bsums[blockIdx.x] = s[0];
}

__global__ __launch_bounds__(256) void scan_bsums_k(int* bsums, int nblk)
{
    __shared__ int s[SCAN_B];
    int t = threadIdx.x;
    int i0 = t * 4;
    int v0 = 0, v1 = 0, v2 = 0, v3 = 0;
    if (i0     < nblk) v0 = bsums[i0];
    if (i0 + 1 < nblk) v1 = bsums[i0 + 1];
    if (i0 + 2 < nblk) v2 = bsums[i0 + 2];
    if (i0 + 3 < nblk) v3 = bsums[i0 + 3];
    int tsum = v0 + v1 + v2 + v3;
    s[t] = tsum; __syncthreads();
    for (int off = 1; off < SCAN_B; off <<= 1) {
        int add = (t >= off) ? s[t - off] : 0;
        int cur = s[t];
        __syncthreads();
        s[t] = cur + add;
        __syncthreads();
    }
    int excl = s[t] - tsum;
    if (i0     < nblk) bsums[i0]     = excl;
    if (i0 + 1 < nblk) bsums[i0 + 1] = excl + v0;
    if (i0 + 2 < nblk) bsums[i0 + 2] = excl + v0 + v1;
    if (i0 + 3 < nblk) bsums[i0 + 3] = excl + v0 + v1 + v2;
}

__global__ __launch_bounds__(256) void scan_final(
    const int* __restrict__ deg, const int* __restrict__ bsums,
    int* __restrict__ outx, int n)
{
    __shared__ int s[SCAN_B];
    int t = threadIdx.x;
    int i0 = blockIdx.x * SCAN_TILE + t * 4;
    int v0 = 0, v1 = 0, v2 = 0, v3 = 0;
    if (i0 + 3 < n) {
        int4 v = *(const int4*)(deg + i0);
        v0 = v.x; v1 = v.y; v2 = v.z; v3 = v.w;
    } else {
        if (i0     < n) v0 = deg[i0];
        if (i0 + 1 < n) v1 = deg[i0 + 1];
        if (i0 + 2 < n) v2 = deg[i0 + 2];
        if (i0 + 3 < n) v3 = deg[i0 + 3];
    }
    int tsum = v0 + v1 + v2 + v3;
    s[t] = tsum; __syncthreads();
    for (int off = 1; off < SCAN_B; off <<= 1) {
        int add = (t >= off) ? s[t - off] : 0;
        int cur = s[t];
        __syncthreads();
        s[t] = cur + add;
        __syncthreads();
    }
    int excl = s[t] - tsum;
    int base = bsums[blockIdx.x] + excl;
    if (i0     < n) outx[i0]     = base;
    if (i0 + 1 < n) outx[i0 + 1] = base + v0;
    if (i0 + 2 < n) outx[i0 + 2] = base + v0 + v1;
    if (i0 + 3 < n) outx[i0 + 3] = base + v0 + v1 + v2;
}

__global__ __launch_bounds__(256) void reorder2_kernel(
    const int* __restrict__ up_index, const float* __restrict__ up_orient,
    const int* __restrict__ dn_index, const float* __restrict__ dn_orient,
    int* __restrict__ end2, unsigned* __restrict__ packed2, int nadj, int E)
{
    int g = blockIdx.x * 256 + threadIdx.x;
    if (g < nadj) {
        int src = up_index[g];
        int dst = up_index[nadj + g];
        int p = atomicAdd(&end2[dst], 1);
        packed2[p] = (unsigned)src | (up_orient[g] < 0.f ? 0x80000000u : 0u);
    } else {
        int e = g - nadj;
        if (e < nadj) {
            int src = dn_index[e];
            int dst = dn_index[nadj + e];
            int p = atomicAdd(&end2[E + dst], 1);
            packed2[p] = (unsigned)src | (dn_orient[e] < 0.f ? 0x80000000u : 0u);
        }
    }
}

// ---------------------------------------------------------------------------
// f32 -> bf16 conversions: x (blocks [0, conv_blocks)) and W (rest)
// Wb layout: [l][mat(0=self,1=up,2=dn)][j][k] bf16
// ---------------------------------------------------------------------------
__global__ __launch_bounds__(256) void conv_all_kernel(
    const float* __restrict__ x, unsigned short* __restrict__ hb, size_t n,
    int conv_blocks,
    const float* __restrict__ Ws, const float* __restrict__ Wu,
    const float* __restrict__ Wd, unsigned short* __restrict__ Wb, int L)
{
    if (blockIdx.x < (unsigned)conv_blocks) {
        size_t i = ((size_t)blockIdx.x * 256 + threadIdx.x) * 4;
        if (i + 3 < n) {
            float4a v = *(const float4a*)(x + i);
            uint2 o;
            o.x = (unsigned)f2bf(v[0]) | ((unsigned)f2bf(v[1]) << 16);
            o.y = (unsigned)f2bf(v[2]) | ((unsigned)f2bf(v[3]) << 16);
            *(uint2*)(hb + i) = o;
        } else {
            for (size_t k = i; k < n; ++k) hb[k] = f2bf(x[k]);
        }
    } else {
        int i = (blockIdx.x - conv_blocks) * 256 + threadIdx.x;
        int total = L * 3 * 4096;
        if (i >= total) return;
        int l = i / (3 * 4096);
        int m = (i / 4096) % 3;
        int r = i & 4095;
        const float* src = (m == 0) ? Ws : ((m == 1) ? Wu : Wd);
        Wb[i] = f2bf(src[l * 4096 + r]);
    }
}

// ---------------------------------------------------------------------------
// gather: wave per dst row. 4 groups of 16 lanes; group g processes entry
// n+4t+g; each lane loads uint2 = 4 features (16 lanes x 8B = 128B/entry).
// One shfl/sgn/addr/load covers 4 entries (~3.6 VALU/entry vs 5 for pair).
// Fused U||D main loop keeps 4 loads (16 random rows) in flight; remainders
// use 2-load steps. Final: 2-level shfl_xor reduce; g0 writes mup, g1 mdn.
// ---------------------------------------------------------------------------
__device__ __forceinline__ void seg_sum4_slow(
    const unsigned* __restrict__ hb32, const unsigned* __restrict__ packed2,
    int s0, int s1, unsigned fp8, int g, int lane, float a[4])
{
    const char* hbase = (const char*)hb32;
    for (int bb = s0; bb < s1; bb += 64) {
        int cnt = min(64, s1 - bb);
        int lim = cnt - 1;
        unsigned pk = (lane < cnt) ? packed2[bb + lane] : 0u;
        for (int n = 0; n < cnt; n += 4) {
            int idx = n + g;
            unsigned pe = __shfl(pk, min(idx, lim));
            float sg = (idx < cnt) ? (((int)pe < 0) ? -1.f : 1.f) : 0.f;
            uint2 v = *(const uint2*)(hbase + ((pe << 7) + fp8));
            a[0] = fmaf(__uint_as_float(v.x << 16),         sg, a[0]);
            a[1] = fmaf(__uint_as_float(v.x & 0xFFFF0000u), sg, a[1]);
            a[2] = fmaf(__uint_as_float(v.y << 16),         sg, a[2]);
            a[3] = fmaf(__uint_as_float(v.y & 0xFFFF0000u), sg, a[3]);
        }
    }
}

__global__ __launch_bounds__(256) void gather_kernel(
    const unsigned* __restrict__ hb32,
    const int* __restrict__ end2, const unsigned* __restrict__ packed2,
    unsigned* __restrict__ mup32, unsigned* __restrict__ mdn32, int E)
{
    int dst = (int)((blockIdx.x * 256u + threadIdx.x) >> 6);
    if (dst >= E) return;
    int lane = threadIdx.x & 63;
    int g  = lane >> 4;        // 0..3 entry group
    unsigned fp = lane & 15;   // feats [4fp, 4fp+4)
    unsigned fp8 = fp * 8;     // byte offset within row
    const char* hbase = (const char*)hb32;

    int s0U = (dst == 0) ? 0 : end2[dst - 1];
    int s1U = end2[dst];
    int s0D = end2[E + dst - 1];
    int s1D = end2[E + dst];
    int cntU = s1U - s0U, cntD = s1D - s0D;

    float a[4] = {0.f, 0.f, 0.f, 0.f};
    float b[4] = {0.f, 0.f, 0.f, 0.f};

    if (cntU <= 64 && cntD <= 64) {
        int limU = max(cntU - 1, 0), limD = max(cntD - 1, 0);
        unsigned pkU = (cntU > 0) ? packed2[s0U + min(lane, limU)] : 0u;
        unsigned pkD = (cntD > 0) ? packed2[s0D + min(lane, limD)] : 0u;
        int nmin = min(cntU, cntD);
        int n = 0;
        // fused main: 2 U-loads + 2 D-loads (16 random rows in flight)
        for (; n < nmin; n += 8) {
            unsigned pU[2], pD[2]; uint2 vU[2], vD[2]; float sU[2], sD[2];
            #pragma unroll
            for (int t = 0; t < 2; ++t) {
                int idx = n + 4 * t + g;
                pU[t] = __shfl(pkU, min(idx, limU));
                pD[t] = __shfl(pkD, min(idx, limD));
                sU[t] = (idx < cntU) ? (((int)pU[t] < 0) ? -1.f : 1.f) : 0.f;
                sD[t] = (idx < cntD) ? (((int)pD[t] < 0) ? -1.f : 1.f) : 0.f;
            }
            #pragma unroll
            for (int t = 0; t < 2; ++t) vU[t] = *(const uint2*)(hbase + ((pU[t] << 7) + fp8));
            #pragma unroll
            for (int t = 0; t < 2; ++t) vD[t] = *(const uint2*)(hbase + ((pD[t] << 7) + fp8));
            #pragma unroll
            for (int t = 0; t < 2; ++t) {
                a[0] = fmaf(__uint_as_float(vU[t].x << 16),         sU[t], a[0]);
                a[1] = fmaf(__uint_as_float(vU[t].x & 0xFFFF0000u), sU[t], a[1]);
                a[2] = fmaf(__uint_as_float(vU[t].y << 16),         sU[t], a[2]);
                a[3] = fmaf(__uint_as_float(vU[t].y & 0xFFFF0000u), sU[t], a[3]);
                b[0] = fmaf(__uint_as_float(vD[t].x << 16),         sD[t], b[0]);
                b[1] = fmaf(__uint_as_float(vD[t].x & 0xFFFF0000u), sD[t], b[1]);
                b[2] = fmaf(__uint_as_float(vD[t].y << 16),         sD[t], b[2]);
                b[3] = fmaf(__uint_as_float(vD[t].y & 0xFFFF0000u), sD[t], b[3]);
            }
        }
        // U remainder: 2-load steps (8 entries)
        for (int q = n; q < cntU; q += 8) {
            unsigned p[2]; uint2 v[2]; float sg[2];
            #pragma unroll
            for (int t = 0; t < 2; ++t) {
                int idx = q + 4 * t + g;
                p[t] = __shfl(pkU, min(idx, limU));
                sg[t] = (idx < cntU) ? (((int)p[t] < 0) ? -1.f : 1.f) : 0.f;
            }
            #pragma unroll
            for (int t = 0; t < 2; ++t) v[t] = *(const uint2*)(hbase + ((p[t] << 7) + fp8));
            #pragma unroll
            for (int t = 0; t < 2; ++t) {
                a[0] = fmaf(__uint_as_float(v[t].x << 16),         sg[t], a[0]);
                a[1] = fmaf(__uint_as_float(v[t].x & 0xFFFF0000u), sg[t], a[1]);
                a[2] = fmaf(__uint_as_float(v[t].y << 16),         sg[t], a[2]);
                a[3] = fmaf(__uint_as_float(v[t].y & 0xFFFF0000u), sg[t], a[3]);
            }
        }
        // D remainder
        for (int q = n; q < cntD; q += 8) {
            unsigned p[2]; uint2 v[2]; float sg[2];
            #pragma unroll
            for (int t = 0; t < 2; ++t) {
                int idx = q + 4 * t + g;
                p[t] = __shfl(pkD, min(idx, limD));
                sg[t] = (idx < cntD) ? (((int)p[t] < 0) ? -1.f : 1.f) : 0.f;
            }
            #pragma unroll
            for (int t = 0; t < 2; ++t) v[t] = *(const uint2*)(hbase + ((p[t] << 7) + fp8));
            #pragma unroll
            for (int t = 0; t < 2; ++t) {
                b[0] = fmaf(__uint_as_float(v[t].x << 16),         sg[t], b[0]);
                b[1] = fmaf(__uint_as_float(v[t].x & 0xFFFF0000u), sg[t], b[1]);
                b[2] = fmaf(__uint_as_float(v[t].y << 16),         sg[t], b[2]);
                b[3] = fmaf(__uint_as_float(v[t].y & 0xFFFF0000u), sg[t], b[3]);
            }
        }
    } else {
        seg_sum4_slow(hb32, packed2, s0U, s1U, fp8, g, lane, a);
        seg_sum4_slow(hb32, packed2, s0D, s1D, fp8, g, lane, b);
    }

    // reduce across the 4 entry-groups
    #pragma unroll
    for (int k = 0; k < 4; ++k) {
        a[k] += __shfl_xor(a[k], 16);
        a[k] += __shfl_xor(a[k], 32);
        b[k] += __shfl_xor(b[k], 16);
        b[k] += __shfl_xor(b[k], 32);
    }

    if (g == 0) {
        uint2 o;
        o.x = (unsigned)f2bf(a[0]) | ((unsigned)f2bf(a[1]) << 16);
        o.y = (unsigned)f2bf(a[2]) | ((unsigned)f2bf(a[3]) << 16);
        *(uint2*)((char*)mup32 + ((size_t)dst * 128 + fp8)) = o;
    } else if (g == 1) {
        uint2 o;
        o.x = (unsigned)f2bf(b[0]) | ((unsigned)f2bf(b[1]) << 16);
        o.y = (unsigned)f2bf(b[2]) | ((unsigned)f2bf(b[3]) << 16);
        *(uint2*)((char*)mdn32 + ((size_t)dst * 128 + fp8)) = o;
    }
}

// ---------------------------------------------------------------------------
// MFMA gemm+tanh: hb = tanh(hb@Ws^T + mup@Wu^T + mdn@Wd^T), all bf16 in/out.
// One wave per 16 rows; B-frags loaded per-matrix (lower VGPR -> more waves).
// ---------------------------------------------------------------------------
__global__ __launch_bounds__(256) void gemm_tanh_mfma(
    const unsigned short* __restrict__ hbin,
    const unsigned short* __restrict__ mupb, const unsigned short* __restrict__ mdnb,
    const unsigned short* __restrict__ Wb,   // [3][64][64] bf16 for this layer
    unsigned short* __restrict__ hbout, int E, int nblk16)
{
    int wid  = (blockIdx.x * 256 + threadIdx.x) >> 6;
    if (wid >= nblk16) return;
    int lane = threadIdx.x & 63;
    int lg = lane >> 4;      // 0..3
    int lr = lane & 15;      // 0..15

    int base = wid * 16;
    int arow = base + lr;
    bool ok = (arow < E);
    size_t aoff = (size_t)arow * H64 + lg * 8;

    f32x4 acc[4];
    #pragma unroll
    for (int jt = 0; jt < 4; ++jt) acc[jt] = (f32x4){0.f, 0.f, 0.f, 0.f};

    bf16x8 zz = {0, 0, 0, 0, 0, 0, 0, 0};
    #pragma unroll
    for (int m = 0; m < 3; ++m) {
        const unsigned short* src = (m == 0) ? hbin : ((m == 1) ? mupb : mdnb);
        bf16x8 a0 = ok ? *(const bf16x8*)(src + aoff)      : zz;
        bf16x8 a1 = ok ? *(const bf16x8*)(src + aoff + 32) : zz;
        const unsigned short* wbase = Wb + m * 4096 + lr * 64 + lg * 8;
        #pragma unroll
        for (int jt = 0; jt < 4; ++jt) {
            bf16x8 b0 = *(const bf16x8*)(wbase + jt * 1024);
            bf16x8 b1 = *(const bf16x8*)(wbase + jt * 1024 + 32);
            acc[jt] = __builtin_amdgcn_mfma_f32_16x16x32_bf16(a0, b0, acc[jt], 0, 0, 0);
            acc[jt] = __builtin_amdgcn_mfma_f32_16x16x32_bf16(a1, b1, acc[jt], 0, 0, 0);
        }
    }

    #pragma unroll
    for (int jt = 0; jt < 4; ++jt) {
        #pragma unroll
        for (int reg = 0; reg < 4; ++reg) {
            int row = base + lg * 4 + reg;
            if (row < E) {
                float v = acc[jt][reg];
                float e2 = __expf(2.f * v);
                float val = 1.f - 2.f / (e2 + 1.f);
                hbout[(size_t)row * H64 + jt * 16 + lr] = f2bf(val);
            }
        }
    }
}

// ---------------------------------------------------------------------------
// pooled[batch[i]] += |h[i]| over sorted batch; h in bf16
// ---------------------------------------------------------------------------
#define ROWS_PER_WAVE 64
__global__ __launch_bounds__(256) void pool_kernel(
    const unsigned short* __restrict__ hb, const int* __restrict__ batch,
    float* __restrict__ pooled, int E)
{
    int wave = (int)((blockIdx.x * 256 + threadIdx.x) >> 6);
    int j = threadIdx.x & 63;
    int row0 = wave * ROWS_PER_WAVE;
    if (row0 >= E) return;
    int row1 = min(row0 + ROWS_PER_WAVE, E);

    int cur = batch[row0];
    float acc = 0.f;
    for (int i = row0; i < row1; ++i) {
        int b = batch[i];
        if (b != cur) {
            atomicAdd(&pooled[(size_t)cur * H64 + j], acc);
            acc = 0.f;
            cur = b;
        }
        unsigned u = hb[(size_t)i * H64 + j];
        acc += fabsf(__uint_as_float(u << 16));
    }
    atomicAdd(&pooled[(size_t)cur * H64 + j], acc);
}

// ---------------------------------------------------------------------------
__global__ __launch_bounds__(64) void head_kernel(
    const float* __restrict__ pooled,
    const float* __restrict__ lin1_w, const float* __restrict__ lin1_b,
    const float* __restrict__ lin2_w, const float* __restrict__ lin2_b,
    float* __restrict__ out, int C)
{
    __shared__ float p[64];
    __shared__ float z[64];
    int b = blockIdx.x;
    int t = threadIdx.x;

    p[t] = pooled[(size_t)b * H64 + t];
    __syncthreads();

    float acc = lin1_b[t];
    #pragma unroll
    for (int k = 0; k < 64; ++k) acc += p[k] * lin1_w[t * 64 + k];
    z[t] = fmaxf(acc, 0.f);
    __syncthreads();

    if (t < C) {
        float o = lin2_b[t];
        #pragma unroll
        for (int k = 0; k < 64; ++k) o += z[k] * lin2_w[t * 64 + k];
        out[(size_t)b * C + t] = o;
    }
}

// ---------------------------------------------------------------------------
extern "C" void kernel_launch(void* const* d_in, const int* in_sizes, int n_in,
                              void* d_out, int out_size, void* d_ws, size_t ws_size,
                              hipStream_t stream)
{
    const float* x          = (const float*)d_in[0];
    const int*   up_index   = (const int*)  d_in[1];
    const float* up_orient  = (const float*)d_in[2];
    const int*   down_index = (const int*)  d_in[3];
    const float* down_orient= (const float*)d_in[4];
    const int*   batch      = (const int*)  d_in[5];
    const float* W_up       = (const float*)d_in[6];
    const float* W_down     = (const float*)d_in[7];
    const float* W_self     = (const float*)d_in[8];
    const float* lin1_w     = (const float*)d_in[9];
    const float* lin1_b     = (const float*)d_in[10];
    const float* lin2_w     = (const float*)d_in[11];
    const float* lin2_b     = (const float*)d_in[12];
    float* out = (float*)d_out;

    const int E    = in_sizes[0] / H64;
    const int NADJ = in_sizes[1] / 2;
    const int C    = in_sizes[11] / H64;
    const int B    = out_size / C;
    const int L    = in_sizes[6] / (H64 * H64);

    // ---- workspace layout ----
    unsigned short* hb      = (unsigned short*)d_ws;              // E*64 bf16
    unsigned short* mupb    = hb   + (size_t)E * H64;             // E*64 bf16
    unsigned short* mdnb    = mupb + (size_t)E * H64;             // E*64 bf16
    float*          pooled  = (float*)(mdnb + (size_t)E * H64);   // B*64 f32
    int*            end2    = (int*)(pooled + (size_t)B * H64);   // 2E
    int*            deg2    = end2 + (size_t)2 * E;               // 2E (fallback)
    int*            bsums   = deg2 + (size_t)2 * E;               // 1024 (fallback)
    int*            bktcnt  = bsums + 1024;                       // NBKT_MAX
    int*            gcur    = bktcnt + NBKT_MAX;                  // NBKT_MAX
    int*            bstart  = gcur + NBKT_MAX;                    // NBKT_MAX+1
    unsigned short* Wb      = (unsigned short*)(bstart + NBKT_MAX + 1); // L*3*4096 bf16
    unsigned*       packed2 = (unsigned*)(Wb + (size_t)L * 3 * 4096);   // 2*NADJ
    unsigned*       binned  = packed2 + (size_t)2 * NADJ;         // 2*NADJ

    const int n2    = 2 * E;
    const int nbkt  = (n2 + RPB - 1) >> RPB_SH;
    const int total = 2 * NADJ;
    const int gather_blocks = (int)(((long long)E * 64 + 255) / 256);
    const int conv_blocks   = (int)(((long long)E * H64 / 4 + 255) / 256);
    const int convw_blocks  = (L * 3 * 4096 + 255) / 256;
    const int nblk16        = (E + 15) / 16;
    const int gemm_blocks   = (nblk16 + 3) / 4;
    const int pool_waves    = (E + ROWS_PER_WAVE - 1) / ROWS_PER_WAVE;
    const int pool_blocks   = (pool_waves + 3) / 4;

    // ---- CSR build ----
    if (nbkt <= NBKT_MAX) {
        const int bc_blocks = (total + BC_CHUNK - 1) / BC_CHUNK;
        const int r1_blocks = (total + R1_CHUNK - 1) / R1_CHUNK;
        hipMemsetAsync(bktcnt, 0, (size_t)NBKT_MAX * sizeof(int), stream);
        bcount_kernel<<<bc_blocks, 256, 0, stream>>>(up_index + NADJ, down_index + NADJ,
                                                     bktcnt, NADJ, E, nbkt);
        bscan_kernel<<<1, 256, 0, stream>>>(bktcnt, bstart, gcur, nbkt, total);
        bin_kernel<<<r1_blocks, 256, 0, stream>>>(up_index, up_orient, down_index, down_orient,
                                                  gcur, binned, NADJ, E, nbkt);
        csr_fill2_kernel<<<nbkt, 256, 0, stream>>>(binned, bstart, end2, packed2, n2);
    } else {
        const int both_blocks = (total + 255) / 256;
        const int nscan = (n2 + SCAN_TILE - 1) / SCAN_TILE;
        hipMemsetAsync(deg2, 0, (size_t)n2 * sizeof(int), stream);
        hist2_kernel<<<both_blocks, 256, 0, stream>>>(up_index + NADJ, down_index + NADJ, deg2, NADJ, E);
        scan_partial<<<nscan, 256, 0, stream>>>(deg2, bsums, n2);
        scan_bsums_k<<<1, 256, 0, stream>>>(bsums, nscan);
        scan_final<<<nscan, 256, 0, stream>>>(deg2, bsums, end2, n2);
        reorder2_kernel<<<both_blocks, 256, 0, stream>>>(up_index, up_orient, down_index, down_orient,
                                                         end2, packed2, NADJ, E);
    }

    // ---- bf16 conversions (x + weights, one kernel) ----
    conv_all_kernel<<<conv_blocks + convw_blocks, 256, 0, stream>>>(
        x, hb, (size_t)E * H64, conv_blocks, W_self, W_up, W_down, Wb, L);

    // ---- layers (all state in hb, bf16) ----
    for (int l = 0; l < L; ++l) {
        gather_kernel<<<gather_blocks, 256, 0, stream>>>(
            (const unsigned*)hb, end2, packed2,
            (unsigned*)mupb, (unsigned*)mdnb, E);
        gemm_tanh_mfma<<<gemm_blocks, 256, 0, stream>>>(
            hb, mupb, mdnb, Wb + (size_t)l * 3 * 4096, hb, E, nblk16);
    }

    // ---- readout ----
    hipMemsetAsync(pooled, 0, (size_t)B * H64 * sizeof(float), stream);
    pool_kernel<<<pool_blocks, 256, 0, stream>>>(hb, batch, pooled, E);
    head_kernel<<<B, 64, 0, stream>>>(pooled, lin1_w, lin1_b, lin2_w, lin2_b, out, C);
}

// Round 14
// 685.950 us; speedup vs baseline: 1.2287x; 1.0281x over previous
//
#include <hip/hip_runtime.h>
#include <hip/hip_bf16.h>

#define H64 64
typedef float float4a __attribute__((ext_vector_type(4)));
typedef float f32x4  __attribute__((ext_vector_type(4)));
typedef short bf16x8 __attribute__((ext_vector_type(8)));

__device__ __forceinline__ unsigned short f2bf(float x) {
    unsigned b = __float_as_uint(x);
    unsigned r = (b + 0x7fffu + ((b >> 16) & 1u)) >> 16;
    return (unsigned short)r;
}

#define SCAN_B 256

// ---------------------------------------------------------------------------
// Binned CSR build over concatenated row space [0,2E): U rows [0,E), D [E,2E)
// entry packing in binned: [sign:1][src:21][dst_low:9]
// packed2 final:           [sign:1][src:31]
// ---------------------------------------------------------------------------
#define RPB       512
#define RPB_SH    9
#define NBKT_MAX  1024
#define R1_CHUNK  8192
#define BC_CHUNK  16384

__global__ __launch_bounds__(256) void bcount_kernel(
    const int* __restrict__ up_dst, const int* __restrict__ dn_dst,
    int* __restrict__ bktcnt, int nadj, int E, int nbkt)
{
    __shared__ int lc[NBKT_MAX];
    int t = threadIdx.x;
    for (int i = t; i < nbkt; i += 256) lc[i] = 0;
    __syncthreads();
    long long base = (long long)blockIdx.x * BC_CHUNK;
    long long total = 2LL * nadj;
    for (int i = 0; i < BC_CHUNK / 256; ++i) {
        long long g = base + i * 256 + t;
        if (g < total) {
            int dst2 = (g < nadj) ? up_dst[(int)g] : E + dn_dst[(int)(g - nadj)];
            atomicAdd(&lc[dst2 >> RPB_SH], 1);
        }
    }
    __syncthreads();
    for (int i = t; i < nbkt; i += 256) {
        int c = lc[i];
        if (c) atomicAdd(&bktcnt[i], c);
    }
}

__global__ __launch_bounds__(256) void bscan_kernel(
    const int* __restrict__ bktcnt, int* __restrict__ bstart, int* __restrict__ gcur,
    int nbkt, int total)
{
    __shared__ int s[SCAN_B];
    int t = threadIdx.x;
    int i0 = t * 4;
    int v0 = (i0     < nbkt) ? bktcnt[i0]     : 0;
    int v1 = (i0 + 1 < nbkt) ? bktcnt[i0 + 1] : 0;
    int v2 = (i0 + 2 < nbkt) ? bktcnt[i0 + 2] : 0;
    int v3 = (i0 + 3 < nbkt) ? bktcnt[i0 + 3] : 0;
    int tsum = v0 + v1 + v2 + v3;
    s[t] = tsum; __syncthreads();
    for (int off = 1; off < SCAN_B; off <<= 1) {
        int add = (t >= off) ? s[t - off] : 0;
        int cur = s[t];
        __syncthreads();
        s[t] = cur + add;
        __syncthreads();
    }
    int excl = s[t] - tsum;
    if (i0     < nbkt) { bstart[i0]     = excl;                gcur[i0]     = excl; }
    if (i0 + 1 < nbkt) { bstart[i0 + 1] = excl + v0;           gcur[i0 + 1] = excl + v0; }
    if (i0 + 2 < nbkt) { bstart[i0 + 2] = excl + v0 + v1;      gcur[i0 + 2] = excl + v0 + v1; }
    if (i0 + 3 < nbkt) { bstart[i0 + 3] = excl + v0 + v1 + v2; gcur[i0 + 3] = excl + v0 + v1 + v2; }
    if (t == 0) bstart[nbkt] = total;
}

__global__ __launch_bounds__(256) void bin_kernel(
    const int* __restrict__ up_index, const float* __restrict__ up_orient,
    const int* __restrict__ dn_index, const float* __restrict__ dn_orient,
    int* __restrict__ gcur, unsigned* __restrict__ binned,
    int nadj, int E, int nbkt)
{
    __shared__ unsigned sval[R1_CHUNK];
    __shared__ unsigned short sbkt[R1_CHUNK];
    __shared__ int lcnt[NBKT_MAX];
    __shared__ int goff[NBKT_MAX];
    __shared__ int lrank[NBKT_MAX];

    int t = threadIdx.x;
    for (int b = t; b < nbkt; b += 256) lcnt[b] = 0;
    __syncthreads();

    long long base = (long long)blockIdx.x * R1_CHUNK;
    int total = 2 * nadj;
    #pragma unroll 4
    for (int i = 0; i < R1_CHUNK / 256; ++i) {
        long long g = base + i * 256 + t;
        int li = i * 256 + t;
        if (g < total) {
            int src, dst2; float orient;
            if (g < nadj) {
                int e = (int)g;
                src = up_index[e]; dst2 = up_index[nadj + e]; orient = up_orient[e];
            } else {
                int e = (int)(g - nadj);
                src = dn_index[e]; dst2 = E + dn_index[nadj + e]; orient = dn_orient[e];
            }
            unsigned v = ((unsigned)src << RPB_SH) | (unsigned)(dst2 & (RPB - 1))
                       | (orient < 0.f ? 0x80000000u : 0u);
            int bk = dst2 >> RPB_SH;
            sval[li] = v;
            sbkt[li] = (unsigned short)bk;
            atomicAdd(&lcnt[bk], 1);
        } else {
            sbkt[li] = 0xFFFFu;
        }
    }
    __syncthreads();
    for (int b = t; b < nbkt; b += 256) {
        int c = lcnt[b];
        lrank[b] = 0;
        if (c > 0) goff[b] = atomicAdd(&gcur[b], c);
    }
    __syncthreads();
    #pragma unroll 4
    for (int i = 0; i < R1_CHUNK / 256; ++i) {
        int li = i * 256 + t;
        unsigned short bk = sbkt[li];
        if (bk != 0xFFFFu) {
            int r = atomicAdd(&lrank[bk], 1);
            binned[goff[bk] + r] = sval[li];
        }
    }
}

// per-bucket exact CSR placement; all per-row atomics in LDS.
__global__ __launch_bounds__(256) void csr_fill2_kernel(
    const unsigned* __restrict__ binned, const int* __restrict__ bstart,
    int* __restrict__ end2, unsigned* __restrict__ packed2, int n2)
{
    __shared__ int lh[RPB];
    __shared__ int lcur[RPB];
    __shared__ int s[SCAN_B];
    int b = blockIdx.x;
    int t = threadIdx.x;
    int s0 = bstart[b], s1 = bstart[b + 1];
    int dbase = b << RPB_SH;

    for (int i = t; i < RPB; i += 256) lh[i] = 0;
    __syncthreads();
    for (int i = s0 + t; i < s1; i += 256) {
        unsigned v = binned[i];
        atomicAdd(&lh[v & (RPB - 1)], 1);
    }
    __syncthreads();

    int i0 = t * 2;
    int c0 = lh[i0], c1 = lh[i0 + 1];
    int tsum = c0 + c1;
    s[t] = tsum; __syncthreads();
    for (int off = 1; off < SCAN_B; off <<= 1) {
        int add = (t >= off) ? s[t - off] : 0;
        int cur = s[t];
        __syncthreads();
        s[t] = cur + add;
        __syncthreads();
    }
    int excl = s[t] - tsum;
    lcur[i0]     = excl;
    lcur[i0 + 1] = excl + c0;
    int gd = dbase + i0;
    if (gd     < n2) end2[gd]     = s0 + excl + c0;
    if (gd + 1 < n2) end2[gd + 1] = s0 + excl + tsum;
    __syncthreads();

    for (int i = s0 + t; i < s1; i += 256) {
        unsigned v = binned[i];
        int d = (int)(v & (RPB - 1));
        int p = atomicAdd(&lcur[d], 1);
        packed2[s0 + p] = (v & 0x80000000u) | ((v >> RPB_SH) & 0x1FFFFFu);
    }
}

// ---------------------------------------------------------------------------
// fallback path (only if nbkt > NBKT_MAX)
// ---------------------------------------------------------------------------
#define SCAN_TILE 1024

__global__ __launch_bounds__(256) void hist2_kernel(
    const int* __restrict__ up_dst, const int* __restrict__ dn_dst,
    int* __restrict__ deg2, int nadj, int E)
{
    int g = blockIdx.x * 256 + threadIdx.x;
    if (g < nadj) {
        atomicAdd(&deg2[up_dst[g]], 1);
    } else {
        int e = g - nadj;
        if (e < nadj) atomicAdd(&deg2[E + dn_dst[e]], 1);
    }
}

__global__ __launch_bounds__(256) void scan_partial(
    const int* __restrict__ deg, int* __restrict__ bsums, int n)
{
    __shared__ int s[SCAN_B];
    int t = threadIdx.x;
    int i0 = blockIdx.x * SCAN_TILE + t * 4;
    int sum = 0;
    if (i0 + 3 < n) {
        int4 v = *(const int4*)(deg + i0);
        sum = v.x + v.y + v.z + v.w;
    } else {
        for (int k = 0; k < 4; ++k) if (i0 + k < n) sum += deg[i0 + k];
    }
    s[t] = sum; __syncthreads();
    for (int off = 128; off > 0; off >>= 1) {
        if (t < off) s[t] += s[t + off];
        __syncthreads();
    }
    if (t == 0) bsums[blockIdx.x] = s[0];
}

__global__ __launch_bounds__(256) void scan_bsums_k(int* bsums, int nblk)
{
    __shared__ int s[SCAN_B];
    int t = threadIdx.x;
    int i0 = t * 4;
    int v0 = 0, v1 = 0, v2 = 0, v3 = 0;
    if (i0     < nblk) v0 = bsums[i0];
    if (i0 + 1 < nblk) v1 = bsums[i0 + 1];
    if (i0 + 2 < nblk) v2 = bsums[i0 + 2];
    if (i0 + 3 < nblk) v3 = bsums[i0 + 3];
    int tsum = v0 + v1 + v2 + v3;
    s[t] = tsum; __syncthreads();
    for (int off = 1; off < SCAN_B; off <<= 1) {
        int add = (t >= off) ? s[t - off] : 0;
        int cur = s[t];
        __syncthreads();
        s[t] = cur + add;
        __syncthreads();
    }
    int excl = s[t] - tsum;
    if (i0     < nblk) bsums[i0]     = excl;
    if (i0 + 1 < nblk) bsums[i0 + 1] = excl + v0;
    if (i0 + 2 < nblk) bsums[i0 + 2] = excl + v0 + v1;
    if (i0 + 3 < nblk) bsums[i0 + 3] = excl + v0 + v1 + v2;
}

__global__ __launch_bounds__(256) void scan_final(
    const int* __restrict__ deg, const int* __restrict__ bsums,
    int* __restrict__ outx, int n)
{
    __shared__ int s[SCAN_B];
    int t = threadIdx.x;
    int i0 = blockIdx.x * SCAN_TILE + t * 4;
    int v0 = 0, v1 = 0, v2 = 0, v3 = 0;
    if (i0 + 3 < n) {
        int4 v = *(const int4*)(deg + i0);
        v0 = v.x; v1 = v.y; v2 = v.z; v3 = v.w;
    } else {
        if (i0     < n) v0 = deg[i0];
        if (i0 + 1 < n) v1 = deg[i0 + 1];
        if (i0 + 2 < n) v2 = deg[i0 + 2];
        if (i0 + 3 < n) v3 = deg[i0 + 3];
    }
    int tsum = v0 + v1 + v2 + v3;
    s[t] = tsum; __syncthreads();
    for (int off = 1; off < SCAN_B; off <<= 1) {
        int add = (t >= off) ? s[t - off] : 0;
        int cur = s[t];
        __syncthreads();
        s[t] = cur + add;
        __syncthreads();
    }
    int excl = s[t] - tsum;
    int base = bsums[blockIdx.x] + excl;
    if (i0     < n) outx[i0]     = base;
    if (i0 + 1 < n) outx[i0 + 1] = base + v0;
    if (i0 + 2 < n) outx[i0 + 2] = base + v0 + v1;
    if (i0 + 3 < n) outx[i0 + 3] = base + v0 + v1 + v2;
}

__global__ __launch_bounds__(256) void reorder2_kernel(
    const int* __restrict__ up_index, const float* __restrict__ up_orient,
    const int* __restrict__ dn_index, const float* __restrict__ dn_orient,
    int* __restrict__ end2, unsigned* __restrict__ packed2, int nadj, int E)
{
    int g = blockIdx.x * 256 + threadIdx.x;
    if (g < nadj) {
        int src = up_index[g];
        int dst = up_index[nadj + g];
        int p = atomicAdd(&end2[dst], 1);
        packed2[p] = (unsigned)src | (up_orient[g] < 0.f ? 0x80000000u : 0u);
    } else {
        int e = g - nadj;
        if (e < nadj) {
            int src = dn_index[e];
            int dst = dn_index[nadj + e];
            int p = atomicAdd(&end2[E + dst], 1);
            packed2[p] = (unsigned)src | (dn_orient[e] < 0.f ? 0x80000000u : 0u);
        }
    }
}

// ---------------------------------------------------------------------------
// f32 -> bf16 conversions: x (blocks [0, conv_blocks)) and W (rest)
// ---------------------------------------------------------------------------
__global__ __launch_bounds__(256) void conv_all_kernel(
    const float* __restrict__ x, unsigned short* __restrict__ hb, size_t n,
    int conv_blocks,
    const float* __restrict__ Ws, const float* __restrict__ Wu,
    const float* __restrict__ Wd, unsigned short* __restrict__ Wb, int L)
{
    if (blockIdx.x < (unsigned)conv_blocks) {
        size_t i = ((size_t)blockIdx.x * 256 + threadIdx.x) * 4;
        if (i + 3 < n) {
            float4a v = *(const float4a*)(x + i);
            uint2 o;
            o.x = (unsigned)f2bf(v[0]) | ((unsigned)f2bf(v[1]) << 16);
            o.y = (unsigned)f2bf(v[2]) | ((unsigned)f2bf(v[3]) << 16);
            *(uint2*)(hb + i) = o;
        } else {
            for (size_t k = i; k < n; ++k) hb[k] = f2bf(x[k]);
        }
    } else {
        int i = (blockIdx.x - conv_blocks) * 256 + threadIdx.x;
        int total = L * 3 * 4096;
        if (i >= total) return;
        int l = i / (3 * 4096);
        int m = (i / 4096) % 3;
        int r = i & 4095;
        const float* src = (m == 0) ? Ws : ((m == 1) ? Wu : Wd);
        Wb[i] = f2bf(src[l * 4096 + r]);
    }
}

// ---------------------------------------------------------------------------
// gather: wave per dst row. 4 groups of 16 lanes; group g handles entry
// n+4t+g; lane loads uint2 = 4 feats (128B/entry). Fused U||D main block is
// 16 entries wide: 4 U-loads + 4 D-loads issued back-to-back (8 outstanding)
// before any FMA. Remainders use 2-load steps. 2-level shfl_xor reduce.
// ---------------------------------------------------------------------------
__device__ __forceinline__ void seg_sum4_slow(
    const unsigned* __restrict__ hb32, const unsigned* __restrict__ packed2,
    int s0, int s1, unsigned fp8, int g, int lane, float a[4])
{
    const char* hbase = (const char*)hb32;
    for (int bb = s0; bb < s1; bb += 64) {
        int cnt = min(64, s1 - bb);
        int lim = cnt - 1;
        unsigned pk = (lane < cnt) ? packed2[bb + lane] : 0u;
        for (int n = 0; n < cnt; n += 4) {
            int idx = n + g;
            unsigned pe = __shfl(pk, min(idx, lim));
            float sg = (idx < cnt) ? (((int)pe < 0) ? -1.f : 1.f) : 0.f;
            uint2 v = *(const uint2*)(hbase + ((pe << 7) + fp8));
            a[0] = fmaf(__uint_as_float(v.x << 16),         sg, a[0]);
            a[1] = fmaf(__uint_as_float(v.x & 0xFFFF0000u), sg, a[1]);
            a[2] = fmaf(__uint_as_float(v.y << 16),         sg, a[2]);
            a[3] = fmaf(__uint_as_float(v.y & 0xFFFF0000u), sg, a[3]);
        }
    }
}

__global__ __launch_bounds__(256) void gather_kernel(
    const unsigned* __restrict__ hb32,
    const int* __restrict__ end2, const unsigned* __restrict__ packed2,
    unsigned* __restrict__ mup32, unsigned* __restrict__ mdn32, int E)
{
    int dst = (int)((blockIdx.x * 256u + threadIdx.x) >> 6);
    if (dst >= E) return;
    int lane = threadIdx.x & 63;
    int g  = lane >> 4;        // 0..3 entry group
    unsigned fp = lane & 15;   // feats [4fp, 4fp+4)
    unsigned fp8 = fp * 8;     // byte offset within row
    const char* hbase = (const char*)hb32;

    int s0U = (dst == 0) ? 0 : end2[dst - 1];
    int s1U = end2[dst];
    int s0D = end2[E + dst - 1];
    int s1D = end2[E + dst];
    int cntU = s1U - s0U, cntD = s1D - s0D;

    float a[4] = {0.f, 0.f, 0.f, 0.f};
    float b[4] = {0.f, 0.f, 0.f, 0.f};

    if (cntU <= 64 && cntD <= 64) {
        int limU = max(cntU - 1, 0), limD = max(cntD - 1, 0);
        unsigned pkU = (cntU > 0) ? packed2[s0U + min(lane, limU)] : 0u;
        unsigned pkD = (cntD > 0) ? packed2[s0D + min(lane, limD)] : 0u;
        int nmin = min(cntU, cntD);
        int n = 0;
        // fused main: 16 entries, 4 U-loads + 4 D-loads in flight
        for (; n < nmin; n += 16) {
            unsigned pU[4], pD[4]; uint2 vU[4], vD[4]; float sU[4], sD[4];
            #pragma unroll
            for (int t = 0; t < 4; ++t) {
                int idx = n + 4 * t + g;
                pU[t] = __shfl(pkU, min(idx, limU));
                pD[t] = __shfl(pkD, min(idx, limD));
                sU[t] = (idx < cntU) ? (((int)pU[t] < 0) ? -1.f : 1.f) : 0.f;
                sD[t] = (idx < cntD) ? (((int)pD[t] < 0) ? -1.f : 1.f) : 0.f;
            }
            #pragma unroll
            for (int t = 0; t < 4; ++t) vU[t] = *(const uint2*)(hbase + ((pU[t] << 7) + fp8));
            #pragma unroll
            for (int t = 0; t < 4; ++t) vD[t] = *(const uint2*)(hbase + ((pD[t] << 7) + fp8));
            #pragma unroll
            for (int t = 0; t < 4; ++t) {
                a[0] = fmaf(__uint_as_float(vU[t].x << 16),         sU[t], a[0]);
                a[1] = fmaf(__uint_as_float(vU[t].x & 0xFFFF0000u), sU[t], a[1]);
                a[2] = fmaf(__uint_as_float(vU[t].y << 16),         sU[t], a[2]);
                a[3] = fmaf(__uint_as_float(vU[t].y & 0xFFFF0000u), sU[t], a[3]);
                b[0] = fmaf(__uint_as_float(vD[t].x << 16),         sD[t], b[0]);
                b[1] = fmaf(__uint_as_float(vD[t].x & 0xFFFF0000u), sD[t], b[1]);
                b[2] = fmaf(__uint_as_float(vD[t].y << 16),         sD[t], b[2]);
                b[3] = fmaf(__uint_as_float(vD[t].y & 0xFFFF0000u), sD[t], b[3]);
            }
        }
        // U remainder: 2-load steps (8 entries)
        for (int q = n; q < cntU; q += 8) {
            unsigned p[2]; uint2 v[2]; float sg[2];
            #pragma unroll
            for (int t = 0; t < 2; ++t) {
                int idx = q + 4 * t + g;
                p[t] = __shfl(pkU, min(idx, limU));
                sg[t] = (idx < cntU) ? (((int)p[t] < 0) ? -1.f : 1.f) : 0.f;
            }
            #pragma unroll
            for (int t = 0; t < 2; ++t) v[t] = *(const uint2*)(hbase + ((p[t] << 7) + fp8));
            #pragma unroll
            for (int t = 0; t < 2; ++t) {
                a[0] = fmaf(__uint_as_float(v[t].x << 16),         sg[t], a[0]);
                a[1] = fmaf(__uint_as_float(v[t].x & 0xFFFF0000u), sg[t], a[1]);
                a[2] = fmaf(__uint_as_float(v[t].y << 16),         sg[t], a[2]);
                a[3] = fmaf(__uint_as_float(v[t].y & 0xFFFF0000u), sg[t], a[3]);
            }
        }
        // D remainder
        for (int q = n; q < cntD; q += 8) {
            unsigned p[2]; uint2 v[2]; float sg[2];
            #pragma unroll
            for (int t = 0; t < 2; ++t) {
                int idx = q + 4 * t + g;
                p[t] = __shfl(pkD, min(idx, limD));
                sg[t] = (idx < cntD) ? (((int)p[t] < 0) ? -1.f : 1.f) : 0.f;
            }
            #pragma unroll
            for (int t = 0; t < 2; ++t) v[t] = *(const uint2*)(hbase + ((p[t] << 7) + fp8));
            #pragma unroll
            for (int t = 0; t < 2; ++t) {
                b[0] = fmaf(__uint_as_float(v[t].x << 16),         sg[t], b[0]);
                b[1] = fmaf(__uint_as_float(v[t].x & 0xFFFF0000u), sg[t], b[1]);
                b[2] = fmaf(__uint_as_float(v[t].y << 16),         sg[t], b[2]);
                b[3] = fmaf(__uint_as_float(v[t].y & 0xFFFF0000u), sg[t], b[3]);
            }
        }
    } else {
        seg_sum4_slow(hb32, packed2, s0U, s1U, fp8, g, lane, a);
        seg_sum4_slow(hb32, packed2, s0D, s1D, fp8, g, lane, b);
    }

    #pragma unroll
    for (int k = 0; k < 4; ++k) {
        a[k] += __shfl_xor(a[k], 16);
        a[k] += __shfl_xor(a[k], 32);
        b[k] += __shfl_xor(b[k], 16);
        b[k] += __shfl_xor(b[k], 32);
    }

    if (g == 0) {
        uint2 o;
        o.x = (unsigned)f2bf(a[0]) | ((unsigned)f2bf(a[1]) << 16);
        o.y = (unsigned)f2bf(a[2]) | ((unsigned)f2bf(a[3]) << 16);
        *(uint2*)((char*)mup32 + ((size_t)dst * 128 + fp8)) = o;
    } else if (g == 1) {
        uint2 o;
        o.x = (unsigned)f2bf(b[0]) | ((unsigned)f2bf(b[1]) << 16);
        o.y = (unsigned)f2bf(b[2]) | ((unsigned)f2bf(b[3]) << 16);
        *(uint2*)((char*)mdn32 + ((size_t)dst * 128 + fp8)) = o;
    }
}

// ---------------------------------------------------------------------------
// MFMA gemm+tanh: hb = tanh(hb@Ws^T + mup@Wu^T + mdn@Wd^T), all bf16 in/out.
// Last layer also accumulates pooled[batch] += |h| (tile-uniform fast path:
// in-register reduce over the 16-row tile + 64 atomics; per-row fallback at
// the ~63 graph-boundary tiles).
// ---------------------------------------------------------------------------
__global__ __launch_bounds__(256) void gemm_tanh_mfma(
    const unsigned short* __restrict__ hbin,
    const unsigned short* __restrict__ mupb, const unsigned short* __restrict__ mdnb,
    const unsigned short* __restrict__ Wb,   // [3][64][64] bf16 for this layer
    unsigned short* __restrict__ hbout, int E, int nblk16,
    const int* __restrict__ batch, float* __restrict__ pooled, int do_pool)
{
    int wid  = (blockIdx.x * 256 + threadIdx.x) >> 6;
    if (wid >= nblk16) return;
    int lane = threadIdx.x & 63;
    int lg = lane >> 4;      // 0..3
    int lr = lane & 15;      // 0..15

    int base = wid * 16;
    int arow = base + lr;
    bool ok = (arow < E);
    size_t aoff = (size_t)arow * H64 + lg * 8;

    f32x4 acc[4];
    #pragma unroll
    for (int jt = 0; jt < 4; ++jt) acc[jt] = (f32x4){0.f, 0.f, 0.f, 0.f};

    bf16x8 zz = {0, 0, 0, 0, 0, 0, 0, 0};
    #pragma unroll
    for (int m = 0; m < 3; ++m) {
        const unsigned short* src = (m == 0) ? hbin : ((m == 1) ? mupb : mdnb);
        bf16x8 a0 = ok ? *(const bf16x8*)(src + aoff)      : zz;
        bf16x8 a1 = ok ? *(const bf16x8*)(src + aoff + 32) : zz;
        const unsigned short* wbase = Wb + m * 4096 + lr * 64 + lg * 8;
        #pragma unroll
        for (int jt = 0; jt < 4; ++jt) {
            bf16x8 b0 = *(const bf16x8*)(wbase + jt * 1024);
            bf16x8 b1 = *(const bf16x8*)(wbase + jt * 1024 + 32);
            acc[jt] = __builtin_amdgcn_mfma_f32_16x16x32_bf16(a0, b0, acc[jt], 0, 0, 0);
            acc[jt] = __builtin_amdgcn_mfma_f32_16x16x32_bf16(a1, b1, acc[jt], 0, 0, 0);
        }
    }

    float aval[4][4];
    #pragma unroll
    for (int jt = 0; jt < 4; ++jt) {
        #pragma unroll
        for (int reg = 0; reg < 4; ++reg) {
            int row = base + lg * 4 + reg;
            float val = 0.f;
            if (row < E) {
                float v = acc[jt][reg];
                float e2 = __expf(2.f * v);
                val = 1.f - 2.f / (e2 + 1.f);
                hbout[(size_t)row * H64 + jt * 16 + lr] = f2bf(val);
            }
            aval[jt][reg] = fabsf(val);
        }
    }

    if (do_pool) {
        bool full = (base + 15 < E);
        int b0 = batch[base];
        int b1 = full ? batch[base + 15] : -1;
        if (full && b0 == b1) {
            float pabs[4];
            #pragma unroll
            for (int jt = 0; jt < 4; ++jt) {
                pabs[jt] = aval[jt][0] + aval[jt][1] + aval[jt][2] + aval[jt][3];
                pabs[jt] += __shfl_xor(pabs[jt], 16);
                pabs[jt] += __shfl_xor(pabs[jt], 32);
            }
            if (lg == 0) {
                #pragma unroll
                for (int jt = 0; jt < 4; ++jt)
                    atomicAdd(&pooled[(size_t)b0 * H64 + jt * 16 + lr], pabs[jt]);
            }
        } else {
            // boundary tile: per-row atomics (rare)
            #pragma unroll
            for (int jt = 0; jt < 4; ++jt) {
                #pragma unroll
                for (int reg = 0; reg < 4; ++reg) {
                    int row = base + lg * 4 + reg;
                    if (row < E)
                        atomicAdd(&pooled[(size_t)batch[row] * H64 + jt * 16 + lr],
                                  aval[jt][reg]);
                }
            }
        }
    }
}

// ---------------------------------------------------------------------------
__global__ __launch_bounds__(64) void head_kernel(
    const float* __restrict__ pooled,
    const float* __restrict__ lin1_w, const float* __restrict__ lin1_b,
    const float* __restrict__ lin2_w, const float* __restrict__ lin2_b,
    float* __restrict__ out, int C)
{
    __shared__ float p[64];
    __shared__ float z[64];
    int b = blockIdx.x;
    int t = threadIdx.x;

    p[t] = pooled[(size_t)b * H64 + t];
    __syncthreads();

    float acc = lin1_b[t];
    #pragma unroll
    for (int k = 0; k < 64; ++k) acc += p[k] * lin1_w[t * 64 + k];
    z[t] = fmaxf(acc, 0.f);
    __syncthreads();

    if (t < C) {
        float o = lin2_b[t];
        #pragma unroll
        for (int k = 0; k < 64; ++k) o += z[k] * lin2_w[t * 64 + k];
        out[(size_t)b * C + t] = o;
    }
}

// ---------------------------------------------------------------------------
extern "C" void kernel_launch(void* const* d_in, const int* in_sizes, int n_in,
                              void* d_out, int out_size, void* d_ws, size_t ws_size,
                              hipStream_t stream)
{
    const float* x          = (const float*)d_in[0];
    const int*   up_index   = (const int*)  d_in[1];
    const float* up_orient  = (const float*)d_in[2];
    const int*   down_index = (const int*)  d_in[3];
    const float* down_orient= (const float*)d_in[4];
    const int*   batch      = (const int*)  d_in[5];
    const float* W_up       = (const float*)d_in[6];
    const float* W_down     = (const float*)d_in[7];
    const float* W_self     = (const float*)d_in[8];
    const float* lin1_w     = (const float*)d_in[9];
    const float* lin1_b     = (const float*)d_in[10];
    const float* lin2_w     = (const float*)d_in[11];
    const float* lin2_b     = (const float*)d_in[12];
    float* out = (float*)d_out;

    const int E    = in_sizes[0] / H64;
    const int NADJ = in_sizes[1] / 2;
    const int C    = in_sizes[11] / H64;
    const int B    = out_size / C;
    const int L    = in_sizes[6] / (H64 * H64);

    // ---- workspace layout ----
    unsigned short* hb      = (unsigned short*)d_ws;              // E*64 bf16
    unsigned short* mupb    = hb   + (size_t)E * H64;             // E*64 bf16
    unsigned short* mdnb    = mupb + (size_t)E * H64;             // E*64 bf16
    float*          pooled  = (float*)(mdnb + (size_t)E * H64);   // B*64 f32
    int*            end2    = (int*)(pooled + (size_t)B * H64);   // 2E
    int*            deg2    = end2 + (size_t)2 * E;               // 2E (fallback)
    int*            bsums   = deg2 + (size_t)2 * E;               // 1024 (fallback)
    int*            bktcnt  = bsums + 1024;                       // NBKT_MAX
    int*            gcur    = bktcnt + NBKT_MAX;                  // NBKT_MAX
    int*            bstart  = gcur + NBKT_MAX;                    // NBKT_MAX+1
    unsigned short* Wb      = (unsigned short*)(bstart + NBKT_MAX + 1); // L*3*4096 bf16
    unsigned*       packed2 = (unsigned*)(Wb + (size_t)L * 3 * 4096);   // 2*NADJ
    unsigned*       binned  = packed2 + (size_t)2 * NADJ;         // 2*NADJ

    const int n2    = 2 * E;
    const int nbkt  = (n2 + RPB - 1) >> RPB_SH;
    const int total = 2 * NADJ;
    const int gather_blocks = (int)(((long long)E * 64 + 255) / 256);
    const int conv_blocks   = (int)(((long long)E * H64 / 4 + 255) / 256);
    const int convw_blocks  = (L * 3 * 4096 + 255) / 256;
    const int nblk16        = (E + 15) / 16;
    const int gemm_blocks   = (nblk16 + 3) / 4;

    // ---- CSR build ----
    if (nbkt <= NBKT_MAX) {
        const int bc_blocks = (total + BC_CHUNK - 1) / BC_CHUNK;
        const int r1_blocks = (total + R1_CHUNK - 1) / R1_CHUNK;
        hipMemsetAsync(bktcnt, 0, (size_t)NBKT_MAX * sizeof(int), stream);
        bcount_kernel<<<bc_blocks, 256, 0, stream>>>(up_index + NADJ, down_index + NADJ,
                                                     bktcnt, NADJ, E, nbkt);
        bscan_kernel<<<1, 256, 0, stream>>>(bktcnt, bstart, gcur, nbkt, total);
        bin_kernel<<<r1_blocks, 256, 0, stream>>>(up_index, up_orient, down_index, down_orient,
                                                  gcur, binned, NADJ, E, nbkt);
        csr_fill2_kernel<<<nbkt, 256, 0, stream>>>(binned, bstart, end2, packed2, n2);
    } else {
        const int both_blocks = (total + 255) / 256;
        const int nscan = (n2 + SCAN_TILE - 1) / SCAN_TILE;
        hipMemsetAsync(deg2, 0, (size_t)n2 * sizeof(int), stream);
        hist2_kernel<<<both_blocks, 256, 0, stream>>>(up_index + NADJ, down_index + NADJ, deg2, NADJ, E);
        scan_partial<<<nscan, 256, 0, stream>>>(deg2, bsums, n2);
        scan_bsums_k<<<1, 256, 0, stream>>>(bsums, nscan);
        scan_final<<<nscan, 256, 0, stream>>>(deg2, bsums, end2, n2);
        reorder2_kernel<<<both_blocks, 256, 0, stream>>>(up_index, up_orient, down_index, down_orient,
                                                         end2, packed2, NADJ, E);
    }

    // ---- bf16 conversions (x + weights, one kernel) ----
    conv_all_kernel<<<conv_blocks + convw_blocks, 256, 0, stream>>>(
        x, hb, (size_t)E * H64, conv_blocks, W_self, W_up, W_down, Wb, L);

    // ---- pooled zero (before fused-pool gemm) ----
    hipMemsetAsync(pooled, 0, (size_t)B * H64 * sizeof(float), stream);

    // ---- layers (all state in hb, bf16); last gemm fuses abs-pool ----
    for (int l = 0; l < L; ++l) {
        gather_kernel<<<gather_blocks, 256, 0, stream>>>(
            (const unsigned*)hb, end2, packed2,
            (unsigned*)mupb, (unsigned*)mdnb, E);
        gemm_tanh_mfma<<<gemm_blocks, 256, 0, stream>>>(
            hb, mupb, mdnb, Wb + (size_t)l * 3 * 4096, hb, E, nblk16,
            batch, pooled, (l == L - 1) ? 1 : 0);
    }

    // ---- readout ----
    head_kernel<<<B, 64, 0, stream>>>(pooled, lin1_w, lin1_b, lin2_w, lin2_b, out, C);
}